// Round 1
// baseline (15744.948 us; speedup 1.0000x reference)
//
#include <hip/hip_runtime.h>

#define N_NODES 50000
#define N_EDGES 1600000
#define N_LAYERS 4
#define N_CH 16
#define HID 48            // N_CH * 3
#define N_GRAPHS 64
#define TP_NORM 0.17677669529663687f   // 1/sqrt(2*N_CH)
#define SQRT3 1.7320508075688772f

// ---------------- embed: h = x @ embed_w ----------------
__global__ void k_embed(const float* __restrict__ x, const float* __restrict__ ew,
                        float* __restrict__ h) {
    int t = blockIdx.x * blockDim.x + threadIdx.x;
    if (t >= N_NODES * HID) return;
    int n = t / HID, c = t % HID;
    float v = x[n * 3 + 0] * ew[0 * HID + c]
            + x[n * 3 + 1] * ew[1 * HID + c]
            + x[n * 3 + 2] * ew[2 * HID + c];
    h[t] = v;
}

// ---------------- per-layer edge kernel ----------------
// one thread per edge: gate MLP + cross-product TP + atomic scatter into dx
__global__ void __launch_bounds__(256) k_edge(
    const int* __restrict__ ei, const float* __restrict__ ea,
    const float* __restrict__ h, float* __restrict__ dx,
    const float* __restrict__ m1w, const float* __restrict__ m1b,
    const float* __restrict__ m2w, const float* __restrict__ m2b,
    const float* __restrict__ tpw)
{
    __shared__ float s_m1w[48];    // (3,16)
    __shared__ float s_m1b[16];
    __shared__ float s_m2w[768];   // (16,48)
    __shared__ float s_m2b[48];
    __shared__ float s_tpw[256];   // (16,16) [u,v]

    for (int i = threadIdx.x; i < 48;  i += 256) s_m1w[i] = m1w[i];
    for (int i = threadIdx.x; i < 16;  i += 256) s_m1b[i] = m1b[i];
    for (int i = threadIdx.x; i < 768; i += 256) s_m2w[i] = m2w[i];
    for (int i = threadIdx.x; i < 48;  i += 256) s_m2b[i] = m2b[i];
    for (int i = threadIdx.x; i < 256; i += 256) s_tpw[i] = tpw[i];
    __syncthreads();

    int e = blockIdx.x * 256 + threadIdx.x;   // N_EDGES % 256 == 0, no guard needed
    int src = ei[e];
    int dst = ei[N_EDGES + e];

    float a0 = ea[e * 5 + 0], a1 = ea[e * 5 + 1];
    float rx = ea[e * 5 + 2], ry = ea[e * 5 + 3], rz = ea[e * 5 + 4];
    float r2 = rx * rx + ry * ry + rz * rz;
    float inv = rsqrtf(fmaxf(r2, 1e-24f));
    float shx = SQRT3 * rx * inv, shy = SQRT3 * ry * inv, shz = SQRT3 * rz * inv;

    // gate = silu([a0,a1,r2] @ m1w + m1b) @ m2w + m2b
    float hid[16];
#pragma unroll
    for (int j = 0; j < 16; j++) {
        float z = a0 * s_m1w[j] + a1 * s_m1w[16 + j] + r2 * s_m1w[32 + j] + s_m1b[j];
        hid[j] = z / (1.f + __expf(-z));
    }
    float gate[48];
#pragma unroll
    for (int c = 0; c < 48; c++) {
        float g = s_m2b[c];
#pragma unroll
        for (int j = 0; j < 16; j++) g += hid[j] * s_m2w[j * 48 + c];
        gate[c] = g;
    }

    // gather source features (12x float4, 192B aligned)
    float xj[48];
    const float4* hv = (const float4*)(h + (size_t)src * HID);
#pragma unroll
    for (int q = 0; q < 12; q++) {
        float4 t = hv[q];
        xj[q * 4 + 0] = t.x; xj[q * 4 + 1] = t.y; xj[q * 4 + 2] = t.z; xj[q * 4 + 3] = t.w;
    }

    // cross products per channel: cr[u] = xj_u x sh
    float cr[48];
#pragma unroll
    for (int u = 0; u < 16; u++) {
        float x0 = xj[u * 3 + 0], x1 = xj[u * 3 + 1], x2 = xj[u * 3 + 2];
        cr[u * 3 + 0] = x1 * shz - x2 * shy;
        cr[u * 3 + 1] = x2 * shx - x0 * shz;
        cr[u * 3 + 2] = x0 * shy - x1 * shx;
    }

    // tp[v,k] = sum_u tpw[u,v] * cr[u,k];  msg = gate * tp * TP_NORM; scatter
    float* dd = dx + (size_t)dst * HID;
#pragma unroll
    for (int v = 0; v < 16; v++) {
        float t0 = 0.f, t1 = 0.f, t2 = 0.f;
#pragma unroll
        for (int u = 0; u < 16; u++) {
            float w = s_tpw[u * 16 + v];
            t0 += w * cr[u * 3 + 0];
            t1 += w * cr[u * 3 + 1];
            t2 += w * cr[u * 3 + 2];
        }
        atomicAdd(dd + v * 3 + 0, gate[v * 3 + 0] * t0 * TP_NORM);
        atomicAdd(dd + v * 3 + 1, gate[v * 3 + 1] * t1 * TP_NORM);
        atomicAdd(dd + v * 3 + 2, gate[v * 3 + 2] * t2 * TP_NORM);
    }
}

// ---------------- h += dx; dx = 0 ----------------
__global__ void k_add(float* __restrict__ h, float* __restrict__ dx) {
    int t = blockIdx.x * blockDim.x + threadIdx.x;
    if (t >= N_NODES * HID) return;
    h[t] += dx[t];
    dx[t] = 0.f;
}

// ---------------- pool: per-graph mean of (h @ lin_w) ----------------
__global__ void __launch_bounds__(256) k_pool(
    const float* __restrict__ h, const int* __restrict__ batch,
    const float* __restrict__ linw, float* __restrict__ gsum, float* __restrict__ gcnt)
{
    __shared__ float ss[N_GRAPHS];
    __shared__ float sc[N_GRAPHS];
    for (int i = threadIdx.x; i < N_GRAPHS; i += 256) { ss[i] = 0.f; sc[i] = 0.f; }
    __syncthreads();

    int n = blockIdx.x * 256 + threadIdx.x;
    if (n < N_NODES) {
        float s = 0.f;
        const float4* hv = (const float4*)(h + (size_t)n * HID);
#pragma unroll
        for (int q = 0; q < 12; q++) {
            float4 t = hv[q];
            s += t.x * linw[q * 4 + 0] + t.y * linw[q * 4 + 1]
               + t.z * linw[q * 4 + 2] + t.w * linw[q * 4 + 3];
        }
        int b = batch[n];
        atomicAdd(&ss[b], s);
        atomicAdd(&sc[b], 1.f);
    }
    __syncthreads();
    for (int i = threadIdx.x; i < N_GRAPHS; i += 256) {
        if (sc[i] != 0.f) {
            atomicAdd(&gsum[i], ss[i]);
            atomicAdd(&gcnt[i], sc[i]);
        }
    }
}

__global__ void k_final(const float* __restrict__ gsum, const float* __restrict__ gcnt,
                        const float* __restrict__ linb, float* __restrict__ out) {
    int g = threadIdx.x;
    if (g < N_GRAPHS) out[g] = gsum[g] / fmaxf(gcnt[g], 1.f) + linb[0];
}

extern "C" void kernel_launch(void* const* d_in, const int* in_sizes, int n_in,
                              void* d_out, int out_size, void* d_ws, size_t ws_size,
                              hipStream_t stream) {
    const float* x    = (const float*)d_in[0];
    const int*   ei   = (const int*)  d_in[1];
    const float* ea   = (const float*)d_in[2];
    const int*   batch= (const int*)  d_in[3];
    const float* ew   = (const float*)d_in[4];
    const float* m1w  = (const float*)d_in[5];
    const float* m1b  = (const float*)d_in[6];
    const float* m2w  = (const float*)d_in[7];
    const float* m2b  = (const float*)d_in[8];
    const float* tpw  = (const float*)d_in[9];
    const float* linw = (const float*)d_in[10];
    const float* linb = (const float*)d_in[11];
    float* out = (float*)d_out;

    float* h    = (float*)d_ws;                 // 50000*48 f32 = 9.6 MB
    float* dx   = h + (size_t)N_NODES * HID;    // 9.6 MB
    float* gsum = dx + (size_t)N_NODES * HID;   // 64
    float* gcnt = gsum + N_GRAPHS;              // 64

    // zero dx + gsum + gcnt (contiguous) once per call
    hipMemsetAsync(dx, 0, ((size_t)N_NODES * HID + 2 * N_GRAPHS) * sizeof(float), stream);

    k_embed<<<(N_NODES * HID + 255) / 256, 256, 0, stream>>>(x, ew, h);

    for (int l = 0; l < N_LAYERS; l++) {
        k_edge<<<N_EDGES / 256, 256, 0, stream>>>(
            ei, ea, h, dx,
            m1w + l * 48, m1b + l * 16, m2w + l * 768, m2b + l * 48, tpw + l * 256);
        k_add<<<(N_NODES * HID + 255) / 256, 256, 0, stream>>>(h, dx);
    }

    k_pool<<<(N_NODES + 255) / 256, 256, 0, stream>>>(h, batch, linw, gsum, gcnt);
    k_final<<<1, 64, 0, stream>>>(gsum, gcnt, linb, out);
}

// Round 3
// 1425.336 us; speedup vs baseline: 11.0465x; 11.0465x over previous
//
#include <hip/hip_runtime.h>

#define N_NODES 50000
#define N_EDGES 1600000
#define N_LAYERS 4
#define N_CH 16
#define HID 48            // N_CH * 3
#define N_GRAPHS 64
#define TP_NORM 0.17677669529663687f   // 1/sqrt(2*N_CH)
#define SQRT3 1.7320508075688772f

// ---------------- embed: h = x @ embed_w ----------------
__global__ void k_embed(const float* __restrict__ x, const float* __restrict__ ew,
                        float* __restrict__ h) {
    int t = blockIdx.x * blockDim.x + threadIdx.x;
    if (t >= N_NODES * HID) return;
    int n = t / HID, c = t % HID;
    h[t] = x[n * 3 + 0] * ew[c] + x[n * 3 + 1] * ew[HID + c] + x[n * 3 + 2] * ew[2 * HID + c];
}

// ---------------- CSR build ----------------
__global__ void k_hist(const int* __restrict__ ei, int* __restrict__ cnt) {
    int e = blockIdx.x * 256 + threadIdx.x;              // N_EDGES % 256 == 0
    atomicAdd(&cnt[ei[N_EDGES + e]], 1);
}

__global__ void __launch_bounds__(1024) k_scan(const int* __restrict__ cnt, int* __restrict__ off) {
    __shared__ int part[1024];
    int t = threadIdx.x;
    const int PER = 49;                                  // 49*1024 >= 50000
    int base = t * PER;
    int s = 0;
    for (int i = 0; i < PER; i++) { int idx = base + i; if (idx < N_NODES) s += cnt[idx]; }
    part[t] = s;
    __syncthreads();
    for (int d = 1; d < 1024; d <<= 1) {
        int v = (t >= d) ? part[t - d] : 0;
        __syncthreads();
        part[t] += v;
        __syncthreads();
    }
    int run = (t == 0) ? 0 : part[t - 1];
    for (int i = 0; i < PER; i++) {
        int idx = base + i;
        if (idx < N_NODES) { off[idx] = run; run += cnt[idx]; }
    }
    if (t == 1023) off[N_NODES] = part[1023];
}

__global__ void k_scatter(const int* __restrict__ ei, const int* __restrict__ off,
                          int* __restrict__ cur, int* __restrict__ perm) {
    int e = blockIdx.x * 256 + threadIdx.x;
    int d = ei[N_EDGES + e];
    int pos = off[d] + atomicAdd(&cur[d], 1);
    perm[pos] = e;
}

// permute src + precompute per-edge scalars [a0, a1, r2, sh(3)] into sorted order
__global__ void k_permute(const int* __restrict__ ei, const float* __restrict__ ea,
                          const int* __restrict__ perm,
                          int* __restrict__ src_s, float* __restrict__ es_s) {
    int e2 = blockIdx.x * 256 + threadIdx.x;
    int e = perm[e2];
    src_s[e2] = ei[e];
    float a0 = ea[e * 5 + 0], a1 = ea[e * 5 + 1];
    float rx = ea[e * 5 + 2], ry = ea[e * 5 + 3], rz = ea[e * 5 + 4];
    float r2 = rx * rx + ry * ry + rz * rz;
    float inv = rsqrtf(fmaxf(r2, 1e-24f)) * SQRT3;
    float* o = es_s + (size_t)e2 * 6;
    o[0] = a0; o[1] = a1; o[2] = r2;
    o[3] = rx * inv; o[4] = ry * inv; o[5] = rz * inv;
}

// ---------------- phase A: per-edge message (no atomics) ----------------
__global__ void __launch_bounds__(256) k_edge_msg(
    const int* __restrict__ src_s, const float* __restrict__ es_s,
    const float* __restrict__ h, float* __restrict__ msg, int base,
    const float* __restrict__ m1w, const float* __restrict__ m1b,
    const float* __restrict__ m2w, const float* __restrict__ m2b,
    const float* __restrict__ tpw)
{
    __shared__ float s_m1w[48];
    __shared__ float s_m1b[16];
    __shared__ float s_m2w[768];
    __shared__ float s_m2b[48];
    __shared__ float s_tpw[256];
    for (int i = threadIdx.x; i < 48;  i += 256) s_m1w[i] = m1w[i];
    for (int i = threadIdx.x; i < 16;  i += 256) s_m1b[i] = m1b[i];
    for (int i = threadIdx.x; i < 768; i += 256) s_m2w[i] = m2w[i];
    for (int i = threadIdx.x; i < 48;  i += 256) s_m2b[i] = m2b[i];
    for (int i = threadIdx.x; i < 256; i += 256) s_tpw[i] = tpw[i];
    __syncthreads();

    int e2 = base + blockIdx.x * 256 + threadIdx.x;
    const float* es = es_s + (size_t)e2 * 6;
    float a0 = es[0], a1 = es[1], r2 = es[2];
    float shx = es[3], shy = es[4], shz = es[5];
    int src = src_s[e2];

    float hid[16];
#pragma unroll
    for (int j = 0; j < 16; j++) {
        float z = fmaf(a0, s_m1w[j], fmaf(a1, s_m1w[16 + j], fmaf(r2, s_m1w[32 + j], s_m1b[j])));
        hid[j] = z / (1.f + __expf(-z));
    }

    float xj[48];
    const float4* hv = (const float4*)(h + (size_t)src * HID);
#pragma unroll
    for (int q = 0; q < 12; q++) {
        float4 t = hv[q];
        xj[q * 4 + 0] = t.x; xj[q * 4 + 1] = t.y; xj[q * 4 + 2] = t.z; xj[q * 4 + 3] = t.w;
    }

    float cr[48];
#pragma unroll
    for (int u = 0; u < 16; u++) {
        float x0 = xj[u * 3 + 0], x1 = xj[u * 3 + 1], x2 = xj[u * 3 + 2];
        cr[u * 3 + 0] = x1 * shz - x2 * shy;
        cr[u * 3 + 1] = x2 * shx - x0 * shz;
        cr[u * 3 + 2] = x0 * shy - x1 * shx;
    }

    float m[48];
#pragma unroll
    for (int v = 0; v < 16; v++) {
        float t0 = 0.f, t1 = 0.f, t2 = 0.f;
#pragma unroll
        for (int u = 0; u < 16; u++) {
            float w = s_tpw[u * 16 + v];
            t0 = fmaf(w, cr[u * 3 + 0], t0);
            t1 = fmaf(w, cr[u * 3 + 1], t1);
            t2 = fmaf(w, cr[u * 3 + 2], t2);
        }
        float g0 = s_m2b[v * 3 + 0], g1 = s_m2b[v * 3 + 1], g2 = s_m2b[v * 3 + 2];
#pragma unroll
        for (int j = 0; j < 16; j++) {
            float hj = hid[j];
            g0 = fmaf(hj, s_m2w[j * 48 + v * 3 + 0], g0);
            g1 = fmaf(hj, s_m2w[j * 48 + v * 3 + 1], g1);
            g2 = fmaf(hj, s_m2w[j * 48 + v * 3 + 2], g2);
        }
        m[v * 3 + 0] = g0 * t0 * TP_NORM;
        m[v * 3 + 1] = g1 * t1 * TP_NORM;
        m[v * 3 + 2] = g2 * t2 * TP_NORM;
    }

    float4* mo = (float4*)(msg + (size_t)(e2 - base) * HID);
#pragma unroll
    for (int q = 0; q < 12; q++)
        mo[q] = make_float4(m[q * 4 + 0], m[q * 4 + 1], m[q * 4 + 2], m[q * 4 + 3]);
}

// ---------------- phase B: wave-per-node contiguous gather into dx ----------------
// dx (not h!) so later chunks' k_edge_msg still read the frozen layer-input h.
// Chunks are serialized on the stream, so plain += on dx is race-free.
__global__ void __launch_bounds__(256) k_gather(
    const float* __restrict__ msg, const int* __restrict__ off,
    float* __restrict__ dx, int base, int chEnd)
{
    int t = blockIdx.x * 256 + threadIdx.x;
    int node = t >> 6;
    int lane = t & 63;
    if (node >= N_NODES) return;
    int lo = off[node], hi = off[node + 1];
    if (lo < base) lo = base;
    if (hi > chEnd) hi = chEnd;
    if (lo >= hi || lane >= HID) return;
    float acc = 0.f;
    const float* mp = msg + (size_t)(lo - base) * HID + lane;
    int j = lo;
    for (; j + 1 < hi; j += 2, mp += 2 * HID) acc += mp[0] + mp[HID];
    if (j < hi) acc += mp[0];
    dx[(size_t)node * HID + lane] += acc;
}

// ---------------- h += dx; dx = 0 ----------------
__global__ void k_add(float* __restrict__ h, float* __restrict__ dx) {
    int t = blockIdx.x * blockDim.x + threadIdx.x;
    if (t >= N_NODES * HID) return;
    h[t] += dx[t];
    dx[t] = 0.f;
}

// ---------------- pool ----------------
__global__ void __launch_bounds__(256) k_pool(
    const float* __restrict__ h, const int* __restrict__ batch,
    const float* __restrict__ linw, float* __restrict__ gsum, float* __restrict__ gcnt)
{
    __shared__ float ss[N_GRAPHS];
    __shared__ float sc[N_GRAPHS];
    for (int i = threadIdx.x; i < N_GRAPHS; i += 256) { ss[i] = 0.f; sc[i] = 0.f; }
    __syncthreads();
    int n = blockIdx.x * 256 + threadIdx.x;
    if (n < N_NODES) {
        float s = 0.f;
        const float4* hv = (const float4*)(h + (size_t)n * HID);
#pragma unroll
        for (int q = 0; q < 12; q++) {
            float4 t = hv[q];
            s += t.x * linw[q * 4 + 0] + t.y * linw[q * 4 + 1]
               + t.z * linw[q * 4 + 2] + t.w * linw[q * 4 + 3];
        }
        int b = batch[n];
        atomicAdd(&ss[b], s);
        atomicAdd(&sc[b], 1.f);
    }
    __syncthreads();
    for (int i = threadIdx.x; i < N_GRAPHS; i += 256) {
        if (sc[i] != 0.f) {
            atomicAdd(&gsum[i], ss[i]);
            atomicAdd(&gcnt[i], sc[i]);
        }
    }
}

__global__ void k_final(const float* __restrict__ gsum, const float* __restrict__ gcnt,
                        const float* __restrict__ linb, float* __restrict__ out) {
    int g = threadIdx.x;
    if (g < N_GRAPHS) out[g] = gsum[g] / fmaxf(gcnt[g], 1.f) + linb[0];
}

// ---------------- fallback (round-1 proven atomic path) ----------------
__global__ void __launch_bounds__(256) k_edge_atomic(
    const int* __restrict__ ei, const float* __restrict__ ea,
    const float* __restrict__ h, float* __restrict__ dx,
    const float* __restrict__ m1w, const float* __restrict__ m1b,
    const float* __restrict__ m2w, const float* __restrict__ m2b,
    const float* __restrict__ tpw)
{
    __shared__ float s_m1w[48];
    __shared__ float s_m1b[16];
    __shared__ float s_m2w[768];
    __shared__ float s_m2b[48];
    __shared__ float s_tpw[256];
    for (int i = threadIdx.x; i < 48;  i += 256) s_m1w[i] = m1w[i];
    for (int i = threadIdx.x; i < 16;  i += 256) s_m1b[i] = m1b[i];
    for (int i = threadIdx.x; i < 768; i += 256) s_m2w[i] = m2w[i];
    for (int i = threadIdx.x; i < 48;  i += 256) s_m2b[i] = m2b[i];
    for (int i = threadIdx.x; i < 256; i += 256) s_tpw[i] = tpw[i];
    __syncthreads();
    int e = blockIdx.x * 256 + threadIdx.x;
    int src = ei[e];
    int dst = ei[N_EDGES + e];
    float a0 = ea[e * 5 + 0], a1 = ea[e * 5 + 1];
    float rx = ea[e * 5 + 2], ry = ea[e * 5 + 3], rz = ea[e * 5 + 4];
    float r2 = rx * rx + ry * ry + rz * rz;
    float inv = rsqrtf(fmaxf(r2, 1e-24f));
    float shx = SQRT3 * rx * inv, shy = SQRT3 * ry * inv, shz = SQRT3 * rz * inv;
    float hid[16];
#pragma unroll
    for (int j = 0; j < 16; j++) {
        float z = a0 * s_m1w[j] + a1 * s_m1w[16 + j] + r2 * s_m1w[32 + j] + s_m1b[j];
        hid[j] = z / (1.f + __expf(-z));
    }
    float xj[48];
    const float4* hv = (const float4*)(h + (size_t)src * HID);
#pragma unroll
    for (int q = 0; q < 12; q++) {
        float4 t = hv[q];
        xj[q * 4 + 0] = t.x; xj[q * 4 + 1] = t.y; xj[q * 4 + 2] = t.z; xj[q * 4 + 3] = t.w;
    }
    float cr[48];
#pragma unroll
    for (int u = 0; u < 16; u++) {
        float x0 = xj[u * 3 + 0], x1 = xj[u * 3 + 1], x2 = xj[u * 3 + 2];
        cr[u * 3 + 0] = x1 * shz - x2 * shy;
        cr[u * 3 + 1] = x2 * shx - x0 * shz;
        cr[u * 3 + 2] = x0 * shy - x1 * shx;
    }
    float* dd = dx + (size_t)dst * HID;
#pragma unroll
    for (int v = 0; v < 16; v++) {
        float t0 = 0.f, t1 = 0.f, t2 = 0.f;
#pragma unroll
        for (int u = 0; u < 16; u++) {
            float w = s_tpw[u * 16 + v];
            t0 += w * cr[u * 3 + 0];
            t1 += w * cr[u * 3 + 1];
            t2 += w * cr[u * 3 + 2];
        }
        float g0 = s_m2b[v * 3 + 0], g1 = s_m2b[v * 3 + 1], g2 = s_m2b[v * 3 + 2];
#pragma unroll
        for (int j = 0; j < 16; j++) {
            float hj = hid[j];
            g0 = fmaf(hj, s_m2w[j * 48 + v * 3 + 0], g0);
            g1 = fmaf(hj, s_m2w[j * 48 + v * 3 + 1], g1);
            g2 = fmaf(hj, s_m2w[j * 48 + v * 3 + 2], g2);
        }
        atomicAdd(dd + v * 3 + 0, g0 * t0 * TP_NORM);
        atomicAdd(dd + v * 3 + 1, g1 * t1 * TP_NORM);
        atomicAdd(dd + v * 3 + 2, g2 * t2 * TP_NORM);
    }
}

extern "C" void kernel_launch(void* const* d_in, const int* in_sizes, int n_in,
                              void* d_out, int out_size, void* d_ws, size_t ws_size,
                              hipStream_t stream) {
    const float* x    = (const float*)d_in[0];
    const int*   ei   = (const int*)  d_in[1];
    const float* ea   = (const float*)d_in[2];
    const int*   batch= (const int*)  d_in[3];
    const float* ew   = (const float*)d_in[4];
    const float* m1w  = (const float*)d_in[5];
    const float* m1b  = (const float*)d_in[6];
    const float* m2w  = (const float*)d_in[7];
    const float* m2b  = (const float*)d_in[8];
    const float* tpw  = (const float*)d_in[9];
    const float* linw = (const float*)d_in[10];
    const float* linb = (const float*)d_in[11];
    float* out = (float*)d_out;

    // -------- workspace layout (256B-aligned carve) --------
    char* w = (char*)d_ws;
    auto alloc = [&](size_t bytes) -> char* {
        char* p = w;
        w += (bytes + 255) & ~(size_t)255;
        return p;
    };
    float* h    = (float*)alloc((size_t)N_NODES * HID * 4);
    float* dx   = (float*)alloc((size_t)N_NODES * HID * 4);
    float* gbuf = (float*)alloc(2 * N_GRAPHS * 4);
    int*   src_s= (int*)  alloc((size_t)N_EDGES * 4);
    float* es_s = (float*)alloc((size_t)N_EDGES * 6 * 4);
    int*   off  = (int*)  alloc((size_t)(N_NODES + 1) * 4);
    char*  msgA = w;                                   // remainder: msg buffer (+ setup aliases)
    size_t used = (size_t)(msgA - (char*)d_ws);
    size_t rest = (ws_size > used) ? (ws_size - used) : 0;
    float* gsum = gbuf;
    float* gcnt = gbuf + N_GRAPHS;

    size_t setup_need = (size_t)(2 * N_NODES + N_EDGES) * 4;   // cnt + cur + perm alias in msgA
    long long ch = (long long)(rest / (HID * 4));
    ch = (ch / 256) * 256;
    if (ch > N_EDGES) ch = N_EDGES;

    if (rest < setup_need || ch < 256) {
        // -------- fallback: round-1 atomic path (needs 19.2MB + 512B) --------
        float* fh   = (float*)d_ws;
        float* fdx  = fh + (size_t)N_NODES * HID;
        float* fgs  = fdx + (size_t)N_NODES * HID;
        float* fgc  = fgs + N_GRAPHS;
        hipMemsetAsync(fdx, 0, ((size_t)N_NODES * HID + 2 * N_GRAPHS) * sizeof(float), stream);
        k_embed<<<(N_NODES * HID + 255) / 256, 256, 0, stream>>>(x, ew, fh);
        for (int l = 0; l < N_LAYERS; l++) {
            k_edge_atomic<<<N_EDGES / 256, 256, 0, stream>>>(ei, ea, fh, fdx,
                m1w + l * 48, m1b + l * 16, m2w + l * 768, m2b + l * 48, tpw + l * 256);
            k_add<<<(N_NODES * HID + 255) / 256, 256, 0, stream>>>(fh, fdx);
        }
        k_pool<<<(N_NODES + 255) / 256, 256, 0, stream>>>(fh, batch, linw, fgs, fgc);
        k_final<<<1, 64, 0, stream>>>(fgs, fgc, linb, out);
        return;
    }

    // -------- CSR setup (aliased into msg area; runs before any msg write) --------
    int* cnt  = (int*)msgA;
    int* cur  = cnt + N_NODES;
    int* perm = cur + N_NODES;
    hipMemsetAsync(cnt, 0, (size_t)2 * N_NODES * 4, stream);
    hipMemsetAsync(gbuf, 0, 2 * N_GRAPHS * 4, stream);
    hipMemsetAsync(dx, 0, (size_t)N_NODES * HID * 4, stream);   // k_add re-zeroes per layer
    k_hist<<<N_EDGES / 256, 256, 0, stream>>>(ei, cnt);
    k_scan<<<1, 1024, 0, stream>>>(cnt, off);
    k_scatter<<<N_EDGES / 256, 256, 0, stream>>>(ei, off, cur, perm);
    k_permute<<<N_EDGES / 256, 256, 0, stream>>>(ei, ea, perm, src_s, es_s);

    k_embed<<<(N_NODES * HID + 255) / 256, 256, 0, stream>>>(x, ew, h);

    float* msg = (float*)msgA;
    const int gatherBlocks = (N_NODES * 64 + 255) / 256;
    for (int l = 0; l < N_LAYERS; l++) {
        for (long long b = 0; b < N_EDGES; b += ch) {
            long long remain = (long long)N_EDGES - b;
            int cb = (int)(remain < ch ? remain : ch);
            k_edge_msg<<<cb / 256, 256, 0, stream>>>(src_s, es_s, h, msg, (int)b,
                m1w + l * 48, m1b + l * 16, m2w + l * 768, m2b + l * 48, tpw + l * 256);
            k_gather<<<gatherBlocks, 256, 0, stream>>>(msg, off, dx, (int)b, (int)(b + cb));
        }
        k_add<<<(N_NODES * HID + 255) / 256, 256, 0, stream>>>(h, dx);
    }

    k_pool<<<(N_NODES + 255) / 256, 256, 0, stream>>>(h, batch, linw, gsum, gcnt);
    k_final<<<1, 64, 0, stream>>>(gsum, gcnt, linb, out);
}

// Round 4
// 1410.350 us; speedup vs baseline: 11.1639x; 1.0106x over previous
//
#include <hip/hip_runtime.h>

#define N_NODES 50000
#define N_EDGES 1600000
#define N_LAYERS 4
#define N_CH 16
#define HID 48            // N_CH * 3
#define N_GRAPHS 64
#define TP_NORM 0.17677669529663687f   // 1/sqrt(2*N_CH)
#define SQRT3 1.7320508075688772f
#define REB 256           // edges per block in fused kernel
#define MPAD 52           // LDS row stride (floats): conflict-minimum for b128

// ---------------- embed: h = x @ embed_w ----------------
__global__ void k_embed(const float* __restrict__ x, const float* __restrict__ ew,
                        float* __restrict__ h) {
    int t = blockIdx.x * blockDim.x + threadIdx.x;
    if (t >= N_NODES * HID) return;
    int n = t / HID, c = t % HID;
    h[t] = x[n * 3 + 0] * ew[c] + x[n * 3 + 1] * ew[HID + c] + x[n * 3 + 2] * ew[2 * HID + c];
}

// ---------------- CSR build ----------------
__global__ void k_hist(const int* __restrict__ ei, int* __restrict__ cnt) {
    int e = blockIdx.x * 256 + threadIdx.x;              // N_EDGES % 256 == 0
    atomicAdd(&cnt[ei[N_EDGES + e]], 1);
}

__global__ void __launch_bounds__(1024) k_scan(const int* __restrict__ cnt, int* __restrict__ off) {
    __shared__ int part[1024];
    int t = threadIdx.x;
    const int PER = 49;                                  // 49*1024 >= 50000
    int base = t * PER;
    int s = 0;
    for (int i = 0; i < PER; i++) { int idx = base + i; if (idx < N_NODES) s += cnt[idx]; }
    part[t] = s;
    __syncthreads();
    for (int d = 1; d < 1024; d <<= 1) {
        int v = (t >= d) ? part[t - d] : 0;
        __syncthreads();
        part[t] += v;
        __syncthreads();
    }
    int run = (t == 0) ? 0 : part[t - 1];
    for (int i = 0; i < PER; i++) {
        int idx = base + i;
        if (idx < N_NODES) { off[idx] = run; run += cnt[idx]; }
    }
    if (t == 1023) off[N_NODES] = part[1023];
}

__global__ void k_scatter(const int* __restrict__ ei, const int* __restrict__ off,
                          int* __restrict__ cur, int* __restrict__ perm) {
    int e = blockIdx.x * 256 + threadIdx.x;
    int d = ei[N_EDGES + e];
    int pos = off[d] + atomicAdd(&cur[d], 1);
    perm[pos] = e;
}

// permute src/dst + precompute per-edge scalars [a0, a1, r2, sh(3)] into sorted order
__global__ void k_permute(const int* __restrict__ ei, const float* __restrict__ ea,
                          const int* __restrict__ perm,
                          int* __restrict__ src_s, int* __restrict__ dst_s,
                          float* __restrict__ es_s) {
    int e2 = blockIdx.x * 256 + threadIdx.x;
    int e = perm[e2];
    src_s[e2] = ei[e];
    dst_s[e2] = ei[N_EDGES + e];
    float a0 = ea[e * 5 + 0], a1 = ea[e * 5 + 1];
    float rx = ea[e * 5 + 2], ry = ea[e * 5 + 3], rz = ea[e * 5 + 4];
    float r2 = rx * rx + ry * ry + rz * rz;
    float inv = rsqrtf(fmaxf(r2, 1e-24f)) * SQRT3;
    float* o = es_s + (size_t)e2 * 6;
    o[0] = a0; o[1] = a1; o[2] = r2;
    o[3] = rx * inv; o[4] = ry * inv; o[5] = rz * inv;
}

// ---------------- fused: message compute + in-LDS segmented reduce -> dx ----------------
__global__ void __launch_bounds__(256) k_fused(
    const int* __restrict__ src_s, const int* __restrict__ dst_s,
    const float* __restrict__ es_s, const int* __restrict__ off,
    const float* __restrict__ h, float* __restrict__ dx,
    const float* __restrict__ m1w, const float* __restrict__ m1b,
    const float* __restrict__ m2w, const float* __restrict__ m2b,
    const float* __restrict__ tpw)
{
    __shared__ float s_m1w[48];
    __shared__ float s_m1b[16];
    __shared__ float s_m2w[768];
    __shared__ float s_m2b[48];
    __shared__ float s_tpw[256];
    __shared__ float s_msg[REB][MPAD];
    __shared__ int s_n0, s_n1;

    int t = threadIdx.x;
    for (int i = t; i < 48;  i += 256) s_m1w[i] = m1w[i];
    for (int i = t; i < 16;  i += 256) s_m1b[i] = m1b[i];
    for (int i = t; i < 768; i += 256) s_m2w[i] = m2w[i];
    for (int i = t; i < 48;  i += 256) s_m2b[i] = m2b[i];
    for (int i = t; i < 256; i += 256) s_tpw[i] = tpw[i];

    int base = blockIdx.x * REB;
    int e2 = base + t;
    if (t == 0)       s_n0 = dst_s[base];
    if (t == REB - 1) s_n1 = dst_s[base + REB - 1];
    __syncthreads();

    // ---- per-edge message (registers) ----
    const float* es = es_s + (size_t)e2 * 6;
    float a0 = es[0], a1 = es[1], r2 = es[2];
    float shx = es[3], shy = es[4], shz = es[5];
    int src = src_s[e2];

    float hid[16];
#pragma unroll
    for (int j = 0; j < 16; j++) {
        float z = fmaf(a0, s_m1w[j], fmaf(a1, s_m1w[16 + j], fmaf(r2, s_m1w[32 + j], s_m1b[j])));
        hid[j] = z / (1.f + __expf(-z));
    }

    float xj[48];
    const float4* hv = (const float4*)(h + (size_t)src * HID);
#pragma unroll
    for (int q = 0; q < 12; q++) {
        float4 v = hv[q];
        xj[q * 4 + 0] = v.x; xj[q * 4 + 1] = v.y; xj[q * 4 + 2] = v.z; xj[q * 4 + 3] = v.w;
    }

    float cr[48];
#pragma unroll
    for (int u = 0; u < 16; u++) {
        float x0 = xj[u * 3 + 0], x1 = xj[u * 3 + 1], x2 = xj[u * 3 + 2];
        cr[u * 3 + 0] = x1 * shz - x2 * shy;
        cr[u * 3 + 1] = x2 * shx - x0 * shz;
        cr[u * 3 + 2] = x0 * shy - x1 * shx;
    }

    float m[48];
#pragma unroll
    for (int v = 0; v < 16; v++) {
        float t0 = 0.f, t1 = 0.f, t2 = 0.f;
#pragma unroll
        for (int u = 0; u < 16; u++) {
            float w = s_tpw[u * 16 + v];
            t0 = fmaf(w, cr[u * 3 + 0], t0);
            t1 = fmaf(w, cr[u * 3 + 1], t1);
            t2 = fmaf(w, cr[u * 3 + 2], t2);
        }
        float g0 = s_m2b[v * 3 + 0], g1 = s_m2b[v * 3 + 1], g2 = s_m2b[v * 3 + 2];
#pragma unroll
        for (int j = 0; j < 16; j++) {
            float hj = hid[j];
            g0 = fmaf(hj, s_m2w[j * 48 + v * 3 + 0], g0);
            g1 = fmaf(hj, s_m2w[j * 48 + v * 3 + 1], g1);
            g2 = fmaf(hj, s_m2w[j * 48 + v * 3 + 2], g2);
        }
        m[v * 3 + 0] = g0 * t0 * TP_NORM;
        m[v * 3 + 1] = g1 * t1 * TP_NORM;
        m[v * 3 + 2] = g2 * t2 * TP_NORM;
    }

    float4* row = (float4*)&s_msg[t][0];   // 208B row stride, 16B aligned
#pragma unroll
    for (int q = 0; q < 12; q++)
        row[q] = make_float4(m[q * 4 + 0], m[q * 4 + 1], m[q * 4 + 2], m[q * 4 + 3]);
    __syncthreads();

    // ---- segmented reduce: 12-thread group per node, float4 per thread ----
    int n0 = s_n0, n1 = s_n1;
    if (t < 252) {
        int gid = t / 12;            // 0..20
        int c4  = (t % 12) * 4;      // column group
        for (int nn = n0 + gid; nn <= n1; nn += 21) {
            int lo = off[nn], hi = off[nn + 1];
            int rlo = (lo > base) ? lo - base : 0;
            int rhi = ((hi < base + REB) ? hi : base + REB) - base;
            if (rlo >= rhi) continue;               // zero-degree node in range
            float4 acc = make_float4(0.f, 0.f, 0.f, 0.f);
            for (int r = rlo; r < rhi; r++) {
                float4 v = *(const float4*)&s_msg[r][c4];
                acc.x += v.x; acc.y += v.y; acc.z += v.z; acc.w += v.w;
            }
            float* dp = dx + (size_t)nn * HID + c4;
            bool bnd = (lo < base) || (hi > base + REB);
            if (bnd) {
                atomicAdd(dp + 0, acc.x);
                atomicAdd(dp + 1, acc.y);
                atomicAdd(dp + 2, acc.z);
                atomicAdd(dp + 3, acc.w);
            } else {
                *(float4*)dp = acc;                  // sole writer of this node
            }
        }
    }
}

// ---------------- h += dx; dx = 0 ----------------
__global__ void k_add(float* __restrict__ h, float* __restrict__ dx) {
    int t = blockIdx.x * blockDim.x + threadIdx.x;
    if (t >= N_NODES * HID) return;
    h[t] += dx[t];
    dx[t] = 0.f;
}

// ---------------- pool ----------------
__global__ void __launch_bounds__(256) k_pool(
    const float* __restrict__ h, const int* __restrict__ batch,
    const float* __restrict__ linw, float* __restrict__ gsum, float* __restrict__ gcnt)
{
    __shared__ float ss[N_GRAPHS];
    __shared__ float sc[N_GRAPHS];
    for (int i = threadIdx.x; i < N_GRAPHS; i += 256) { ss[i] = 0.f; sc[i] = 0.f; }
    __syncthreads();
    int n = blockIdx.x * 256 + threadIdx.x;
    if (n < N_NODES) {
        float s = 0.f;
        const float4* hv = (const float4*)(h + (size_t)n * HID);
#pragma unroll
        for (int q = 0; q < 12; q++) {
            float4 v = hv[q];
            s += v.x * linw[q * 4 + 0] + v.y * linw[q * 4 + 1]
               + v.z * linw[q * 4 + 2] + v.w * linw[q * 4 + 3];
        }
        int b = batch[n];
        atomicAdd(&ss[b], s);
        atomicAdd(&sc[b], 1.f);
    }
    __syncthreads();
    for (int i = threadIdx.x; i < N_GRAPHS; i += 256) {
        if (sc[i] != 0.f) {
            atomicAdd(&gsum[i], ss[i]);
            atomicAdd(&gcnt[i], sc[i]);
        }
    }
}

__global__ void k_final(const float* __restrict__ gsum, const float* __restrict__ gcnt,
                        const float* __restrict__ linb, float* __restrict__ out) {
    int g = threadIdx.x;
    if (g < N_GRAPHS) out[g] = gsum[g] / fmaxf(gcnt[g], 1.f) + linb[0];
}

// ---------------- fallback (round-1 proven atomic path) ----------------
__global__ void __launch_bounds__(256) k_edge_atomic(
    const int* __restrict__ ei, const float* __restrict__ ea,
    const float* __restrict__ h, float* __restrict__ dx,
    const float* __restrict__ m1w, const float* __restrict__ m1b,
    const float* __restrict__ m2w, const float* __restrict__ m2b,
    const float* __restrict__ tpw)
{
    __shared__ float s_m1w[48];
    __shared__ float s_m1b[16];
    __shared__ float s_m2w[768];
    __shared__ float s_m2b[48];
    __shared__ float s_tpw[256];
    for (int i = threadIdx.x; i < 48;  i += 256) s_m1w[i] = m1w[i];
    for (int i = threadIdx.x; i < 16;  i += 256) s_m1b[i] = m1b[i];
    for (int i = threadIdx.x; i < 768; i += 256) s_m2w[i] = m2w[i];
    for (int i = threadIdx.x; i < 48;  i += 256) s_m2b[i] = m2b[i];
    for (int i = threadIdx.x; i < 256; i += 256) s_tpw[i] = tpw[i];
    __syncthreads();
    int e = blockIdx.x * 256 + threadIdx.x;
    int src = ei[e];
    int dst = ei[N_EDGES + e];
    float a0 = ea[e * 5 + 0], a1 = ea[e * 5 + 1];
    float rx = ea[e * 5 + 2], ry = ea[e * 5 + 3], rz = ea[e * 5 + 4];
    float r2 = rx * rx + ry * ry + rz * rz;
    float inv = rsqrtf(fmaxf(r2, 1e-24f));
    float shx = SQRT3 * rx * inv, shy = SQRT3 * ry * inv, shz = SQRT3 * rz * inv;
    float hid[16];
#pragma unroll
    for (int j = 0; j < 16; j++) {
        float z = a0 * s_m1w[j] + a1 * s_m1w[16 + j] + r2 * s_m1w[32 + j] + s_m1b[j];
        hid[j] = z / (1.f + __expf(-z));
    }
    float xj[48];
    const float4* hv = (const float4*)(h + (size_t)src * HID);
#pragma unroll
    for (int q = 0; q < 12; q++) {
        float4 v = hv[q];
        xj[q * 4 + 0] = v.x; xj[q * 4 + 1] = v.y; xj[q * 4 + 2] = v.z; xj[q * 4 + 3] = v.w;
    }
    float cr[48];
#pragma unroll
    for (int u = 0; u < 16; u++) {
        float x0 = xj[u * 3 + 0], x1 = xj[u * 3 + 1], x2 = xj[u * 3 + 2];
        cr[u * 3 + 0] = x1 * shz - x2 * shy;
        cr[u * 3 + 1] = x2 * shx - x0 * shz;
        cr[u * 3 + 2] = x0 * shy - x1 * shx;
    }
    float* dd = dx + (size_t)dst * HID;
#pragma unroll
    for (int v = 0; v < 16; v++) {
        float t0 = 0.f, t1 = 0.f, t2 = 0.f;
#pragma unroll
        for (int u = 0; u < 16; u++) {
            float w = s_tpw[u * 16 + v];
            t0 += w * cr[u * 3 + 0];
            t1 += w * cr[u * 3 + 1];
            t2 += w * cr[u * 3 + 2];
        }
        float g0 = s_m2b[v * 3 + 0], g1 = s_m2b[v * 3 + 1], g2 = s_m2b[v * 3 + 2];
#pragma unroll
        for (int j = 0; j < 16; j++) {
            float hj = hid[j];
            g0 = fmaf(hj, s_m2w[j * 48 + v * 3 + 0], g0);
            g1 = fmaf(hj, s_m2w[j * 48 + v * 3 + 1], g1);
            g2 = fmaf(hj, s_m2w[j * 48 + v * 3 + 2], g2);
        }
        atomicAdd(dd + v * 3 + 0, g0 * t0 * TP_NORM);
        atomicAdd(dd + v * 3 + 1, g1 * t1 * TP_NORM);
        atomicAdd(dd + v * 3 + 2, g2 * t2 * TP_NORM);
    }
}

extern "C" void kernel_launch(void* const* d_in, const int* in_sizes, int n_in,
                              void* d_out, int out_size, void* d_ws, size_t ws_size,
                              hipStream_t stream) {
    const float* x    = (const float*)d_in[0];
    const int*   ei   = (const int*)  d_in[1];
    const float* ea   = (const float*)d_in[2];
    const int*   batch= (const int*)  d_in[3];
    const float* ew   = (const float*)d_in[4];
    const float* m1w  = (const float*)d_in[5];
    const float* m1b  = (const float*)d_in[6];
    const float* m2w  = (const float*)d_in[7];
    const float* m2b  = (const float*)d_in[8];
    const float* tpw  = (const float*)d_in[9];
    const float* linw = (const float*)d_in[10];
    const float* linb = (const float*)d_in[11];
    float* out = (float*)d_out;

    // -------- workspace layout (256B-aligned carve) --------
    char* w = (char*)d_ws;
    auto alloc = [&](size_t bytes) -> char* {
        char* p = w;
        w += (bytes + 255) & ~(size_t)255;
        return p;
    };
    float* h    = (float*)alloc((size_t)N_NODES * HID * 4);
    float* dx   = (float*)alloc((size_t)N_NODES * HID * 4);
    float* gbuf = (float*)alloc(2 * N_GRAPHS * 4);
    int*   src_s= (int*)  alloc((size_t)N_EDGES * 4);
    int*   dst_s= (int*)  alloc((size_t)N_EDGES * 4);
    float* es_s = (float*)alloc((size_t)N_EDGES * 6 * 4);
    int*   off  = (int*)  alloc((size_t)(N_NODES + 1) * 4);
    int*   cnt  = (int*)  alloc((size_t)N_NODES * 4);
    int*   cur  = (int*)  alloc((size_t)N_NODES * 4);
    int*   perm = (int*)  alloc((size_t)N_EDGES * 4);
    size_t need = (size_t)(w - (char*)d_ws);
    float* gsum = gbuf;
    float* gcnt = gbuf + N_GRAPHS;

    if (ws_size < need) {
        // -------- fallback: round-1 atomic path (needs 19.2MB + 512B) --------
        float* fh   = (float*)d_ws;
        float* fdx  = fh + (size_t)N_NODES * HID;
        float* fgs  = fdx + (size_t)N_NODES * HID;
        float* fgc  = fgs + N_GRAPHS;
        hipMemsetAsync(fdx, 0, ((size_t)N_NODES * HID + 2 * N_GRAPHS) * sizeof(float), stream);
        k_embed<<<(N_NODES * HID + 255) / 256, 256, 0, stream>>>(x, ew, fh);
        for (int l = 0; l < N_LAYERS; l++) {
            k_edge_atomic<<<N_EDGES / 256, 256, 0, stream>>>(ei, ea, fh, fdx,
                m1w + l * 48, m1b + l * 16, m2w + l * 768, m2b + l * 48, tpw + l * 256);
            k_add<<<(N_NODES * HID + 255) / 256, 256, 0, stream>>>(fh, fdx);
        }
        k_pool<<<(N_NODES + 255) / 256, 256, 0, stream>>>(fh, batch, linw, fgs, fgc);
        k_final<<<1, 64, 0, stream>>>(fgs, fgc, linb, out);
        return;
    }

    // -------- CSR setup --------
    hipMemsetAsync(cnt, 0, (size_t)N_NODES * 4, stream);
    hipMemsetAsync(cur, 0, (size_t)N_NODES * 4, stream);
    hipMemsetAsync(gbuf, 0, 2 * N_GRAPHS * 4, stream);
    hipMemsetAsync(dx, 0, (size_t)N_NODES * HID * 4, stream);   // k_add re-zeroes per layer
    k_hist<<<N_EDGES / 256, 256, 0, stream>>>(ei, cnt);
    k_scan<<<1, 1024, 0, stream>>>(cnt, off);
    k_scatter<<<N_EDGES / 256, 256, 0, stream>>>(ei, off, cur, perm);
    k_permute<<<N_EDGES / 256, 256, 0, stream>>>(ei, ea, perm, src_s, dst_s, es_s);

    k_embed<<<(N_NODES * HID + 255) / 256, 256, 0, stream>>>(x, ew, h);

    for (int l = 0; l < N_LAYERS; l++) {
        k_fused<<<N_EDGES / REB, 256, 0, stream>>>(src_s, dst_s, es_s, off, h, dx,
            m1w + l * 48, m1b + l * 16, m2w + l * 768, m2b + l * 48, tpw + l * 256);
        k_add<<<(N_NODES * HID + 255) / 256, 256, 0, stream>>>(h, dx);
    }

    k_pool<<<(N_NODES + 255) / 256, 256, 0, stream>>>(h, batch, linw, gsum, gcnt);
    k_final<<<1, 64, 0, stream>>>(gsum, gcnt, linb, out);
}

// Round 5
// 898.071 us; speedup vs baseline: 17.5320x; 1.5704x over previous
//
#include <hip/hip_runtime.h>

#define N_NODES 50000
#define N_EDGES 1600000
#define N_LAYERS 4
#define N_CH 16
#define HID 48            // N_CH * 3
#define N_GRAPHS 64
#define TP_NORM 0.17677669529663687f   // 1/sqrt(2*N_CH)
#define SQRT3 1.7320508075688772f
#define REB 256           // edges per block in fused kernel
#define MPAD 28           // LDS row stride (floats) for 24-col half-message

// ---------------- embed: h = x @ embed_w ----------------
__global__ void k_embed(const float* __restrict__ x, const float* __restrict__ ew,
                        float* __restrict__ h) {
    int t = blockIdx.x * blockDim.x + threadIdx.x;
    if (t >= N_NODES * HID) return;
    int n = t / HID, c = t % HID;
    h[t] = x[n * 3 + 0] * ew[c] + x[n * 3 + 1] * ew[HID + c] + x[n * 3 + 2] * ew[2 * HID + c];
}

// ---------------- CSR build ----------------
__global__ void k_hist(const int* __restrict__ ei, int* __restrict__ cnt) {
    int e = blockIdx.x * 256 + threadIdx.x;              // N_EDGES % 256 == 0
    atomicAdd(&cnt[ei[N_EDGES + e]], 1);
}

__global__ void __launch_bounds__(1024) k_scan(const int* __restrict__ cnt, int* __restrict__ off) {
    __shared__ int part[1024];
    int t = threadIdx.x;
    const int PER = 49;                                  // 49*1024 >= 50000
    int base = t * PER;
    int s = 0;
    for (int i = 0; i < PER; i++) { int idx = base + i; if (idx < N_NODES) s += cnt[idx]; }
    part[t] = s;
    __syncthreads();
    for (int d = 1; d < 1024; d <<= 1) {
        int v = (t >= d) ? part[t - d] : 0;
        __syncthreads();
        part[t] += v;
        __syncthreads();
    }
    int run = (t == 0) ? 0 : part[t - 1];
    for (int i = 0; i < PER; i++) {
        int idx = base + i;
        if (idx < N_NODES) { off[idx] = run; run += cnt[idx]; }
    }
    if (t == 1023) off[N_NODES] = part[1023];
}

__global__ void k_scatter(const int* __restrict__ ei, const int* __restrict__ off,
                          int* __restrict__ cur, int* __restrict__ perm) {
    int e = blockIdx.x * 256 + threadIdx.x;
    int d = ei[N_EDGES + e];
    int pos = off[d] + atomicAdd(&cur[d], 1);
    perm[pos] = e;
}

// permute src/dst + precompute per-edge scalars [a0,a1,r2,shx,shy,shz,-,-] stride 8
__global__ void k_permute(const int* __restrict__ ei, const float* __restrict__ ea,
                          const int* __restrict__ perm,
                          int* __restrict__ src_s, int* __restrict__ dst_s,
                          float* __restrict__ es_s) {
    int e2 = blockIdx.x * 256 + threadIdx.x;
    int e = perm[e2];
    src_s[e2] = ei[e];
    dst_s[e2] = ei[N_EDGES + e];
    float a0 = ea[e * 5 + 0], a1 = ea[e * 5 + 1];
    float rx = ea[e * 5 + 2], ry = ea[e * 5 + 3], rz = ea[e * 5 + 4];
    float r2 = rx * rx + ry * ry + rz * rz;
    float inv = rsqrtf(fmaxf(r2, 1e-24f)) * SQRT3;
    float* o = es_s + (size_t)e2 * 8;
    o[0] = a0; o[1] = a1; o[2] = r2; o[3] = rx * inv;
    o[4] = ry * inv; o[5] = rz * inv; o[6] = 0.f; o[7] = 0.f;
}

// ---------------- per-node tpw transform: h2[n,v,i] = sum_u tpw[u,v] hin[n,u,i] ----------------
__global__ void k_h2(const float* __restrict__ hin, const float* __restrict__ tpw,
                     float* __restrict__ h2) {
    int t = blockIdx.x * blockDim.x + threadIdx.x;
    if (t >= N_NODES * HID) return;
    int n = t / HID, c = t % HID, v = c / 3, i = c % 3;
    const float* hr = hin + (size_t)n * HID + i;
    float s = 0.f;
#pragma unroll
    for (int u = 0; u < 16; u++) s = fmaf(tpw[u * 16 + v], hr[u * 3], s);
    h2[t] = s;
}

// same, but input row is (hin + dxin); also writes hout = hin + dxin (fused residual add)
__global__ void k_h2_add(const float* __restrict__ hin, const float* __restrict__ dxin,
                         const float* __restrict__ tpw,
                         float* __restrict__ h2, float* __restrict__ hout) {
    int t = blockIdx.x * blockDim.x + threadIdx.x;
    if (t >= N_NODES * HID) return;
    int n = t / HID, c = t % HID, v = c / 3, i = c % 3;
    size_t rb = (size_t)n * HID;
    const float* hr = hin + rb + i;
    const float* dr = dxin + rb + i;
    float s = 0.f;
#pragma unroll
    for (int u = 0; u < 16; u++) s = fmaf(tpw[u * 16 + v], hr[u * 3] + dr[u * 3], s);
    h2[t] = s;
    hout[t] = hin[t] + dxin[t];
}

// ---------------- fused: message compute (2 half-passes) + in-LDS segmented reduce -> dx ----------------
__global__ void __launch_bounds__(256) k_fused(
    const int* __restrict__ src_s, const int* __restrict__ dst_s,
    const float* __restrict__ es_s, const int* __restrict__ off,
    const float* __restrict__ h2, float* __restrict__ dx,
    const float* __restrict__ m1w, const float* __restrict__ m1b,
    const float* __restrict__ m2w, const float* __restrict__ m2b)
{
    __shared__ float s_m1w[48];
    __shared__ float s_m1b[16];
    __shared__ float s_m2w[768];
    __shared__ float s_m2b[48];
    __shared__ float s_msg[REB][MPAD];
    __shared__ int s_n0, s_n1;

    int t = threadIdx.x;
    int base = blockIdx.x * REB;
    int e2 = base + t;

    // early global loads (overlap weight staging)
    const float* esp = es_s + (size_t)e2 * 8;
    float4 es0 = *(const float4*)esp;          // a0,a1,r2,shx
    float2 es1 = *(const float2*)(esp + 4);    // shy,shz
    int src = src_s[e2];

    for (int i = t; i < 48;  i += 256) s_m1w[i] = m1w[i];
    for (int i = t; i < 16;  i += 256) s_m1b[i] = m1b[i];
    for (int i = t; i < 768; i += 256) s_m2w[i] = m2w[i];
    for (int i = t; i < 48;  i += 256) s_m2b[i] = m2b[i];
    if (t == 0)       s_n0 = dst_s[base];
    if (t == REB - 1) s_n1 = dst_s[base + REB - 1];
    __syncthreads();

    float a0 = es0.x, a1 = es0.y, r2 = es0.z;
    float shx = es0.w, shy = es1.x, shz = es1.y;

    float hid[16];
#pragma unroll
    for (int j = 0; j < 16; j++) {
        float z = fmaf(a0, s_m1w[j], fmaf(a1, s_m1w[16 + j], fmaf(r2, s_m1w[32 + j], s_m1b[j])));
        hid[j] = z / (1.f + __expf(-z));
    }

    const float4* hv = (const float4*)(h2 + (size_t)src * HID);
    int n0 = s_n0, n1 = s_n1;
    int gid = t / 6, q = t % 6;            // reduce mapping: 42 groups x 6 float4-cols

    // ================= PASS A: channels v=0..7 (cols 0..23) =================
    float xj[24];
    ((float4*)xj)[0] = hv[0]; ((float4*)xj)[1] = hv[1]; ((float4*)xj)[2] = hv[2];
    ((float4*)xj)[3] = hv[3]; ((float4*)xj)[4] = hv[4]; ((float4*)xj)[5] = hv[5];

    float m[24];
#pragma unroll
    for (int v = 0; v < 8; v++) {
        float x0 = xj[v * 3 + 0], x1 = xj[v * 3 + 1], x2 = xj[v * 3 + 2];
        float c0 = x1 * shz - x2 * shy;
        float c1 = x2 * shx - x0 * shz;
        float c2 = x0 * shy - x1 * shx;
        int cb = v * 3;
        float g0 = s_m2b[cb], g1 = s_m2b[cb + 1], g2 = s_m2b[cb + 2];
#pragma unroll
        for (int j = 0; j < 16; j++) {
            float hj = hid[j];
            g0 = fmaf(hj, s_m2w[j * 48 + cb + 0], g0);
            g1 = fmaf(hj, s_m2w[j * 48 + cb + 1], g1);
            g2 = fmaf(hj, s_m2w[j * 48 + cb + 2], g2);
        }
        m[cb + 0] = g0 * c0 * TP_NORM;
        m[cb + 1] = g1 * c1 * TP_NORM;
        m[cb + 2] = g2 * c2 * TP_NORM;
    }
    {
        float4* row = (float4*)&s_msg[t][0];
#pragma unroll
        for (int qq = 0; qq < 6; qq++) row[qq] = ((float4*)m)[qq];
    }
    // issue pass-B gather now (latency hides under reduce A)
    ((float4*)xj)[0] = hv[6];  ((float4*)xj)[1] = hv[7];  ((float4*)xj)[2] = hv[8];
    ((float4*)xj)[3] = hv[9];  ((float4*)xj)[4] = hv[10]; ((float4*)xj)[5] = hv[11];
    __syncthreads();

    if (t < 252) {
        for (int nn = n0 + gid; nn <= n1; nn += 42) {
            int lo = off[nn], hi = off[nn + 1];
            int rlo = (lo > base) ? lo - base : 0;
            int rhi = ((hi < base + REB) ? hi : base + REB) - base;
            if (rlo >= rhi) continue;
            float4 acc = make_float4(0.f, 0.f, 0.f, 0.f);
            for (int r = rlo; r < rhi; r++) {
                float4 v = *(const float4*)&s_msg[r][q * 4];
                acc.x += v.x; acc.y += v.y; acc.z += v.z; acc.w += v.w;
            }
            float* dp = dx + (size_t)nn * HID + q * 4;
            if (lo < base || hi > base + REB) {
                atomicAdd(dp + 0, acc.x); atomicAdd(dp + 1, acc.y);
                atomicAdd(dp + 2, acc.z); atomicAdd(dp + 3, acc.w);
            } else {
                *(float4*)dp = acc;
            }
        }
    }
    __syncthreads();

    // ================= PASS B: channels v=8..15 (cols 24..47) =================
#pragma unroll
    for (int v = 0; v < 8; v++) {
        float x0 = xj[v * 3 + 0], x1 = xj[v * 3 + 1], x2 = xj[v * 3 + 2];
        float c0 = x1 * shz - x2 * shy;
        float c1 = x2 * shx - x0 * shz;
        float c2 = x0 * shy - x1 * shx;
        int cb = v * 3;
        int col = 24 + cb;
        float g0 = s_m2b[col], g1 = s_m2b[col + 1], g2 = s_m2b[col + 2];
#pragma unroll
        for (int j = 0; j < 16; j++) {
            float hj = hid[j];
            g0 = fmaf(hj, s_m2w[j * 48 + col + 0], g0);
            g1 = fmaf(hj, s_m2w[j * 48 + col + 1], g1);
            g2 = fmaf(hj, s_m2w[j * 48 + col + 2], g2);
        }
        m[cb + 0] = g0 * c0 * TP_NORM;
        m[cb + 1] = g1 * c1 * TP_NORM;
        m[cb + 2] = g2 * c2 * TP_NORM;
    }
    {
        float4* row = (float4*)&s_msg[t][0];
#pragma unroll
        for (int qq = 0; qq < 6; qq++) row[qq] = ((float4*)m)[qq];
    }
    __syncthreads();

    if (t < 252) {
        for (int nn = n0 + gid; nn <= n1; nn += 42) {
            int lo = off[nn], hi = off[nn + 1];
            int rlo = (lo > base) ? lo - base : 0;
            int rhi = ((hi < base + REB) ? hi : base + REB) - base;
            if (rlo >= rhi) continue;
            float4 acc = make_float4(0.f, 0.f, 0.f, 0.f);
            for (int r = rlo; r < rhi; r++) {
                float4 v = *(const float4*)&s_msg[r][q * 4];
                acc.x += v.x; acc.y += v.y; acc.z += v.z; acc.w += v.w;
            }
            float* dp = dx + (size_t)nn * HID + 24 + q * 4;
            if (lo < base || hi > base + REB) {
                atomicAdd(dp + 0, acc.x); atomicAdd(dp + 1, acc.y);
                atomicAdd(dp + 2, acc.z); atomicAdd(dp + 3, acc.w);
            } else {
                *(float4*)dp = acc;
            }
        }
    }
}

// ---------------- h += dx; dx = 0 (fallback path only) ----------------
__global__ void k_add(float* __restrict__ h, float* __restrict__ dx) {
    int t = blockIdx.x * blockDim.x + threadIdx.x;
    if (t >= N_NODES * HID) return;
    h[t] += dx[t];
    dx[t] = 0.f;
}

// ---------------- pool: per-graph mean of ((h+dx) @ lin_w) ----------------
__global__ void __launch_bounds__(256) k_pool(
    const float* __restrict__ h, const float* __restrict__ dxin, const int* __restrict__ batch,
    const float* __restrict__ linw, float* __restrict__ gsum, float* __restrict__ gcnt)
{
    __shared__ float ss[N_GRAPHS];
    __shared__ float sc[N_GRAPHS];
    for (int i = threadIdx.x; i < N_GRAPHS; i += 256) { ss[i] = 0.f; sc[i] = 0.f; }
    __syncthreads();
    int n = blockIdx.x * 256 + threadIdx.x;
    if (n < N_NODES) {
        float s = 0.f;
        const float4* hv = (const float4*)(h + (size_t)n * HID);
        const float4* dv = (const float4*)(dxin + (size_t)n * HID);
#pragma unroll
        for (int qq = 0; qq < 12; qq++) {
            float4 v = hv[qq], d = dv[qq];
            s += (v.x + d.x) * linw[qq * 4 + 0] + (v.y + d.y) * linw[qq * 4 + 1]
               + (v.z + d.z) * linw[qq * 4 + 2] + (v.w + d.w) * linw[qq * 4 + 3];
        }
        int b = batch[n];
        atomicAdd(&ss[b], s);
        atomicAdd(&sc[b], 1.f);
    }
    __syncthreads();
    for (int i = threadIdx.x; i < N_GRAPHS; i += 256) {
        if (sc[i] != 0.f) {
            atomicAdd(&gsum[i], ss[i]);
            atomicAdd(&gcnt[i], sc[i]);
        }
    }
}

__global__ void k_final(const float* __restrict__ gsum, const float* __restrict__ gcnt,
                        const float* __restrict__ linb, float* __restrict__ out) {
    int g = threadIdx.x;
    if (g < N_GRAPHS) out[g] = gsum[g] / fmaxf(gcnt[g], 1.f) + linb[0];
}

// ---------------- fallback (round-1 proven atomic path) ----------------
__global__ void __launch_bounds__(256) k_edge_atomic(
    const int* __restrict__ ei, const float* __restrict__ ea,
    const float* __restrict__ h, float* __restrict__ dx,
    const float* __restrict__ m1w, const float* __restrict__ m1b,
    const float* __restrict__ m2w, const float* __restrict__ m2b,
    const float* __restrict__ tpw)
{
    __shared__ float s_m1w[48];
    __shared__ float s_m1b[16];
    __shared__ float s_m2w[768];
    __shared__ float s_m2b[48];
    __shared__ float s_tpw[256];
    for (int i = threadIdx.x; i < 48;  i += 256) s_m1w[i] = m1w[i];
    for (int i = threadIdx.x; i < 16;  i += 256) s_m1b[i] = m1b[i];
    for (int i = threadIdx.x; i < 768; i += 256) s_m2w[i] = m2w[i];
    for (int i = threadIdx.x; i < 48;  i += 256) s_m2b[i] = m2b[i];
    for (int i = threadIdx.x; i < 256; i += 256) s_tpw[i] = tpw[i];
    __syncthreads();
    int e = blockIdx.x * 256 + threadIdx.x;
    int src = ei[e];
    int dst = ei[N_EDGES + e];
    float a0 = ea[e * 5 + 0], a1 = ea[e * 5 + 1];
    float rx = ea[e * 5 + 2], ry = ea[e * 5 + 3], rz = ea[e * 5 + 4];
    float r2 = rx * rx + ry * ry + rz * rz;
    float inv = rsqrtf(fmaxf(r2, 1e-24f));
    float shx = SQRT3 * rx * inv, shy = SQRT3 * ry * inv, shz = SQRT3 * rz * inv;
    float hid[16];
#pragma unroll
    for (int j = 0; j < 16; j++) {
        float z = a0 * s_m1w[j] + a1 * s_m1w[16 + j] + r2 * s_m1w[32 + j] + s_m1b[j];
        hid[j] = z / (1.f + __expf(-z));
    }
    float xj[48];
    const float4* hv = (const float4*)(h + (size_t)src * HID);
#pragma unroll
    for (int qq = 0; qq < 12; qq++) {
        float4 v = hv[qq];
        xj[qq * 4 + 0] = v.x; xj[qq * 4 + 1] = v.y; xj[qq * 4 + 2] = v.z; xj[qq * 4 + 3] = v.w;
    }
    float cr[48];
#pragma unroll
    for (int u = 0; u < 16; u++) {
        float x0 = xj[u * 3 + 0], x1 = xj[u * 3 + 1], x2 = xj[u * 3 + 2];
        cr[u * 3 + 0] = x1 * shz - x2 * shy;
        cr[u * 3 + 1] = x2 * shx - x0 * shz;
        cr[u * 3 + 2] = x0 * shy - x1 * shx;
    }
    float* dd = dx + (size_t)dst * HID;
#pragma unroll
    for (int v = 0; v < 16; v++) {
        float t0 = 0.f, t1 = 0.f, t2 = 0.f;
#pragma unroll
        for (int u = 0; u < 16; u++) {
            float w = s_tpw[u * 16 + v];
            t0 += w * cr[u * 3 + 0];
            t1 += w * cr[u * 3 + 1];
            t2 += w * cr[u * 3 + 2];
        }
        float g0 = s_m2b[v * 3 + 0], g1 = s_m2b[v * 3 + 1], g2 = s_m2b[v * 3 + 2];
#pragma unroll
        for (int j = 0; j < 16; j++) {
            float hj = hid[j];
            g0 = fmaf(hj, s_m2w[j * 48 + v * 3 + 0], g0);
            g1 = fmaf(hj, s_m2w[j * 48 + v * 3 + 1], g1);
            g2 = fmaf(hj, s_m2w[j * 48 + v * 3 + 2], g2);
        }
        atomicAdd(dd + v * 3 + 0, g0 * t0 * TP_NORM);
        atomicAdd(dd + v * 3 + 1, g1 * t1 * TP_NORM);
        atomicAdd(dd + v * 3 + 2, g2 * t2 * TP_NORM);
    }
}

extern "C" void kernel_launch(void* const* d_in, const int* in_sizes, int n_in,
                              void* d_out, int out_size, void* d_ws, size_t ws_size,
                              hipStream_t stream) {
    const float* x    = (const float*)d_in[0];
    const int*   ei   = (const int*)  d_in[1];
    const float* ea   = (const float*)d_in[2];
    const int*   batch= (const int*)  d_in[3];
    const float* ew   = (const float*)d_in[4];
    const float* m1w  = (const float*)d_in[5];
    const float* m1b  = (const float*)d_in[6];
    const float* m2w  = (const float*)d_in[7];
    const float* m2b  = (const float*)d_in[8];
    const float* tpw  = (const float*)d_in[9];
    const float* linw = (const float*)d_in[10];
    const float* linb = (const float*)d_in[11];
    float* out = (float*)d_out;

    // -------- workspace layout (256B-aligned carve) --------
    char* w = (char*)d_ws;
    auto alloc = [&](size_t bytes) -> char* {
        char* p = w;
        w += (bytes + 255) & ~(size_t)255;
        return p;
    };
    float* hA   = (float*)alloc((size_t)N_NODES * HID * 4);
    float* hB   = (float*)alloc((size_t)N_NODES * HID * 4);
    float* h2   = (float*)alloc((size_t)N_NODES * HID * 4);
    float* dx   = (float*)alloc((size_t)N_NODES * HID * 4);
    float* gbuf = (float*)alloc(2 * N_GRAPHS * 4);
    int*   src_s= (int*)  alloc((size_t)N_EDGES * 4);
    int*   dst_s= (int*)  alloc((size_t)N_EDGES * 4);
    float* es_s = (float*)alloc((size_t)N_EDGES * 8 * 4);
    int*   off  = (int*)  alloc((size_t)(N_NODES + 1) * 4);
    int*   cnt  = (int*)  alloc((size_t)N_NODES * 4);
    int*   cur  = (int*)  alloc((size_t)N_NODES * 4);
    int*   perm = (int*)  alloc((size_t)N_EDGES * 4);
    size_t need = (size_t)(w - (char*)d_ws);
    float* gsum = gbuf;
    float* gcnt = gbuf + N_GRAPHS;

    if (ws_size < need) {
        // -------- fallback: round-1 atomic path (needs 19.2MB + 512B) --------
        float* fh   = (float*)d_ws;
        float* fdx  = fh + (size_t)N_NODES * HID;
        float* fgs  = fdx + (size_t)N_NODES * HID;
        float* fgc  = fgs + N_GRAPHS;
        hipMemsetAsync(fdx, 0, ((size_t)N_NODES * HID + 2 * N_GRAPHS) * sizeof(float), stream);
        k_embed<<<(N_NODES * HID + 255) / 256, 256, 0, stream>>>(x, ew, fh);
        for (int l = 0; l < N_LAYERS; l++) {
            k_edge_atomic<<<N_EDGES / 256, 256, 0, stream>>>(ei, ea, fh, fdx,
                m1w + l * 48, m1b + l * 16, m2w + l * 768, m2b + l * 48, tpw + l * 256);
            k_add<<<(N_NODES * HID + 255) / 256, 256, 0, stream>>>(fh, fdx);
        }
        hipMemsetAsync(fdx, 0, (size_t)N_NODES * HID * 4, stream);
        k_pool<<<(N_NODES + 255) / 256, 256, 0, stream>>>(fh, fdx, batch, linw, fgs, fgc);
        k_final<<<1, 64, 0, stream>>>(fgs, fgc, linb, out);
        return;
    }

    // -------- CSR setup --------
    hipMemsetAsync(cnt, 0, (size_t)N_NODES * 4, stream);
    hipMemsetAsync(cur, 0, (size_t)N_NODES * 4, stream);
    hipMemsetAsync(gbuf, 0, 2 * N_GRAPHS * 4, stream);
    k_hist<<<N_EDGES / 256, 256, 0, stream>>>(ei, cnt);
    k_scan<<<1, 1024, 0, stream>>>(cnt, off);
    k_scatter<<<N_EDGES / 256, 256, 0, stream>>>(ei, off, cur, perm);
    k_permute<<<N_EDGES / 256, 256, 0, stream>>>(ei, ea, perm, src_s, dst_s, es_s);

    k_embed<<<(N_NODES * HID + 255) / 256, 256, 0, stream>>>(x, ew, hA);

    const int nhBlocks = (N_NODES * HID + 255) / 256;
    float* hcur = hA;
    float* hnxt = hB;
    for (int l = 0; l < N_LAYERS; l++) {
        if (l == 0) {
            k_h2<<<nhBlocks, 256, 0, stream>>>(hcur, tpw, h2);
        } else {
            // fold previous layer's residual add: hnxt = hcur + dx, h2 = tpw[l]^T (hcur+dx)
            k_h2_add<<<nhBlocks, 256, 0, stream>>>(hcur, dx, tpw + l * 256, h2, hnxt);
            float* tmp = hcur; hcur = hnxt; hnxt = tmp;
        }
        hipMemsetAsync(dx, 0, (size_t)N_NODES * HID * 4, stream);
        k_fused<<<N_EDGES / REB, 256, 0, stream>>>(src_s, dst_s, es_s, off, h2, dx,
            m1w + l * 48, m1b + l * 16, m2w + l * 768, m2b + l * 48);
    }

    // pool over h_final = hcur + dx (last layer's residual folded into pool)
    k_pool<<<(N_NODES + 255) / 256, 256, 0, stream>>>(hcur, dx, batch, linw, gsum, gcnt);
    k_final<<<1, 64, 0, stream>>>(gsum, gcnt, linb, out);
}

// Round 6
// 706.362 us; speedup vs baseline: 22.2902x; 1.2714x over previous
//
#include <hip/hip_runtime.h>

#define N_NODES 50000
#define N_EDGES 1600000
#define N_LAYERS 4
#define N_CH 16
#define HID 48            // N_CH * 3
#define N_GRAPHS 64
#define TP_NORM 0.17677669529663687f   // 1/sqrt(2*N_CH)
#define SQRT3 1.7320508075688772f
#define REB 256           // edges per block in fused kernel
#define MPAD 28           // LDS row stride (floats) for 24-col half-message
#define NBLK (N_EDGES / REB)

// ---------------- embed: h = x @ embed_w ----------------
__global__ void k_embed(const float* __restrict__ x, const float* __restrict__ ew,
                        float* __restrict__ h) {
    int t = blockIdx.x * blockDim.x + threadIdx.x;
    if (t >= N_NODES * HID) return;
    int n = t / HID, c = t % HID;
    h[t] = x[n * 3 + 0] * ew[c] + x[n * 3 + 1] * ew[HID + c] + x[n * 3 + 2] * ew[2 * HID + c];
}

// ---------------- CSR build (single atomic pass) ----------------
// rank[e] = arrival index of edge e among edges with same dst
__global__ void k_count(const int* __restrict__ ei, int* __restrict__ cnt,
                        int* __restrict__ rank) {
    int e = blockIdx.x * 256 + threadIdx.x;              // N_EDGES % 256 == 0
    rank[e] = atomicAdd(&cnt[ei[N_EDGES + e]], 1);
}

__global__ void __launch_bounds__(1024) k_scan(const int* __restrict__ cnt, int* __restrict__ off) {
    __shared__ int part[1024];
    int t = threadIdx.x;
    const int PER = 49;                                  // 49*1024 >= 50000
    int base = t * PER;
    int s = 0;
    for (int i = 0; i < PER; i++) { int idx = base + i; if (idx < N_NODES) s += cnt[idx]; }
    part[t] = s;
    __syncthreads();
    for (int d = 1; d < 1024; d <<= 1) {
        int v = (t >= d) ? part[t - d] : 0;
        __syncthreads();
        part[t] += v;
        __syncthreads();
    }
    int run = (t == 0) ? 0 : part[t - 1];
    for (int i = 0; i < PER; i++) {
        int idx = base + i;
        if (idx < N_NODES) { off[idx] = run; run += cnt[idx]; }
    }
    if (t == 1023) off[N_NODES] = part[1023];
}

// per fused-block node range via binary search (replaces dst_s array)
__global__ void k_rng(const int* __restrict__ off, int* __restrict__ blk) {
    int b = blockIdx.x * blockDim.x + threadIdx.x;
    if (b >= NBLK) return;
    int base = b * REB;
    int lo = 0, hi = N_NODES;
    while (lo < hi) { int mid = (lo + hi + 1) >> 1; if (off[mid] <= base) lo = mid; else hi = mid - 1; }
    blk[2 * b] = lo;
    int last = base + REB - 1;
    int hi2 = N_NODES;
    while (lo < hi2) { int mid = (lo + hi2 + 1) >> 1; if (off[mid] <= last) lo = mid; else hi2 = mid - 1; }
    blk[2 * b + 1] = lo;
}

// sorted 32B record per edge: [a0, a1, r2, shx, shy, shz, src_bits, 0]
__global__ void k_build(const int* __restrict__ ei, const float* __restrict__ ea,
                        const int* __restrict__ off, const int* __restrict__ rank,
                        float* __restrict__ es_s) {
    int e = blockIdx.x * 256 + threadIdx.x;
    int d = ei[N_EDGES + e];
    int pos = off[d] + rank[e];
    float a0 = ea[e * 5 + 0], a1 = ea[e * 5 + 1];
    float rx = ea[e * 5 + 2], ry = ea[e * 5 + 3], rz = ea[e * 5 + 4];
    float r2 = rx * rx + ry * ry + rz * rz;
    float inv = rsqrtf(fmaxf(r2, 1e-24f)) * SQRT3;
    float4* o = (float4*)(es_s + (size_t)pos * 8);
    o[0] = make_float4(a0, a1, r2, rx * inv);
    o[1] = make_float4(ry * inv, rz * inv, __int_as_float(ei[e]), 0.f);
}

// ---------------- per-node tpw transform: h2[n,v,i] = sum_u tpw[u,v] hin[n,u,i] ----------------
// also zeroes dx (needed before k_fused's boundary atomics)
__global__ void k_h2(const float* __restrict__ hin, const float* __restrict__ tpw,
                     float* __restrict__ h2, float* __restrict__ dx) {
    int t = blockIdx.x * blockDim.x + threadIdx.x;
    if (t >= N_NODES * HID) return;
    int n = t / HID, c = t % HID, v = c / 3, i = c % 3;
    const float* hr = hin + (size_t)n * HID + i;
    float s = 0.f;
#pragma unroll
    for (int u = 0; u < 16; u++) s = fmaf(tpw[u * 16 + v], hr[u * 3], s);
    h2[t] = s;
    dx[t] = 0.f;
}

// input row is (hin + dxin); writes hout = hin + dxin (fused residual) and zeroes dxin
__global__ void k_h2_add(const float* __restrict__ hin, float* __restrict__ dxin,
                         const float* __restrict__ tpw,
                         float* __restrict__ h2, float* __restrict__ hout) {
    int t = blockIdx.x * blockDim.x + threadIdx.x;
    if (t >= N_NODES * HID) return;
    int n = t / HID, c = t % HID, v = c / 3, i = c % 3;
    size_t rb = (size_t)n * HID;
    const float* hr = hin + rb + i;
    const float* dr = dxin + rb + i;
    float s = 0.f;
#pragma unroll
    for (int u = 0; u < 16; u++) s = fmaf(tpw[u * 16 + v], hr[u * 3] + dr[u * 3], s);
    h2[t] = s;
    hout[t] = hin[t] + dxin[t];
    dxin[t] = 0.f;
}

// ---------------- fused: message compute (2 half-passes) + in-LDS segmented reduce -> dx ----------------
__global__ void __launch_bounds__(256) k_fused(
    const float* __restrict__ es_s, const int* __restrict__ off,
    const int* __restrict__ blk,
    const float* __restrict__ h2, float* __restrict__ dx,
    const float* __restrict__ m1w, const float* __restrict__ m1b,
    const float* __restrict__ m2w, const float* __restrict__ m2b)
{
    __shared__ float s_m1w[48];
    __shared__ float s_m1b[16];
    __shared__ float s_m2w[768];
    __shared__ float s_m2b[48];
    __shared__ float s_msg[REB][MPAD];

    int t = threadIdx.x;
    int base = blockIdx.x * REB;
    int e2 = base + t;

    // early global loads (overlap weight staging)
    const float4* esp = (const float4*)(es_s + (size_t)e2 * 8);
    float4 es0 = esp[0];                       // a0,a1,r2,shx
    float4 es1 = esp[1];                       // shy,shz,src,-
    int src = __float_as_int(es1.z);
    int n0 = blk[2 * blockIdx.x];
    int n1 = blk[2 * blockIdx.x + 1];

    for (int i = t; i < 48;  i += 256) s_m1w[i] = m1w[i];
    for (int i = t; i < 16;  i += 256) s_m1b[i] = m1b[i];
    for (int i = t; i < 768; i += 256) s_m2w[i] = m2w[i];
    for (int i = t; i < 48;  i += 256) s_m2b[i] = m2b[i];
    __syncthreads();

    float a0 = es0.x, a1 = es0.y, r2 = es0.z;
    float shx = es0.w, shy = es1.x, shz = es1.y;

    float hid[16];
#pragma unroll
    for (int j = 0; j < 16; j++) {
        float z = fmaf(a0, s_m1w[j], fmaf(a1, s_m1w[16 + j], fmaf(r2, s_m1w[32 + j], s_m1b[j])));
        hid[j] = z / (1.f + __expf(-z));
    }

    const float4* hv = (const float4*)(h2 + (size_t)src * HID);
    int gid = t / 12;            // 0..20 (21 groups); threads 252..255 idle in reduce
    int rem = t % 12;
    int q   = rem >> 1;          // float4 column 0..5
    int half= rem & 1;           // row-parity split, combined via shfl_xor(1)

    // ================= PASS A: channels v=0..7 (cols 0..23) =================
    float xj[24];
    ((float4*)xj)[0] = hv[0]; ((float4*)xj)[1] = hv[1]; ((float4*)xj)[2] = hv[2];
    ((float4*)xj)[3] = hv[3]; ((float4*)xj)[4] = hv[4]; ((float4*)xj)[5] = hv[5];

    float m[24];
#pragma unroll
    for (int v = 0; v < 8; v++) {
        float x0 = xj[v * 3 + 0], x1 = xj[v * 3 + 1], x2 = xj[v * 3 + 2];
        float c0 = x1 * shz - x2 * shy;
        float c1 = x2 * shx - x0 * shz;
        float c2 = x0 * shy - x1 * shx;
        int cb = v * 3;
        float g0 = s_m2b[cb], g1 = s_m2b[cb + 1], g2 = s_m2b[cb + 2];
#pragma unroll
        for (int j = 0; j < 16; j++) {
            float hj = hid[j];
            g0 = fmaf(hj, s_m2w[j * 48 + cb + 0], g0);
            g1 = fmaf(hj, s_m2w[j * 48 + cb + 1], g1);
            g2 = fmaf(hj, s_m2w[j * 48 + cb + 2], g2);
        }
        m[cb + 0] = g0 * c0 * TP_NORM;
        m[cb + 1] = g1 * c1 * TP_NORM;
        m[cb + 2] = g2 * c2 * TP_NORM;
    }
    {
        float4* row = (float4*)&s_msg[t][0];
#pragma unroll
        for (int qq = 0; qq < 6; qq++) row[qq] = ((float4*)m)[qq];
    }
    // issue pass-B gather now (latency hides under reduce A)
    ((float4*)xj)[0] = hv[6];  ((float4*)xj)[1] = hv[7];  ((float4*)xj)[2] = hv[8];
    ((float4*)xj)[3] = hv[9];  ((float4*)xj)[4] = hv[10]; ((float4*)xj)[5] = hv[11];
    __syncthreads();

    if (t < 252) {
        for (int nn = n0 + gid; nn <= n1; nn += 21) {
            int lo = off[nn], hi = off[nn + 1];
            int rlo = (lo > base) ? lo - base : 0;
            int rhi = ((hi < base + REB) ? hi : base + REB) - base;
            if (rlo < rhi) {                     // same for both halves of a pair
                float4 acc = make_float4(0.f, 0.f, 0.f, 0.f);
                for (int r = rlo + half; r < rhi; r += 2) {
                    float4 v = *(const float4*)&s_msg[r][q * 4];
                    acc.x += v.x; acc.y += v.y; acc.z += v.z; acc.w += v.w;
                }
                acc.x += __shfl_xor(acc.x, 1);
                acc.y += __shfl_xor(acc.y, 1);
                acc.z += __shfl_xor(acc.z, 1);
                acc.w += __shfl_xor(acc.w, 1);
                if (half == 0) {
                    float* dp = dx + (size_t)nn * HID + q * 4;
                    if (lo < base || hi > base + REB) {
                        atomicAdd(dp + 0, acc.x); atomicAdd(dp + 1, acc.y);
                        atomicAdd(dp + 2, acc.z); atomicAdd(dp + 3, acc.w);
                    } else {
                        *(float4*)dp = acc;
                    }
                }
            }
        }
    }
    __syncthreads();

    // ================= PASS B: channels v=8..15 (cols 24..47) =================
#pragma unroll
    for (int v = 0; v < 8; v++) {
        float x0 = xj[v * 3 + 0], x1 = xj[v * 3 + 1], x2 = xj[v * 3 + 2];
        float c0 = x1 * shz - x2 * shy;
        float c1 = x2 * shx - x0 * shz;
        float c2 = x0 * shy - x1 * shx;
        int cb = v * 3;
        int col = 24 + cb;
        float g0 = s_m2b[col], g1 = s_m2b[col + 1], g2 = s_m2b[col + 2];
#pragma unroll
        for (int j = 0; j < 16; j++) {
            float hj = hid[j];
            g0 = fmaf(hj, s_m2w[j * 48 + col + 0], g0);
            g1 = fmaf(hj, s_m2w[j * 48 + col + 1], g1);
            g2 = fmaf(hj, s_m2w[j * 48 + col + 2], g2);
        }
        m[cb + 0] = g0 * c0 * TP_NORM;
        m[cb + 1] = g1 * c1 * TP_NORM;
        m[cb + 2] = g2 * c2 * TP_NORM;
    }
    {
        float4* row = (float4*)&s_msg[t][0];
#pragma unroll
        for (int qq = 0; qq < 6; qq++) row[qq] = ((float4*)m)[qq];
    }
    __syncthreads();

    if (t < 252) {
        for (int nn = n0 + gid; nn <= n1; nn += 21) {
            int lo = off[nn], hi = off[nn + 1];
            int rlo = (lo > base) ? lo - base : 0;
            int rhi = ((hi < base + REB) ? hi : base + REB) - base;
            if (rlo < rhi) {
                float4 acc = make_float4(0.f, 0.f, 0.f, 0.f);
                for (int r = rlo + half; r < rhi; r += 2) {
                    float4 v = *(const float4*)&s_msg[r][q * 4];
                    acc.x += v.x; acc.y += v.y; acc.z += v.z; acc.w += v.w;
                }
                acc.x += __shfl_xor(acc.x, 1);
                acc.y += __shfl_xor(acc.y, 1);
                acc.z += __shfl_xor(acc.z, 1);
                acc.w += __shfl_xor(acc.w, 1);
                if (half == 0) {
                    float* dp = dx + (size_t)nn * HID + 24 + q * 4;
                    if (lo < base || hi > base + REB) {
                        atomicAdd(dp + 0, acc.x); atomicAdd(dp + 1, acc.y);
                        atomicAdd(dp + 2, acc.z); atomicAdd(dp + 3, acc.w);
                    } else {
                        *(float4*)dp = acc;
                    }
                }
            }
        }
    }
}

// ---------------- h += dx; dx = 0 (fallback path only) ----------------
__global__ void k_add(float* __restrict__ h, float* __restrict__ dx) {
    int t = blockIdx.x * blockDim.x + threadIdx.x;
    if (t >= N_NODES * HID) return;
    h[t] += dx[t];
    dx[t] = 0.f;
}

// ---------------- pool: per-graph mean of ((h+dx) @ lin_w) ----------------
__global__ void __launch_bounds__(256) k_pool(
    const float* __restrict__ h, const float* __restrict__ dxin, const int* __restrict__ batch,
    const float* __restrict__ linw, float* __restrict__ gsum, float* __restrict__ gcnt)
{
    __shared__ float ss[N_GRAPHS];
    __shared__ float sc[N_GRAPHS];
    for (int i = threadIdx.x; i < N_GRAPHS; i += 256) { ss[i] = 0.f; sc[i] = 0.f; }
    __syncthreads();
    int n = blockIdx.x * 256 + threadIdx.x;
    if (n < N_NODES) {
        float s = 0.f;
        const float4* hv = (const float4*)(h + (size_t)n * HID);
        const float4* dv = (const float4*)(dxin + (size_t)n * HID);
#pragma unroll
        for (int qq = 0; qq < 12; qq++) {
            float4 v = hv[qq], d = dv[qq];
            s += (v.x + d.x) * linw[qq * 4 + 0] + (v.y + d.y) * linw[qq * 4 + 1]
               + (v.z + d.z) * linw[qq * 4 + 2] + (v.w + d.w) * linw[qq * 4 + 3];
        }
        int b = batch[n];
        atomicAdd(&ss[b], s);
        atomicAdd(&sc[b], 1.f);
    }
    __syncthreads();
    for (int i = threadIdx.x; i < N_GRAPHS; i += 256) {
        if (sc[i] != 0.f) {
            atomicAdd(&gsum[i], ss[i]);
            atomicAdd(&gcnt[i], sc[i]);
        }
    }
}

__global__ void k_final(const float* __restrict__ gsum, const float* __restrict__ gcnt,
                        const float* __restrict__ linb, float* __restrict__ out) {
    int g = threadIdx.x;
    if (g < N_GRAPHS) out[g] = gsum[g] / fmaxf(gcnt[g], 1.f) + linb[0];
}

// ---------------- fallback (round-1 proven atomic path) ----------------
__global__ void __launch_bounds__(256) k_edge_atomic(
    const int* __restrict__ ei, const float* __restrict__ ea,
    const float* __restrict__ h, float* __restrict__ dx,
    const float* __restrict__ m1w, const float* __restrict__ m1b,
    const float* __restrict__ m2w, const float* __restrict__ m2b,
    const float* __restrict__ tpw)
{
    __shared__ float s_m1w[48];
    __shared__ float s_m1b[16];
    __shared__ float s_m2w[768];
    __shared__ float s_m2b[48];
    __shared__ float s_tpw[256];
    for (int i = threadIdx.x; i < 48;  i += 256) s_m1w[i] = m1w[i];
    for (int i = threadIdx.x; i < 16;  i += 256) s_m1b[i] = m1b[i];
    for (int i = threadIdx.x; i < 768; i += 256) s_m2w[i] = m2w[i];
    for (int i = threadIdx.x; i < 48;  i += 256) s_m2b[i] = m2b[i];
    for (int i = threadIdx.x; i < 256; i += 256) s_tpw[i] = tpw[i];
    __syncthreads();
    int e = blockIdx.x * 256 + threadIdx.x;
    int src = ei[e];
    int dst = ei[N_EDGES + e];
    float a0 = ea[e * 5 + 0], a1 = ea[e * 5 + 1];
    float rx = ea[e * 5 + 2], ry = ea[e * 5 + 3], rz = ea[e * 5 + 4];
    float r2 = rx * rx + ry * ry + rz * rz;
    float inv = rsqrtf(fmaxf(r2, 1e-24f));
    float shx = SQRT3 * rx * inv, shy = SQRT3 * ry * inv, shz = SQRT3 * rz * inv;
    float hid[16];
#pragma unroll
    for (int j = 0; j < 16; j++) {
        float z = a0 * s_m1w[j] + a1 * s_m1w[16 + j] + r2 * s_m1w[32 + j] + s_m1b[j];
        hid[j] = z / (1.f + __expf(-z));
    }
    float xj[48];
    const float4* hv = (const float4*)(h + (size_t)src * HID);
#pragma unroll
    for (int qq = 0; qq < 12; qq++) {
        float4 v = hv[qq];
        xj[qq * 4 + 0] = v.x; xj[qq * 4 + 1] = v.y; xj[qq * 4 + 2] = v.z; xj[qq * 4 + 3] = v.w;
    }
    float cr[48];
#pragma unroll
    for (int u = 0; u < 16; u++) {
        float x0 = xj[u * 3 + 0], x1 = xj[u * 3 + 1], x2 = xj[u * 3 + 2];
        cr[u * 3 + 0] = x1 * shz - x2 * shy;
        cr[u * 3 + 1] = x2 * shx - x0 * shz;
        cr[u * 3 + 2] = x0 * shy - x1 * shx;
    }
    float* dd = dx + (size_t)dst * HID;
#pragma unroll
    for (int v = 0; v < 16; v++) {
        float t0 = 0.f, t1 = 0.f, t2 = 0.f;
#pragma unroll
        for (int u = 0; u < 16; u++) {
            float w = s_tpw[u * 16 + v];
            t0 += w * cr[u * 3 + 0];
            t1 += w * cr[u * 3 + 1];
            t2 += w * cr[u * 3 + 2];
        }
        float g0 = s_m2b[v * 3 + 0], g1 = s_m2b[v * 3 + 1], g2 = s_m2b[v * 3 + 2];
#pragma unroll
        for (int j = 0; j < 16; j++) {
            float hj = hid[j];
            g0 = fmaf(hj, s_m2w[j * 48 + v * 3 + 0], g0);
            g1 = fmaf(hj, s_m2w[j * 48 + v * 3 + 1], g1);
            g2 = fmaf(hj, s_m2w[j * 48 + v * 3 + 2], g2);
        }
        atomicAdd(dd + v * 3 + 0, g0 * t0 * TP_NORM);
        atomicAdd(dd + v * 3 + 1, g1 * t1 * TP_NORM);
        atomicAdd(dd + v * 3 + 2, g2 * t2 * TP_NORM);
    }
}

extern "C" void kernel_launch(void* const* d_in, const int* in_sizes, int n_in,
                              void* d_out, int out_size, void* d_ws, size_t ws_size,
                              hipStream_t stream) {
    const float* x    = (const float*)d_in[0];
    const int*   ei   = (const int*)  d_in[1];
    const float* ea   = (const float*)d_in[2];
    const int*   batch= (const int*)  d_in[3];
    const float* ew   = (const float*)d_in[4];
    const float* m1w  = (const float*)d_in[5];
    const float* m1b  = (const float*)d_in[6];
    const float* m2w  = (const float*)d_in[7];
    const float* m2b  = (const float*)d_in[8];
    const float* tpw  = (const float*)d_in[9];
    const float* linw = (const float*)d_in[10];
    const float* linb = (const float*)d_in[11];
    float* out = (float*)d_out;

    // -------- workspace layout (256B-aligned carve) --------
    char* w = (char*)d_ws;
    auto alloc = [&](size_t bytes) -> char* {
        char* p = w;
        w += (bytes + 255) & ~(size_t)255;
        return p;
    };
    float* hA   = (float*)alloc((size_t)N_NODES * HID * 4);
    float* hB   = (float*)alloc((size_t)N_NODES * HID * 4);
    float* h2   = (float*)alloc((size_t)N_NODES * HID * 4);
    float* dx   = (float*)alloc((size_t)N_NODES * HID * 4);
    float* gbuf = (float*)alloc(2 * N_GRAPHS * 4);
    float* es_s = (float*)alloc((size_t)N_EDGES * 8 * 4);
    int*   off  = (int*)  alloc((size_t)(N_NODES + 1) * 4);
    int*   cnt  = (int*)  alloc((size_t)N_NODES * 4);
    int*   rank = (int*)  alloc((size_t)N_EDGES * 4);
    int*   blk  = (int*)  alloc((size_t)NBLK * 2 * 4);
    size_t need = (size_t)(w - (char*)d_ws);
    float* gsum = gbuf;
    float* gcnt = gbuf + N_GRAPHS;

    if (ws_size < need) {
        // -------- fallback: round-1 atomic path (needs 19.2MB + 512B) --------
        float* fh   = (float*)d_ws;
        float* fdx  = fh + (size_t)N_NODES * HID;
        float* fgs  = fdx + (size_t)N_NODES * HID;
        float* fgc  = fgs + N_GRAPHS;
        hipMemsetAsync(fdx, 0, ((size_t)N_NODES * HID + 2 * N_GRAPHS) * sizeof(float), stream);
        k_embed<<<(N_NODES * HID + 255) / 256, 256, 0, stream>>>(x, ew, fh);
        for (int l = 0; l < N_LAYERS; l++) {
            k_edge_atomic<<<N_EDGES / 256, 256, 0, stream>>>(ei, ea, fh, fdx,
                m1w + l * 48, m1b + l * 16, m2w + l * 768, m2b + l * 48, tpw + l * 256);
            k_add<<<(N_NODES * HID + 255) / 256, 256, 0, stream>>>(fh, fdx);
        }
        hipMemsetAsync(fdx, 0, (size_t)N_NODES * HID * 4, stream);
        k_pool<<<(N_NODES + 255) / 256, 256, 0, stream>>>(fh, fdx, batch, linw, fgs, fgc);
        k_final<<<1, 64, 0, stream>>>(fgs, fgc, linb, out);
        return;
    }

    // -------- CSR setup: one atomic pass --------
    hipMemsetAsync(cnt, 0, (size_t)N_NODES * 4, stream);
    hipMemsetAsync(gbuf, 0, 2 * N_GRAPHS * 4, stream);
    k_count<<<N_EDGES / 256, 256, 0, stream>>>(ei, cnt, rank);
    k_scan<<<1, 1024, 0, stream>>>(cnt, off);
    k_rng<<<(NBLK + 255) / 256, 256, 0, stream>>>(off, blk);
    k_build<<<N_EDGES / 256, 256, 0, stream>>>(ei, ea, off, rank, es_s);

    k_embed<<<(N_NODES * HID + 255) / 256, 256, 0, stream>>>(x, ew, hA);

    const int nhBlocks = (N_NODES * HID + 255) / 256;
    float* hcur = hA;
    float* hnxt = hB;
    for (int l = 0; l < N_LAYERS; l++) {
        if (l == 0) {
            k_h2<<<nhBlocks, 256, 0, stream>>>(hcur, tpw, h2, dx);
        } else {
            k_h2_add<<<nhBlocks, 256, 0, stream>>>(hcur, dx, tpw + l * 256, h2, hnxt);
            float* tmp = hcur; hcur = hnxt; hnxt = tmp;
        }
        k_fused<<<NBLK, 256, 0, stream>>>(es_s, off, blk, h2, dx,
            m1w + l * 48, m1b + l * 16, m2w + l * 768, m2b + l * 48);
    }

    // pool over h_final = hcur + dx (last layer's residual folded into pool)
    k_pool<<<(N_NODES + 255) / 256, 256, 0, stream>>>(hcur, dx, batch, linw, gsum, gcnt);
    k_final<<<1, 64, 0, stream>>>(gsum, gcnt, linb, out);
}

// Round 7
// 578.205 us; speedup vs baseline: 27.2308x; 1.2216x over previous
//
#include <hip/hip_runtime.h>

#define N_NODES 50000
#define N_EDGES 1600000
#define N_LAYERS 4
#define N_CH 16
#define HID 48            // N_CH * 3
#define N_GRAPHS 64
#define TP_NORM 0.17677669529663687f   // 1/sqrt(2*N_CH)
#define SQRT3 1.7320508075688772f
#define REB 256           // edges per block in fused kernel
#define MPAD 28           // LDS row stride (floats) for 24-col half-message
#define NBLK (N_EDGES / REB)

// ---------------- embed: h = x @ embed_w ----------------
__global__ void k_embed(const float* __restrict__ x, const float* __restrict__ ew,
                        float* __restrict__ h) {
    int t = blockIdx.x * blockDim.x + threadIdx.x;
    if (t >= N_NODES * HID) return;
    int n = t / HID, c = t % HID;
    h[t] = x[n * 3 + 0] * ew[c] + x[n * 3 + 1] * ew[HID + c] + x[n * 3 + 2] * ew[2 * HID + c];
}

// ---------------- CSR build (single atomic pass) ----------------
__global__ void k_count(const int* __restrict__ ei, int* __restrict__ cnt,
                        int* __restrict__ rank) {
    int e = blockIdx.x * 256 + threadIdx.x;              // N_EDGES % 256 == 0
    rank[e] = atomicAdd(&cnt[ei[N_EDGES + e]], 1);
}

__global__ void __launch_bounds__(1024) k_scan(const int* __restrict__ cnt, int* __restrict__ off) {
    __shared__ int part[1024];
    int t = threadIdx.x;
    const int PER = 49;                                  // 49*1024 >= 50000
    int base = t * PER;
    int s = 0;
    for (int i = 0; i < PER; i++) { int idx = base + i; if (idx < N_NODES) s += cnt[idx]; }
    part[t] = s;
    __syncthreads();
    for (int d = 1; d < 1024; d <<= 1) {
        int v = (t >= d) ? part[t - d] : 0;
        __syncthreads();
        part[t] += v;
        __syncthreads();
    }
    int run = (t == 0) ? 0 : part[t - 1];
    for (int i = 0; i < PER; i++) {
        int idx = base + i;
        if (idx < N_NODES) { off[idx] = run; run += cnt[idx]; }
    }
    if (t == 1023) off[N_NODES] = part[1023];
}

// per fused-block node range via binary search (replaces dst_s array)
__global__ void k_rng(const int* __restrict__ off, int* __restrict__ blk) {
    int b = blockIdx.x * blockDim.x + threadIdx.x;
    if (b >= NBLK) return;
    int base = b * REB;
    int lo = 0, hi = N_NODES;
    while (lo < hi) { int mid = (lo + hi + 1) >> 1; if (off[mid] <= base) lo = mid; else hi = mid - 1; }
    blk[2 * b] = lo;
    int last = base + REB - 1;
    int hi2 = N_NODES;
    while (lo < hi2) { int mid = (lo + hi2 + 1) >> 1; if (off[mid] <= last) lo = mid; else hi2 = mid - 1; }
    blk[2 * b + 1] = lo;
}

// sorted 32B record per edge: [a0, a1, r2, shx, shy, shz, src_bits, 0]
__global__ void k_build(const int* __restrict__ ei, const float* __restrict__ ea,
                        const int* __restrict__ off, const int* __restrict__ rank,
                        float* __restrict__ es_s) {
    int e = blockIdx.x * 256 + threadIdx.x;
    int d = ei[N_EDGES + e];
    int pos = off[d] + rank[e];
    float a0 = ea[e * 5 + 0], a1 = ea[e * 5 + 1];
    float rx = ea[e * 5 + 2], ry = ea[e * 5 + 3], rz = ea[e * 5 + 4];
    float r2 = rx * rx + ry * ry + rz * rz;
    float inv = rsqrtf(fmaxf(r2, 1e-24f)) * SQRT3;
    float4* o = (float4*)(es_s + (size_t)pos * 8);
    o[0] = make_float4(a0, a1, r2, rx * inv);
    o[1] = make_float4(ry * inv, rz * inv, __int_as_float(ei[e]), 0.f);
}

// ---------------- per-node tpw transform: h2[n,v,i] = sum_u tpw[u,v] hin[n,u,i] ----------------
__global__ void k_h2(const float* __restrict__ hin, const float* __restrict__ tpw,
                     float* __restrict__ h2, float* __restrict__ dx) {
    int t = blockIdx.x * blockDim.x + threadIdx.x;
    if (t >= N_NODES * HID) return;
    int n = t / HID, c = t % HID, v = c / 3, i = c % 3;
    const float* hr = hin + (size_t)n * HID + i;
    float s = 0.f;
#pragma unroll
    for (int u = 0; u < 16; u++) s = fmaf(tpw[u * 16 + v], hr[u * 3], s);
    h2[t] = s;
    dx[t] = 0.f;
}

__global__ void k_h2_add(const float* __restrict__ hin, float* __restrict__ dxin,
                         const float* __restrict__ tpw,
                         float* __restrict__ h2, float* __restrict__ hout) {
    int t = blockIdx.x * blockDim.x + threadIdx.x;
    if (t >= N_NODES * HID) return;
    int n = t / HID, c = t % HID, v = c / 3, i = c % 3;
    size_t rb = (size_t)n * HID;
    const float* hr = hin + rb + i;
    const float* dr = dxin + rb + i;
    float s = 0.f;
#pragma unroll
    for (int u = 0; u < 16; u++) s = fmaf(tpw[u * 16 + v], hr[u * 3] + dr[u * 3], s);
    h2[t] = s;
    hout[t] = hin[t] + dxin[t];
    dxin[t] = 0.f;
}

// ---------------- fused: message compute + in-LDS segmented reduce -> dx ----------------
// Weights are read DIRECTLY from global with wave-uniform compile-time offsets:
// the compiler scalarizes these to s_load through the constant cache, keeping the
// LDS pipe free for s_msg staging + reduce (was 768 b32 broadcast reads/edge).
__global__ void __launch_bounds__(256) k_fused(
    const float* __restrict__ es_s, const int* __restrict__ off,
    const int* __restrict__ blk,
    const float* __restrict__ h2, float* __restrict__ dx,
    const float* __restrict__ m1w, const float* __restrict__ m1b,
    const float* __restrict__ m2w, const float* __restrict__ m2b)
{
    __shared__ float s_msg[REB][MPAD];

    int t = threadIdx.x;
    int base = blockIdx.x * REB;
    int e2 = base + t;

    // per-lane global loads issued first (latency buried under gate compute)
    const float4* esp = (const float4*)(es_s + (size_t)e2 * 8);
    float4 es0 = esp[0];                       // a0,a1,r2,shx
    float4 es1 = esp[1];                       // shy,shz,src,-
    int src = __float_as_int(es1.z);
    const float4* hv = (const float4*)(h2 + (size_t)src * HID);
    float xj[24];
    ((float4*)xj)[0] = hv[0]; ((float4*)xj)[1] = hv[1]; ((float4*)xj)[2] = hv[2];
    ((float4*)xj)[3] = hv[3]; ((float4*)xj)[4] = hv[4]; ((float4*)xj)[5] = hv[5];
    int n0 = blk[2 * blockIdx.x];
    int n1 = blk[2 * blockIdx.x + 1];

    float a0 = es0.x, a1 = es0.y, r2 = es0.z;
    float shx = es0.w, shy = es1.x, shz = es1.y;

    // gate hidden layer (uniform scalar weight reads)
    float hid[16];
#pragma unroll
    for (int j = 0; j < 16; j++) {
        float z = fmaf(a0, m1w[j], fmaf(a1, m1w[16 + j], fmaf(r2, m1w[32 + j], m1b[j])));
        hid[j] = z / (1.f + __expf(-z));
    }

    int gid = t / 12;            // 0..20 (21 groups); threads 252..255 idle in reduce
    int rem = t % 12;
    int q   = rem >> 1;          // float4 column 0..5
    int half= rem & 1;           // row-parity split, combined via shfl_xor(1)

    // ================= PASS A: channels v=0..7 (cols 0..23) =================
    float m[24];
#pragma unroll
    for (int qq = 0; qq < 6; qq++) {
        float4 b = *(const float4*)(m2b + qq * 4);
        m[qq * 4 + 0] = b.x; m[qq * 4 + 1] = b.y; m[qq * 4 + 2] = b.z; m[qq * 4 + 3] = b.w;
    }
#pragma unroll
    for (int j = 0; j < 16; j++) {
        float hj = hid[j];
#pragma unroll
        for (int qq = 0; qq < 6; qq++) {
            float4 w4 = *(const float4*)(m2w + j * 48 + qq * 4);
            m[qq * 4 + 0] = fmaf(hj, w4.x, m[qq * 4 + 0]);
            m[qq * 4 + 1] = fmaf(hj, w4.y, m[qq * 4 + 1]);
            m[qq * 4 + 2] = fmaf(hj, w4.z, m[qq * 4 + 2]);
            m[qq * 4 + 3] = fmaf(hj, w4.w, m[qq * 4 + 3]);
        }
    }
#pragma unroll
    for (int v = 0; v < 8; v++) {
        float x0 = xj[v * 3 + 0], x1 = xj[v * 3 + 1], x2 = xj[v * 3 + 2];
        float c0 = x1 * shz - x2 * shy;
        float c1 = x2 * shx - x0 * shz;
        float c2 = x0 * shy - x1 * shx;
        m[v * 3 + 0] *= c0 * TP_NORM;
        m[v * 3 + 1] *= c1 * TP_NORM;
        m[v * 3 + 2] *= c2 * TP_NORM;
    }
    {
        float4* row = (float4*)&s_msg[t][0];
#pragma unroll
        for (int qq = 0; qq < 6; qq++) row[qq] = ((float4*)m)[qq];
    }
    // prefetch pass-B half of the gather (overlaps reduce A)
    ((float4*)xj)[0] = hv[6];  ((float4*)xj)[1] = hv[7];  ((float4*)xj)[2] = hv[8];
    ((float4*)xj)[3] = hv[9];  ((float4*)xj)[4] = hv[10]; ((float4*)xj)[5] = hv[11];
    __syncthreads();

    if (t < 252) {
        for (int nn = n0 + gid; nn <= n1; nn += 21) {
            int lo = off[nn], hi = off[nn + 1];
            int rlo = (lo > base) ? lo - base : 0;
            int rhi = ((hi < base + REB) ? hi : base + REB) - base;
            if (rlo < rhi) {                     // same for both halves of a pair
                float4 acc = make_float4(0.f, 0.f, 0.f, 0.f);
                for (int r = rlo + half; r < rhi; r += 2) {
                    float4 v = *(const float4*)&s_msg[r][q * 4];
                    acc.x += v.x; acc.y += v.y; acc.z += v.z; acc.w += v.w;
                }
                acc.x += __shfl_xor(acc.x, 1);
                acc.y += __shfl_xor(acc.y, 1);
                acc.z += __shfl_xor(acc.z, 1);
                acc.w += __shfl_xor(acc.w, 1);
                if (half == 0) {
                    float* dp = dx + (size_t)nn * HID + q * 4;
                    if (lo < base || hi > base + REB) {
                        atomicAdd(dp + 0, acc.x); atomicAdd(dp + 1, acc.y);
                        atomicAdd(dp + 2, acc.z); atomicAdd(dp + 3, acc.w);
                    } else {
                        *(float4*)dp = acc;
                    }
                }
            }
        }
    }
    __syncthreads();

    // ================= PASS B: channels v=8..15 (cols 24..47) =================
#pragma unroll
    for (int qq = 0; qq < 6; qq++) {
        float4 b = *(const float4*)(m2b + 24 + qq * 4);
        m[qq * 4 + 0] = b.x; m[qq * 4 + 1] = b.y; m[qq * 4 + 2] = b.z; m[qq * 4 + 3] = b.w;
    }
#pragma unroll
    for (int j = 0; j < 16; j++) {
        float hj = hid[j];
#pragma unroll
        for (int qq = 0; qq < 6; qq++) {
            float4 w4 = *(const float4*)(m2w + j * 48 + 24 + qq * 4);
            m[qq * 4 + 0] = fmaf(hj, w4.x, m[qq * 4 + 0]);
            m[qq * 4 + 1] = fmaf(hj, w4.y, m[qq * 4 + 1]);
            m[qq * 4 + 2] = fmaf(hj, w4.z, m[qq * 4 + 2]);
            m[qq * 4 + 3] = fmaf(hj, w4.w, m[qq * 4 + 3]);
        }
    }
#pragma unroll
    for (int v = 0; v < 8; v++) {
        float x0 = xj[v * 3 + 0], x1 = xj[v * 3 + 1], x2 = xj[v * 3 + 2];
        float c0 = x1 * shz - x2 * shy;
        float c1 = x2 * shx - x0 * shz;
        float c2 = x0 * shy - x1 * shx;
        m[v * 3 + 0] *= c0 * TP_NORM;
        m[v * 3 + 1] *= c1 * TP_NORM;
        m[v * 3 + 2] *= c2 * TP_NORM;
    }
    {
        float4* row = (float4*)&s_msg[t][0];
#pragma unroll
        for (int qq = 0; qq < 6; qq++) row[qq] = ((float4*)m)[qq];
    }
    __syncthreads();

    if (t < 252) {
        for (int nn = n0 + gid; nn <= n1; nn += 21) {
            int lo = off[nn], hi = off[nn + 1];
            int rlo = (lo > base) ? lo - base : 0;
            int rhi = ((hi < base + REB) ? hi : base + REB) - base;
            if (rlo < rhi) {
                float4 acc = make_float4(0.f, 0.f, 0.f, 0.f);
                for (int r = rlo + half; r < rhi; r += 2) {
                    float4 v = *(const float4*)&s_msg[r][q * 4];
                    acc.x += v.x; acc.y += v.y; acc.z += v.z; acc.w += v.w;
                }
                acc.x += __shfl_xor(acc.x, 1);
                acc.y += __shfl_xor(acc.y, 1);
                acc.z += __shfl_xor(acc.z, 1);
                acc.w += __shfl_xor(acc.w, 1);
                if (half == 0) {
                    float* dp = dx + (size_t)nn * HID + 24 + q * 4;
                    if (lo < base || hi > base + REB) {
                        atomicAdd(dp + 0, acc.x); atomicAdd(dp + 1, acc.y);
                        atomicAdd(dp + 2, acc.z); atomicAdd(dp + 3, acc.w);
                    } else {
                        *(float4*)dp = acc;
                    }
                }
            }
        }
    }
}

// ---------------- h += dx; dx = 0 (fallback path only) ----------------
__global__ void k_add(float* __restrict__ h, float* __restrict__ dx) {
    int t = blockIdx.x * blockDim.x + threadIdx.x;
    if (t >= N_NODES * HID) return;
    h[t] += dx[t];
    dx[t] = 0.f;
}

// ---------------- pool: per-graph mean of ((h+dx) @ lin_w) ----------------
__global__ void __launch_bounds__(256) k_pool(
    const float* __restrict__ h, const float* __restrict__ dxin, const int* __restrict__ batch,
    const float* __restrict__ linw, float* __restrict__ gsum, float* __restrict__ gcnt)
{
    __shared__ float ss[N_GRAPHS];
    __shared__ float sc[N_GRAPHS];
    for (int i = threadIdx.x; i < N_GRAPHS; i += 256) { ss[i] = 0.f; sc[i] = 0.f; }
    __syncthreads();
    int n = blockIdx.x * 256 + threadIdx.x;
    if (n < N_NODES) {
        float s = 0.f;
        const float4* hv = (const float4*)(h + (size_t)n * HID);
        const float4* dv = (const float4*)(dxin + (size_t)n * HID);
#pragma unroll
        for (int qq = 0; qq < 12; qq++) {
            float4 v = hv[qq], d = dv[qq];
            s += (v.x + d.x) * linw[qq * 4 + 0] + (v.y + d.y) * linw[qq * 4 + 1]
               + (v.z + d.z) * linw[qq * 4 + 2] + (v.w + d.w) * linw[qq * 4 + 3];
        }
        int b = batch[n];
        atomicAdd(&ss[b], s);
        atomicAdd(&sc[b], 1.f);
    }
    __syncthreads();
    for (int i = threadIdx.x; i < N_GRAPHS; i += 256) {
        if (sc[i] != 0.f) {
            atomicAdd(&gsum[i], ss[i]);
            atomicAdd(&gcnt[i], sc[i]);
        }
    }
}

__global__ void k_final(const float* __restrict__ gsum, const float* __restrict__ gcnt,
                        const float* __restrict__ linb, float* __restrict__ out) {
    int g = threadIdx.x;
    if (g < N_GRAPHS) out[g] = gsum[g] / fmaxf(gcnt[g], 1.f) + linb[0];
}

// ---------------- fallback (round-1 proven atomic path) ----------------
__global__ void __launch_bounds__(256) k_edge_atomic(
    const int* __restrict__ ei, const float* __restrict__ ea,
    const float* __restrict__ h, float* __restrict__ dx,
    const float* __restrict__ m1w, const float* __restrict__ m1b,
    const float* __restrict__ m2w, const float* __restrict__ m2b,
    const float* __restrict__ tpw)
{
    __shared__ float s_m1w[48];
    __shared__ float s_m1b[16];
    __shared__ float s_m2w[768];
    __shared__ float s_m2b[48];
    __shared__ float s_tpw[256];
    for (int i = threadIdx.x; i < 48;  i += 256) s_m1w[i] = m1w[i];
    for (int i = threadIdx.x; i < 16;  i += 256) s_m1b[i] = m1b[i];
    for (int i = threadIdx.x; i < 768; i += 256) s_m2w[i] = m2w[i];
    for (int i = threadIdx.x; i < 48;  i += 256) s_m2b[i] = m2b[i];
    for (int i = threadIdx.x; i < 256; i += 256) s_tpw[i] = tpw[i];
    __syncthreads();
    int e = blockIdx.x * 256 + threadIdx.x;
    int src = ei[e];
    int dst = ei[N_EDGES + e];
    float a0 = ea[e * 5 + 0], a1 = ea[e * 5 + 1];
    float rx = ea[e * 5 + 2], ry = ea[e * 5 + 3], rz = ea[e * 5 + 4];
    float r2 = rx * rx + ry * ry + rz * rz;
    float inv = rsqrtf(fmaxf(r2, 1e-24f));
    float shx = SQRT3 * rx * inv, shy = SQRT3 * ry * inv, shz = SQRT3 * rz * inv;
    float hid[16];
#pragma unroll
    for (int j = 0; j < 16; j++) {
        float z = a0 * s_m1w[j] + a1 * s_m1w[16 + j] + r2 * s_m1w[32 + j] + s_m1b[j];
        hid[j] = z / (1.f + __expf(-z));
    }
    float xj[48];
    const float4* hv = (const float4*)(h + (size_t)src * HID);
#pragma unroll
    for (int qq = 0; qq < 12; qq++) {
        float4 v = hv[qq];
        xj[qq * 4 + 0] = v.x; xj[qq * 4 + 1] = v.y; xj[qq * 4 + 2] = v.z; xj[qq * 4 + 3] = v.w;
    }
    float cr[48];
#pragma unroll
    for (int u = 0; u < 16; u++) {
        float x0 = xj[u * 3 + 0], x1 = xj[u * 3 + 1], x2 = xj[u * 3 + 2];
        cr[u * 3 + 0] = x1 * shz - x2 * shy;
        cr[u * 3 + 1] = x2 * shx - x0 * shz;
        cr[u * 3 + 2] = x0 * shy - x1 * shx;
    }
    float* dd = dx + (size_t)dst * HID;
#pragma unroll
    for (int v = 0; v < 16; v++) {
        float t0 = 0.f, t1 = 0.f, t2 = 0.f;
#pragma unroll
        for (int u = 0; u < 16; u++) {
            float w = s_tpw[u * 16 + v];
            t0 += w * cr[u * 3 + 0];
            t1 += w * cr[u * 3 + 1];
            t2 += w * cr[u * 3 + 2];
        }
        float g0 = s_m2b[v * 3 + 0], g1 = s_m2b[v * 3 + 1], g2 = s_m2b[v * 3 + 2];
#pragma unroll
        for (int j = 0; j < 16; j++) {
            float hj = hid[j];
            g0 = fmaf(hj, s_m2w[j * 48 + v * 3 + 0], g0);
            g1 = fmaf(hj, s_m2w[j * 48 + v * 3 + 1], g1);
            g2 = fmaf(hj, s_m2w[j * 48 + v * 3 + 2], g2);
        }
        atomicAdd(dd + v * 3 + 0, g0 * t0 * TP_NORM);
        atomicAdd(dd + v * 3 + 1, g1 * t1 * TP_NORM);
        atomicAdd(dd + v * 3 + 2, g2 * t2 * TP_NORM);
    }
}

extern "C" void kernel_launch(void* const* d_in, const int* in_sizes, int n_in,
                              void* d_out, int out_size, void* d_ws, size_t ws_size,
                              hipStream_t stream) {
    const float* x    = (const float*)d_in[0];
    const int*   ei   = (const int*)  d_in[1];
    const float* ea   = (const float*)d_in[2];
    const int*   batch= (const int*)  d_in[3];
    const float* ew   = (const float*)d_in[4];
    const float* m1w  = (const float*)d_in[5];
    const float* m1b  = (const float*)d_in[6];
    const float* m2w  = (const float*)d_in[7];
    const float* m2b  = (const float*)d_in[8];
    const float* tpw  = (const float*)d_in[9];
    const float* linw = (const float*)d_in[10];
    const float* linb = (const float*)d_in[11];
    float* out = (float*)d_out;

    // -------- workspace layout (256B-aligned carve) --------
    char* w = (char*)d_ws;
    auto alloc = [&](size_t bytes) -> char* {
        char* p = w;
        w += (bytes + 255) & ~(size_t)255;
        return p;
    };
    float* hA   = (float*)alloc((size_t)N_NODES * HID * 4);
    float* hB   = (float*)alloc((size_t)N_NODES * HID * 4);
    float* h2   = (float*)alloc((size_t)N_NODES * HID * 4);
    float* dx   = (float*)alloc((size_t)N_NODES * HID * 4);
    float* gbuf = (float*)alloc(2 * N_GRAPHS * 4);
    float* es_s = (float*)alloc((size_t)N_EDGES * 8 * 4);
    int*   off  = (int*)  alloc((size_t)(N_NODES + 1) * 4);
    int*   cnt  = (int*)  alloc((size_t)N_NODES * 4);
    int*   rank = (int*)  alloc((size_t)N_EDGES * 4);
    int*   blk  = (int*)  alloc((size_t)NBLK * 2 * 4);
    size_t need = (size_t)(w - (char*)d_ws);
    float* gsum = gbuf;
    float* gcnt = gbuf + N_GRAPHS;

    if (ws_size < need) {
        // -------- fallback: round-1 atomic path (needs 19.2MB + 512B) --------
        float* fh   = (float*)d_ws;
        float* fdx  = fh + (size_t)N_NODES * HID;
        float* fgs  = fdx + (size_t)N_NODES * HID;
        float* fgc  = fgs + N_GRAPHS;
        hipMemsetAsync(fdx, 0, ((size_t)N_NODES * HID + 2 * N_GRAPHS) * sizeof(float), stream);
        k_embed<<<(N_NODES * HID + 255) / 256, 256, 0, stream>>>(x, ew, fh);
        for (int l = 0; l < N_LAYERS; l++) {
            k_edge_atomic<<<N_EDGES / 256, 256, 0, stream>>>(ei, ea, fh, fdx,
                m1w + l * 48, m1b + l * 16, m2w + l * 768, m2b + l * 48, tpw + l * 256);
            k_add<<<(N_NODES * HID + 255) / 256, 256, 0, stream>>>(fh, fdx);
        }
        hipMemsetAsync(fdx, 0, (size_t)N_NODES * HID * 4, stream);
        k_pool<<<(N_NODES + 255) / 256, 256, 0, stream>>>(fh, fdx, batch, linw, fgs, fgc);
        k_final<<<1, 64, 0, stream>>>(fgs, fgc, linb, out);
        return;
    }

    // -------- CSR setup: one atomic pass --------
    hipMemsetAsync(cnt, 0, (size_t)N_NODES * 4, stream);
    hipMemsetAsync(gbuf, 0, 2 * N_GRAPHS * 4, stream);
    k_count<<<N_EDGES / 256, 256, 0, stream>>>(ei, cnt, rank);
    k_scan<<<1, 1024, 0, stream>>>(cnt, off);
    k_rng<<<(NBLK + 255) / 256, 256, 0, stream>>>(off, blk);
    k_build<<<N_EDGES / 256, 256, 0, stream>>>(ei, ea, off, rank, es_s);

    k_embed<<<(N_NODES * HID + 255) / 256, 256, 0, stream>>>(x, ew, hA);

    const int nhBlocks = (N_NODES * HID + 255) / 256;
    float* hcur = hA;
    float* hnxt = hB;
    for (int l = 0; l < N_LAYERS; l++) {
        if (l == 0) {
            k_h2<<<nhBlocks, 256, 0, stream>>>(hcur, tpw, h2, dx);
        } else {
            k_h2_add<<<nhBlocks, 256, 0, stream>>>(hcur, dx, tpw + l * 256, h2, hnxt);
            float* tmp = hcur; hcur = hnxt; hnxt = tmp;
        }
        k_fused<<<NBLK, 256, 0, stream>>>(es_s, off, blk, h2, dx,
            m1w + l * 48, m1b + l * 16, m2w + l * 768, m2b + l * 48);
    }

    // pool over h_final = hcur + dx (last layer's residual folded into pool)
    k_pool<<<(N_NODES + 255) / 256, 256, 0, stream>>>(hcur, dx, batch, linw, gsum, gcnt);
    k_final<<<1, 64, 0, stream>>>(gsum, gcnt, linb, out);
}

// Round 8
// 493.600 us; speedup vs baseline: 31.8982x; 1.1714x over previous
//
#include <hip/hip_runtime.h>

#define N_NODES 50000
#define N_EDGES 1600000
#define N_LAYERS 4
#define N_CH 16
#define HID 48            // N_CH * 3
#define N_GRAPHS 64
#define TP_NORM 0.17677669529663687f   // 1/sqrt(2*N_CH)
#define SQRT3 1.7320508075688772f
#define REB 256           // edges per block in fused kernel
#define MPAD 28           // LDS row stride (floats) for 24-col half-message
#define NBLK (N_EDGES / REB)
#define NPART ((N_NODES + 255) / 256)   // 196 scan partials

// ---------------- embed: h = x @ embed_w ----------------
__global__ void k_embed(const float* __restrict__ x, const float* __restrict__ ew,
                        float* __restrict__ h) {
    int t = blockIdx.x * blockDim.x + threadIdx.x;
    if (t >= N_NODES * HID) return;
    int n = t / HID, c = t % HID;
    h[t] = x[n * 3 + 0] * ew[c] + x[n * 3 + 1] * ew[HID + c] + x[n * 3 + 2] * ew[2 * HID + c];
}

// ---------------- CSR build (single atomic pass) ----------------
__global__ void k_count(const int* __restrict__ ei, int* __restrict__ cnt,
                        int* __restrict__ rank) {
    int e = blockIdx.x * 256 + threadIdx.x;              // N_EDGES % 256 == 0
    rank[e] = atomicAdd(&cnt[ei[N_EDGES + e]], 1);
}

// ---- two-level scan of cnt -> off (replaces 93us single-block k_scan) ----
__global__ void k_sred(const int* __restrict__ cnt, int* __restrict__ bsum) {
    __shared__ int red[256];
    int b = blockIdx.x, t = threadIdx.x;
    int idx = b * 256 + t;
    red[t] = (idx < N_NODES) ? cnt[idx] : 0;
    __syncthreads();
    for (int d = 128; d > 0; d >>= 1) {
        if (t < d) red[t] += red[t + d];
        __syncthreads();
    }
    if (t == 0) bsum[b] = red[0];
}

__global__ void k_sscan(const int* __restrict__ bsum, int* __restrict__ bbase) {
    __shared__ int s[256];
    int t = threadIdx.x;
    int v = (t < NPART) ? bsum[t] : 0;
    s[t] = v;
    __syncthreads();
    for (int d = 1; d < 256; d <<= 1) {
        int x = (t >= d) ? s[t - d] : 0;
        __syncthreads();
        s[t] += x;
        __syncthreads();
    }
    if (t < NPART) bbase[t] = s[t] - v;          // exclusive
    if (t == NPART - 1) bbase[NPART] = s[t];     // grand total (== N_EDGES)
}

__global__ void k_soff(const int* __restrict__ cnt, const int* __restrict__ bbase,
                       int* __restrict__ off) {
    __shared__ int s[256];
    int b = blockIdx.x, t = threadIdx.x;
    int idx = b * 256 + t;
    int v = (idx < N_NODES) ? cnt[idx] : 0;
    s[t] = v;
    __syncthreads();
    for (int d = 1; d < 256; d <<= 1) {
        int x = (t >= d) ? s[t - d] : 0;
        __syncthreads();
        s[t] += x;
        __syncthreads();
    }
    if (idx < N_NODES) off[idx] = bbase[b] + s[t] - v;   // exclusive prefix
    if (idx == 0) off[N_NODES] = bbase[NPART];
}

// per fused-block node range via binary search (replaces dst_s array)
__global__ void k_rng(const int* __restrict__ off, int* __restrict__ blk) {
    int b = blockIdx.x * blockDim.x + threadIdx.x;
    if (b >= NBLK) return;
    int base = b * REB;
    int lo = 0, hi = N_NODES;
    while (lo < hi) { int mid = (lo + hi + 1) >> 1; if (off[mid] <= base) lo = mid; else hi = mid - 1; }
    blk[2 * b] = lo;
    int last = base + REB - 1;
    int hi2 = N_NODES;
    while (lo < hi2) { int mid = (lo + hi2 + 1) >> 1; if (off[mid] <= last) lo = mid; else hi2 = mid - 1; }
    blk[2 * b + 1] = lo;
}

// sorted 32B record per edge: [a0, a1, r2, shx, shy, shz, src_bits, 0]
__global__ void k_build(const int* __restrict__ ei, const float* __restrict__ ea,
                        const int* __restrict__ off, const int* __restrict__ rank,
                        float* __restrict__ es_s) {
    int e = blockIdx.x * 256 + threadIdx.x;
    int d = ei[N_EDGES + e];
    int pos = off[d] + rank[e];
    float a0 = ea[e * 5 + 0], a1 = ea[e * 5 + 1];
    float rx = ea[e * 5 + 2], ry = ea[e * 5 + 3], rz = ea[e * 5 + 4];
    float r2 = rx * rx + ry * ry + rz * rz;
    float inv = rsqrtf(fmaxf(r2, 1e-24f)) * SQRT3;
    float4* o = (float4*)(es_s + (size_t)pos * 8);
    o[0] = make_float4(a0, a1, r2, rx * inv);
    o[1] = make_float4(ry * inv, rz * inv, __int_as_float(ei[e]), 0.f);
}

// ---------------- per-node tpw transform: h2[n,v,i] = sum_u tpw[u,v] hin[n,u,i] ----------------
__global__ void k_h2(const float* __restrict__ hin, const float* __restrict__ tpw,
                     float* __restrict__ h2, float* __restrict__ dx) {
    int t = blockIdx.x * blockDim.x + threadIdx.x;
    if (t >= N_NODES * HID) return;
    int n = t / HID, c = t % HID, v = c / 3, i = c % 3;
    const float* hr = hin + (size_t)n * HID + i;
    float s = 0.f;
#pragma unroll
    for (int u = 0; u < 16; u++) s = fmaf(tpw[u * 16 + v], hr[u * 3], s);
    h2[t] = s;
    dx[t] = 0.f;
}

__global__ void k_h2_add(const float* __restrict__ hin, float* __restrict__ dxin,
                         const float* __restrict__ tpw,
                         float* __restrict__ h2, float* __restrict__ hout) {
    int t = blockIdx.x * blockDim.x + threadIdx.x;
    if (t >= N_NODES * HID) return;
    int n = t / HID, c = t % HID, v = c / 3, i = c % 3;
    size_t rb = (size_t)n * HID;
    const float* hr = hin + rb + i;
    const float* dr = dxin + rb + i;
    float s = 0.f;
#pragma unroll
    for (int u = 0; u < 16; u++) s = fmaf(tpw[u * 16 + v], hr[u * 3] + dr[u * 3], s);
    h2[t] = s;
    hout[t] = hin[t] + dxin[t];
    dxin[t] = 0.f;
}

// ---------------- fused: message compute + in-LDS segmented reduce -> dx ----------------
// Weights read directly from global with wave-uniform offsets (scalar-cache path);
// LDS holds only the 24-col half-message tile.
__global__ void __launch_bounds__(256) k_fused(
    const float* __restrict__ es_s, const int* __restrict__ off,
    const int* __restrict__ blk,
    const float* __restrict__ h2, float* __restrict__ dx,
    const float* __restrict__ m1w, const float* __restrict__ m1b,
    const float* __restrict__ m2w, const float* __restrict__ m2b)
{
    __shared__ float s_msg[REB][MPAD];

    int t = threadIdx.x;
    int base = blockIdx.x * REB;
    int e2 = base + t;

    // per-lane global loads issued first (latency buried under gate compute)
    const float4* esp = (const float4*)(es_s + (size_t)e2 * 8);
    float4 es0 = esp[0];                       // a0,a1,r2,shx
    float4 es1 = esp[1];                       // shy,shz,src,-
    int src = __float_as_int(es1.z);
    const float4* hv = (const float4*)(h2 + (size_t)src * HID);
    float xj[24];
    ((float4*)xj)[0] = hv[0]; ((float4*)xj)[1] = hv[1]; ((float4*)xj)[2] = hv[2];
    ((float4*)xj)[3] = hv[3]; ((float4*)xj)[4] = hv[4]; ((float4*)xj)[5] = hv[5];
    int n0 = blk[2 * blockIdx.x];
    int n1 = blk[2 * blockIdx.x + 1];

    float a0 = es0.x, a1 = es0.y, r2 = es0.z;
    float shx = es0.w, shy = es1.x, shz = es1.y;

    float hid[16];
#pragma unroll
    for (int j = 0; j < 16; j++) {
        float z = fmaf(a0, m1w[j], fmaf(a1, m1w[16 + j], fmaf(r2, m1w[32 + j], m1b[j])));
        hid[j] = z / (1.f + __expf(-z));
    }

    int gid = t / 12;            // 0..20 (21 groups); threads 252..255 idle in reduce
    int rem = t % 12;
    int q   = rem >> 1;          // float4 column 0..5
    int half= rem & 1;           // row-parity split, combined via shfl_xor(1)

    // ================= PASS A: channels v=0..7 (cols 0..23) =================
    float m[24];
#pragma unroll
    for (int qq = 0; qq < 6; qq++) {
        float4 b = *(const float4*)(m2b + qq * 4);
        m[qq * 4 + 0] = b.x; m[qq * 4 + 1] = b.y; m[qq * 4 + 2] = b.z; m[qq * 4 + 3] = b.w;
    }
#pragma unroll
    for (int j = 0; j < 16; j++) {
        float hj = hid[j];
#pragma unroll
        for (int qq = 0; qq < 6; qq++) {
            float4 w4 = *(const float4*)(m2w + j * 48 + qq * 4);
            m[qq * 4 + 0] = fmaf(hj, w4.x, m[qq * 4 + 0]);
            m[qq * 4 + 1] = fmaf(hj, w4.y, m[qq * 4 + 1]);
            m[qq * 4 + 2] = fmaf(hj, w4.z, m[qq * 4 + 2]);
            m[qq * 4 + 3] = fmaf(hj, w4.w, m[qq * 4 + 3]);
        }
    }
#pragma unroll
    for (int v = 0; v < 8; v++) {
        float x0 = xj[v * 3 + 0], x1 = xj[v * 3 + 1], x2 = xj[v * 3 + 2];
        float c0 = x1 * shz - x2 * shy;
        float c1 = x2 * shx - x0 * shz;
        float c2 = x0 * shy - x1 * shx;
        m[v * 3 + 0] *= c0 * TP_NORM;
        m[v * 3 + 1] *= c1 * TP_NORM;
        m[v * 3 + 2] *= c2 * TP_NORM;
    }
    {
        float4* row = (float4*)&s_msg[t][0];
#pragma unroll
        for (int qq = 0; qq < 6; qq++) row[qq] = ((float4*)m)[qq];
    }
    // prefetch pass-B half of the gather (overlaps reduce A)
    ((float4*)xj)[0] = hv[6];  ((float4*)xj)[1] = hv[7];  ((float4*)xj)[2] = hv[8];
    ((float4*)xj)[3] = hv[9];  ((float4*)xj)[4] = hv[10]; ((float4*)xj)[5] = hv[11];
    __syncthreads();

    if (t < 252) {
        for (int nn = n0 + gid; nn <= n1; nn += 21) {
            int lo = off[nn], hi = off[nn + 1];
            int rlo = (lo > base) ? lo - base : 0;
            int rhi = ((hi < base + REB) ? hi : base + REB) - base;
            if (rlo < rhi) {                     // same for both halves of a pair
                float4 acc = make_float4(0.f, 0.f, 0.f, 0.f);
                for (int r = rlo + half; r < rhi; r += 2) {
                    float4 v = *(const float4*)&s_msg[r][q * 4];
                    acc.x += v.x; acc.y += v.y; acc.z += v.z; acc.w += v.w;
                }
                acc.x += __shfl_xor(acc.x, 1);
                acc.y += __shfl_xor(acc.y, 1);
                acc.z += __shfl_xor(acc.z, 1);
                acc.w += __shfl_xor(acc.w, 1);
                if (half == 0) {
                    float* dp = dx + (size_t)nn * HID + q * 4;
                    if (lo < base || hi > base + REB) {
                        atomicAdd(dp + 0, acc.x); atomicAdd(dp + 1, acc.y);
                        atomicAdd(dp + 2, acc.z); atomicAdd(dp + 3, acc.w);
                    } else {
                        *(float4*)dp = acc;
                    }
                }
            }
        }
    }
    __syncthreads();

    // ================= PASS B: channels v=8..15 (cols 24..47) =================
#pragma unroll
    for (int qq = 0; qq < 6; qq++) {
        float4 b = *(const float4*)(m2b + 24 + qq * 4);
        m[qq * 4 + 0] = b.x; m[qq * 4 + 1] = b.y; m[qq * 4 + 2] = b.z; m[qq * 4 + 3] = b.w;
    }
#pragma unroll
    for (int j = 0; j < 16; j++) {
        float hj = hid[j];
#pragma unroll
        for (int qq = 0; qq < 6; qq++) {
            float4 w4 = *(const float4*)(m2w + j * 48 + 24 + qq * 4);
            m[qq * 4 + 0] = fmaf(hj, w4.x, m[qq * 4 + 0]);
            m[qq * 4 + 1] = fmaf(hj, w4.y, m[qq * 4 + 1]);
            m[qq * 4 + 2] = fmaf(hj, w4.z, m[qq * 4 + 2]);
            m[qq * 4 + 3] = fmaf(hj, w4.w, m[qq * 4 + 3]);
        }
    }
#pragma unroll
    for (int v = 0; v < 8; v++) {
        float x0 = xj[v * 3 + 0], x1 = xj[v * 3 + 1], x2 = xj[v * 3 + 2];
        float c0 = x1 * shz - x2 * shy;
        float c1 = x2 * shx - x0 * shz;
        float c2 = x0 * shy - x1 * shx;
        m[v * 3 + 0] *= c0 * TP_NORM;
        m[v * 3 + 1] *= c1 * TP_NORM;
        m[v * 3 + 2] *= c2 * TP_NORM;
    }
    {
        float4* row = (float4*)&s_msg[t][0];
#pragma unroll
        for (int qq = 0; qq < 6; qq++) row[qq] = ((float4*)m)[qq];
    }
    __syncthreads();

    if (t < 252) {
        for (int nn = n0 + gid; nn <= n1; nn += 21) {
            int lo = off[nn], hi = off[nn + 1];
            int rlo = (lo > base) ? lo - base : 0;
            int rhi = ((hi < base + REB) ? hi : base + REB) - base;
            if (rlo < rhi) {
                float4 acc = make_float4(0.f, 0.f, 0.f, 0.f);
                for (int r = rlo + half; r < rhi; r += 2) {
                    float4 v = *(const float4*)&s_msg[r][q * 4];
                    acc.x += v.x; acc.y += v.y; acc.z += v.z; acc.w += v.w;
                }
                acc.x += __shfl_xor(acc.x, 1);
                acc.y += __shfl_xor(acc.y, 1);
                acc.z += __shfl_xor(acc.z, 1);
                acc.w += __shfl_xor(acc.w, 1);
                if (half == 0) {
                    float* dp = dx + (size_t)nn * HID + 24 + q * 4;
                    if (lo < base || hi > base + REB) {
                        atomicAdd(dp + 0, acc.x); atomicAdd(dp + 1, acc.y);
                        atomicAdd(dp + 2, acc.z); atomicAdd(dp + 3, acc.w);
                    } else {
                        *(float4*)dp = acc;
                    }
                }
            }
        }
    }
}

// ---------------- h += dx; dx = 0 (fallback path only) ----------------
__global__ void k_add(float* __restrict__ h, float* __restrict__ dx) {
    int t = blockIdx.x * blockDim.x + threadIdx.x;
    if (t >= N_NODES * HID) return;
    h[t] += dx[t];
    dx[t] = 0.f;
}

// ---------------- pool: per-graph mean of ((h+dx) @ lin_w) ----------------
__global__ void __launch_bounds__(256) k_pool(
    const float* __restrict__ h, const float* __restrict__ dxin, const int* __restrict__ batch,
    const float* __restrict__ linw, float* __restrict__ gsum, float* __restrict__ gcnt)
{
    __shared__ float ss[N_GRAPHS];
    __shared__ float sc[N_GRAPHS];
    for (int i = threadIdx.x; i < N_GRAPHS; i += 256) { ss[i] = 0.f; sc[i] = 0.f; }
    __syncthreads();
    int n = blockIdx.x * 256 + threadIdx.x;
    if (n < N_NODES) {
        float s = 0.f;
        const float4* hv = (const float4*)(h + (size_t)n * HID);
        const float4* dv = (const float4*)(dxin + (size_t)n * HID);
#pragma unroll
        for (int qq = 0; qq < 12; qq++) {
            float4 v = hv[qq], d = dv[qq];
            s += (v.x + d.x) * linw[qq * 4 + 0] + (v.y + d.y) * linw[qq * 4 + 1]
               + (v.z + d.z) * linw[qq * 4 + 2] + (v.w + d.w) * linw[qq * 4 + 3];
        }
        int b = batch[n];
        atomicAdd(&ss[b], s);
        atomicAdd(&sc[b], 1.f);
    }
    __syncthreads();
    for (int i = threadIdx.x; i < N_GRAPHS; i += 256) {
        if (sc[i] != 0.f) {
            atomicAdd(&gsum[i], ss[i]);
            atomicAdd(&gcnt[i], sc[i]);
        }
    }
}

__global__ void k_final(const float* __restrict__ gsum, const float* __restrict__ gcnt,
                        const float* __restrict__ linb, float* __restrict__ out) {
    int g = threadIdx.x;
    if (g < N_GRAPHS) out[g] = gsum[g] / fmaxf(gcnt[g], 1.f) + linb[0];
}

// ---------------- fallback (round-1 proven atomic path) ----------------
__global__ void __launch_bounds__(256) k_edge_atomic(
    const int* __restrict__ ei, const float* __restrict__ ea,
    const float* __restrict__ h, float* __restrict__ dx,
    const float* __restrict__ m1w, const float* __restrict__ m1b,
    const float* __restrict__ m2w, const float* __restrict__ m2b,
    const float* __restrict__ tpw)
{
    __shared__ float s_m1w[48];
    __shared__ float s_m1b[16];
    __shared__ float s_m2w[768];
    __shared__ float s_m2b[48];
    __shared__ float s_tpw[256];
    for (int i = threadIdx.x; i < 48;  i += 256) s_m1w[i] = m1w[i];
    for (int i = threadIdx.x; i < 16;  i += 256) s_m1b[i] = m1b[i];
    for (int i = threadIdx.x; i < 768; i += 256) s_m2w[i] = m2w[i];
    for (int i = threadIdx.x; i < 48;  i += 256) s_m2b[i] = m2b[i];
    for (int i = threadIdx.x; i < 256; i += 256) s_tpw[i] = tpw[i];
    __syncthreads();
    int e = blockIdx.x * 256 + threadIdx.x;
    int src = ei[e];
    int dst = ei[N_EDGES + e];
    float a0 = ea[e * 5 + 0], a1 = ea[e * 5 + 1];
    float rx = ea[e * 5 + 2], ry = ea[e * 5 + 3], rz = ea[e * 5 + 4];
    float r2 = rx * rx + ry * ry + rz * rz;
    float inv = rsqrtf(fmaxf(r2, 1e-24f));
    float shx = SQRT3 * rx * inv, shy = SQRT3 * ry * inv, shz = SQRT3 * rz * inv;
    float hid[16];
#pragma unroll
    for (int j = 0; j < 16; j++) {
        float z = a0 * s_m1w[j] + a1 * s_m1w[16 + j] + r2 * s_m1w[32 + j] + s_m1b[j];
        hid[j] = z / (1.f + __expf(-z));
    }
    float xj[48];
    const float4* hv = (const float4*)(h + (size_t)src * HID);
#pragma unroll
    for (int qq = 0; qq < 12; qq++) {
        float4 v = hv[qq];
        xj[qq * 4 + 0] = v.x; xj[qq * 4 + 1] = v.y; xj[qq * 4 + 2] = v.z; xj[qq * 4 + 3] = v.w;
    }
    float cr[48];
#pragma unroll
    for (int u = 0; u < 16; u++) {
        float x0 = xj[u * 3 + 0], x1 = xj[u * 3 + 1], x2 = xj[u * 3 + 2];
        cr[u * 3 + 0] = x1 * shz - x2 * shy;
        cr[u * 3 + 1] = x2 * shx - x0 * shz;
        cr[u * 3 + 2] = x0 * shy - x1 * shx;
    }
    float* dd = dx + (size_t)dst * HID;
#pragma unroll
    for (int v = 0; v < 16; v++) {
        float t0 = 0.f, t1 = 0.f, t2 = 0.f;
#pragma unroll
        for (int u = 0; u < 16; u++) {
            float w = s_tpw[u * 16 + v];
            t0 += w * cr[u * 3 + 0];
            t1 += w * cr[u * 3 + 1];
            t2 += w * cr[u * 3 + 2];
        }
        float g0 = s_m2b[v * 3 + 0], g1 = s_m2b[v * 3 + 1], g2 = s_m2b[v * 3 + 2];
#pragma unroll
        for (int j = 0; j < 16; j++) {
            float hj = hid[j];
            g0 = fmaf(hj, s_m2w[j * 48 + v * 3 + 0], g0);
            g1 = fmaf(hj, s_m2w[j * 48 + v * 3 + 1], g1);
            g2 = fmaf(hj, s_m2w[j * 48 + v * 3 + 2], g2);
        }
        atomicAdd(dd + v * 3 + 0, g0 * t0 * TP_NORM);
        atomicAdd(dd + v * 3 + 1, g1 * t1 * TP_NORM);
        atomicAdd(dd + v * 3 + 2, g2 * t2 * TP_NORM);
    }
}

extern "C" void kernel_launch(void* const* d_in, const int* in_sizes, int n_in,
                              void* d_out, int out_size, void* d_ws, size_t ws_size,
                              hipStream_t stream) {
    const float* x    = (const float*)d_in[0];
    const int*   ei   = (const int*)  d_in[1];
    const float* ea   = (const float*)d_in[2];
    const int*   batch= (const int*)  d_in[3];
    const float* ew   = (const float*)d_in[4];
    const float* m1w  = (const float*)d_in[5];
    const float* m1b  = (const float*)d_in[6];
    const float* m2w  = (const float*)d_in[7];
    const float* m2b  = (const float*)d_in[8];
    const float* tpw  = (const float*)d_in[9];
    const float* linw = (const float*)d_in[10];
    const float* linb = (const float*)d_in[11];
    float* out = (float*)d_out;

    // -------- workspace layout (256B-aligned carve) --------
    char* w = (char*)d_ws;
    auto alloc = [&](size_t bytes) -> char* {
        char* p = w;
        w += (bytes + 255) & ~(size_t)255;
        return p;
    };
    float* hA   = (float*)alloc((size_t)N_NODES * HID * 4);
    float* hB   = (float*)alloc((size_t)N_NODES * HID * 4);
    float* h2   = (float*)alloc((size_t)N_NODES * HID * 4);
    float* dx   = (float*)alloc((size_t)N_NODES * HID * 4);
    float* gbuf = (float*)alloc(2 * N_GRAPHS * 4);
    float* es_s = (float*)alloc((size_t)N_EDGES * 8 * 4);
    int*   off  = (int*)  alloc((size_t)(N_NODES + 1) * 4);
    int*   cnt  = (int*)  alloc((size_t)N_NODES * 4);
    int*   rank = (int*)  alloc((size_t)N_EDGES * 4);
    int*   blk  = (int*)  alloc((size_t)NBLK * 2 * 4);
    int*   bsum = (int*)  alloc((size_t)NPART * 4);
    int*   bbase= (int*)  alloc((size_t)(NPART + 1) * 4);
    size_t need = (size_t)(w - (char*)d_ws);
    float* gsum = gbuf;
    float* gcnt = gbuf + N_GRAPHS;

    if (ws_size < need) {
        // -------- fallback: round-1 atomic path (needs 19.2MB + 512B) --------
        float* fh   = (float*)d_ws;
        float* fdx  = fh + (size_t)N_NODES * HID;
        float* fgs  = fdx + (size_t)N_NODES * HID;
        float* fgc  = fgs + N_GRAPHS;
        hipMemsetAsync(fdx, 0, ((size_t)N_NODES * HID + 2 * N_GRAPHS) * sizeof(float), stream);
        k_embed<<<(N_NODES * HID + 255) / 256, 256, 0, stream>>>(x, ew, fh);
        for (int l = 0; l < N_LAYERS; l++) {
            k_edge_atomic<<<N_EDGES / 256, 256, 0, stream>>>(ei, ea, fh, fdx,
                m1w + l * 48, m1b + l * 16, m2w + l * 768, m2b + l * 48, tpw + l * 256);
            k_add<<<(N_NODES * HID + 255) / 256, 256, 0, stream>>>(fh, fdx);
        }
        hipMemsetAsync(fdx, 0, (size_t)N_NODES * HID * 4, stream);
        k_pool<<<(N_NODES + 255) / 256, 256, 0, stream>>>(fh, fdx, batch, linw, fgs, fgc);
        k_final<<<1, 64, 0, stream>>>(fgs, fgc, linb, out);
        return;
    }

    // -------- CSR setup: one atomic pass + two-level scan --------
    hipMemsetAsync(cnt, 0, (size_t)N_NODES * 4, stream);
    hipMemsetAsync(gbuf, 0, 2 * N_GRAPHS * 4, stream);
    k_count<<<N_EDGES / 256, 256, 0, stream>>>(ei, cnt, rank);
    k_sred<<<NPART, 256, 0, stream>>>(cnt, bsum);
    k_sscan<<<1, 256, 0, stream>>>(bsum, bbase);
    k_soff<<<NPART, 256, 0, stream>>>(cnt, bbase, off);
    k_rng<<<(NBLK + 255) / 256, 256, 0, stream>>>(off, blk);
    k_build<<<N_EDGES / 256, 256, 0, stream>>>(ei, ea, off, rank, es_s);

    k_embed<<<(N_NODES * HID + 255) / 256, 256, 0, stream>>>(x, ew, hA);

    const int nhBlocks = (N_NODES * HID + 255) / 256;
    float* hcur = hA;
    float* hnxt = hB;
    for (int l = 0; l < N_LAYERS; l++) {
        if (l == 0) {
            k_h2<<<nhBlocks, 256, 0, stream>>>(hcur, tpw, h2, dx);
        } else {
            k_h2_add<<<nhBlocks, 256, 0, stream>>>(hcur, dx, tpw + l * 256, h2, hnxt);
            float* tmp = hcur; hcur = hnxt; hnxt = tmp;
        }
        k_fused<<<NBLK, 256, 0, stream>>>(es_s, off, blk, h2, dx,
            m1w + l * 48, m1b + l * 16, m2w + l * 768, m2b + l * 48);
    }

    // pool over h_final = hcur + dx (last layer's residual folded into pool)
    k_pool<<<(N_NODES + 255) / 256, 256, 0, stream>>>(hcur, dx, batch, linw, gsum, gcnt);
    k_final<<<1, 64, 0, stream>>>(gsum, gcnt, linb, out);
}

// Round 9
// 466.647 us; speedup vs baseline: 33.7406x; 1.0578x over previous
//
#include <hip/hip_runtime.h>

#define N_NODES 50000
#define N_EDGES 1600000
#define N_LAYERS 4
#define N_CH 16
#define HID 48            // N_CH * 3
#define N_GRAPHS 64
#define TP_NORM 0.17677669529663687f   // 1/sqrt(2*N_CH)
#define SQRT3 1.7320508075688772f
#define REB 256           // edges per block in fused kernel
#define MPAD 28           // LDS row stride (floats) for 24-col half-message
#define NBLK (N_EDGES / REB)
#define NPART ((N_NODES + 255) / 256)   // 196 scan partials

// bf16 pack/unpack (RNE pack; unpack is 1 bit-op per value)
__device__ __forceinline__ unsigned bfpack2(float a, float b) {
    unsigned ua = __float_as_uint(a);
    unsigned ub = __float_as_uint(b);
    ua = (ua + 0x7fffu + ((ua >> 16) & 1u)) >> 16;
    ub = (ub + 0x7fffu + ((ub >> 16) & 1u)) >> 16;
    return ua | (ub << 16);
}
#define BFLO(u) __uint_as_float((u) << 16)
#define BFHI(u) __uint_as_float((u) & 0xffff0000u)

// ---------------- embed: h = x @ embed_w ----------------
__global__ void k_embed(const float* __restrict__ x, const float* __restrict__ ew,
                        float* __restrict__ h) {
    int t = blockIdx.x * blockDim.x + threadIdx.x;
    if (t >= N_NODES * HID) return;
    int n = t / HID, c = t % HID;
    h[t] = x[n * 3 + 0] * ew[c] + x[n * 3 + 1] * ew[HID + c] + x[n * 3 + 2] * ew[2 * HID + c];
}

// ---------------- CSR build (single atomic pass) ----------------
__global__ void k_count(const int* __restrict__ ei, int* __restrict__ cnt,
                        int* __restrict__ rank) {
    int e = blockIdx.x * 256 + threadIdx.x;              // N_EDGES % 256 == 0
    rank[e] = atomicAdd(&cnt[ei[N_EDGES + e]], 1);
}

// ---- two-level scan of cnt -> off ----
__global__ void k_sred(const int* __restrict__ cnt, int* __restrict__ bsum) {
    __shared__ int red[256];
    int b = blockIdx.x, t = threadIdx.x;
    int idx = b * 256 + t;
    red[t] = (idx < N_NODES) ? cnt[idx] : 0;
    __syncthreads();
    for (int d = 128; d > 0; d >>= 1) {
        if (t < d) red[t] += red[t + d];
        __syncthreads();
    }
    if (t == 0) bsum[b] = red[0];
}

__global__ void k_sscan(const int* __restrict__ bsum, int* __restrict__ bbase) {
    __shared__ int s[256];
    int t = threadIdx.x;
    int v = (t < NPART) ? bsum[t] : 0;
    s[t] = v;
    __syncthreads();
    for (int d = 1; d < 256; d <<= 1) {
        int x = (t >= d) ? s[t - d] : 0;
        __syncthreads();
        s[t] += x;
        __syncthreads();
    }
    if (t < NPART) bbase[t] = s[t] - v;          // exclusive
    if (t == NPART - 1) bbase[NPART] = s[t];     // grand total (== N_EDGES)
}

__global__ void k_soff(const int* __restrict__ cnt, const int* __restrict__ bbase,
                       int* __restrict__ off) {
    __shared__ int s[256];
    int b = blockIdx.x, t = threadIdx.x;
    int idx = b * 256 + t;
    int v = (idx < N_NODES) ? cnt[idx] : 0;
    s[t] = v;
    __syncthreads();
    for (int d = 1; d < 256; d <<= 1) {
        int x = (t >= d) ? s[t - d] : 0;
        __syncthreads();
        s[t] += x;
        __syncthreads();
    }
    if (idx < N_NODES) off[idx] = bbase[b] + s[t] - v;   // exclusive prefix
    if (idx == 0) off[N_NODES] = bbase[NPART];
}

// per fused-block node range via binary search
__global__ void k_rng(const int* __restrict__ off, int* __restrict__ blk) {
    int b = blockIdx.x * blockDim.x + threadIdx.x;
    if (b >= NBLK) return;
    int base = b * REB;
    int lo = 0, hi = N_NODES;
    while (lo < hi) { int mid = (lo + hi + 1) >> 1; if (off[mid] <= base) lo = mid; else hi = mid - 1; }
    blk[2 * b] = lo;
    int last = base + REB - 1;
    int hi2 = N_NODES;
    while (lo < hi2) { int mid = (lo + hi2 + 1) >> 1; if (off[mid] <= last) lo = mid; else hi2 = mid - 1; }
    blk[2 * b + 1] = lo;
}

// sorted 32B record per edge: [a0, a1, r2, shx, shy, shz, src_bits, 0]
__global__ void k_build(const int* __restrict__ ei, const float* __restrict__ ea,
                        const int* __restrict__ off, const int* __restrict__ rank,
                        float* __restrict__ es_s) {
    int e = blockIdx.x * 256 + threadIdx.x;
    int d = ei[N_EDGES + e];
    int pos = off[d] + rank[e];
    float a0 = ea[e * 5 + 0], a1 = ea[e * 5 + 1];
    float rx = ea[e * 5 + 2], ry = ea[e * 5 + 3], rz = ea[e * 5 + 4];
    float r2 = rx * rx + ry * ry + rz * rz;
    float inv = rsqrtf(fmaxf(r2, 1e-24f)) * SQRT3;
    float4* o = (float4*)(es_s + (size_t)pos * 8);
    o[0] = make_float4(a0, a1, r2, rx * inv);
    o[1] = make_float4(ry * inv, rz * inv, __int_as_float(ei[e]), 0.f);
}

// ---------------- per-node tpw transform -> bf16 h2; zero dx ----------------
// thread per channel-pair: h2[n, 2p..2p+1] packed into one uint
__global__ void k_h2(const float* __restrict__ hin, const float* __restrict__ tpw,
                     unsigned* __restrict__ h2, float* __restrict__ dx) {
    int t = blockIdx.x * blockDim.x + threadIdx.x;
    if (t >= N_NODES * 24) return;
    int n = t / 24, p = t % 24;
    int c0 = 2 * p, c1 = c0 + 1;
    int v0 = c0 / 3, i0 = c0 % 3;
    int v1 = c1 / 3, i1 = c1 % 3;
    const float* hr = hin + (size_t)n * HID;
    float s0 = 0.f, s1 = 0.f;
#pragma unroll
    for (int u = 0; u < 16; u++) {
        s0 = fmaf(tpw[u * 16 + v0], hr[u * 3 + i0], s0);
        s1 = fmaf(tpw[u * 16 + v1], hr[u * 3 + i1], s1);
    }
    h2[t] = bfpack2(s0, s1);
    *(float2*)(dx + (size_t)n * HID + c0) = make_float2(0.f, 0.f);
}

// reads (hin + dxin) [both read-only], writes hout = hin+dxin, h2 bf16, zeroes dxout.
// dxin/dxout are DISJOINT ping-pong buffers (fixes prior in-place read/zero race).
__global__ void k_h2_add(const float* __restrict__ hin, const float* __restrict__ dxin,
                         const float* __restrict__ tpw,
                         unsigned* __restrict__ h2, float* __restrict__ hout,
                         float* __restrict__ dxout) {
    int t = blockIdx.x * blockDim.x + threadIdx.x;
    if (t >= N_NODES * 24) return;
    int n = t / 24, p = t % 24;
    int c0 = 2 * p, c1 = c0 + 1;
    int v0 = c0 / 3, i0 = c0 % 3;
    int v1 = c1 / 3, i1 = c1 % 3;
    size_t rb = (size_t)n * HID;
    const float* hr = hin + rb;
    const float* dr = dxin + rb;
    float s0 = 0.f, s1 = 0.f;
#pragma unroll
    for (int u = 0; u < 16; u++) {
        float e0 = hr[u * 3 + i0] + dr[u * 3 + i0];
        float e1 = hr[u * 3 + i1] + dr[u * 3 + i1];
        s0 = fmaf(tpw[u * 16 + v0], e0, s0);
        s1 = fmaf(tpw[u * 16 + v1], e1, s1);
    }
    h2[t] = bfpack2(s0, s1);
    float2 hv = *(const float2*)(hr + c0);
    float2 dv = *(const float2*)(dr + c0);
    *(float2*)(hout + rb + c0) = make_float2(hv.x + dv.x, hv.y + dv.y);
    *(float2*)(dxout + rb + c0) = make_float2(0.f, 0.f);
}

// ---------------- fused: message compute + in-LDS segmented reduce -> dx ----------------
// Weights via wave-uniform scalar-cache reads; h2 gathered as bf16 (halved bytes).
__global__ void __launch_bounds__(256) k_fused(
    const float* __restrict__ es_s, const int* __restrict__ off,
    const int* __restrict__ blk,
    const unsigned* __restrict__ h2, float* __restrict__ dx,
    const float* __restrict__ m1w, const float* __restrict__ m1b,
    const float* __restrict__ m2w, const float* __restrict__ m2b)
{
    __shared__ float s_msg[REB][MPAD];

    int t = threadIdx.x;
    int base = blockIdx.x * REB;
    int e2 = base + t;

    // per-lane global loads issued first (latency buried under gate compute)
    const float4* esp = (const float4*)(es_s + (size_t)e2 * 8);
    float4 es0 = esp[0];                       // a0,a1,r2,shx
    float4 es1 = esp[1];                       // shy,shz,src,-
    int src = __float_as_int(es1.z);
    const uint4* hv = (const uint4*)(h2 + (size_t)src * 24);   // 96B bf16 row
    uint4 A0 = hv[0], A1 = hv[1], A2 = hv[2];  // pass-A half (c 0..23)
    int n0 = blk[2 * blockIdx.x];
    int n1 = blk[2 * blockIdx.x + 1];

    float a0 = es0.x, a1 = es0.y, r2 = es0.z;
    float shx = es0.w, shy = es1.x, shz = es1.y;

    float hid[16];
#pragma unroll
    for (int j = 0; j < 16; j++) {
        float z = fmaf(a0, m1w[j], fmaf(a1, m1w[16 + j], fmaf(r2, m1w[32 + j], m1b[j])));
        hid[j] = z / (1.f + __expf(-z));
    }

    int gid = t / 12;            // 0..20 (21 groups); threads 252..255 idle in reduce
    int rem = t % 12;
    int q   = rem >> 1;          // float4 column 0..5
    int half= rem & 1;           // row-parity split, combined via shfl_xor(1)

    float xj[24];
#define UNPK8(u, d) { (d)[0]=BFLO((u).x); (d)[1]=BFHI((u).x); (d)[2]=BFLO((u).y); (d)[3]=BFHI((u).y); \
                      (d)[4]=BFLO((u).z); (d)[5]=BFHI((u).z); (d)[6]=BFLO((u).w); (d)[7]=BFHI((u).w); }
    UNPK8(A0, &xj[0]); UNPK8(A1, &xj[8]); UNPK8(A2, &xj[16]);

    // ================= PASS A: channels v=0..7 (cols 0..23) =================
    float m[24];
#pragma unroll
    for (int qq = 0; qq < 6; qq++) {
        float4 b = *(const float4*)(m2b + qq * 4);
        m[qq * 4 + 0] = b.x; m[qq * 4 + 1] = b.y; m[qq * 4 + 2] = b.z; m[qq * 4 + 3] = b.w;
    }
#pragma unroll
    for (int j = 0; j < 16; j++) {
        float hj = hid[j];
#pragma unroll
        for (int qq = 0; qq < 6; qq++) {
            float4 w4 = *(const float4*)(m2w + j * 48 + qq * 4);
            m[qq * 4 + 0] = fmaf(hj, w4.x, m[qq * 4 + 0]);
            m[qq * 4 + 1] = fmaf(hj, w4.y, m[qq * 4 + 1]);
            m[qq * 4 + 2] = fmaf(hj, w4.z, m[qq * 4 + 2]);
            m[qq * 4 + 3] = fmaf(hj, w4.w, m[qq * 4 + 3]);
        }
    }
#pragma unroll
    for (int v = 0; v < 8; v++) {
        float x0 = xj[v * 3 + 0], x1 = xj[v * 3 + 1], x2 = xj[v * 3 + 2];
        float c0 = x1 * shz - x2 * shy;
        float c1 = x2 * shx - x0 * shz;
        float c2 = x0 * shy - x1 * shx;
        m[v * 3 + 0] *= c0 * TP_NORM;
        m[v * 3 + 1] *= c1 * TP_NORM;
        m[v * 3 + 2] *= c2 * TP_NORM;
    }
    {
        float4* row = (float4*)&s_msg[t][0];
#pragma unroll
        for (int qq = 0; qq < 6; qq++) row[qq] = ((float4*)m)[qq];
    }
    // prefetch + unpack pass-B half (overlaps reduce A)
    {
        uint4 B0 = hv[3], B1 = hv[4], B2 = hv[5];
        UNPK8(B0, &xj[0]); UNPK8(B1, &xj[8]); UNPK8(B2, &xj[16]);
    }
    __syncthreads();

    if (t < 252) {
        for (int nn = n0 + gid; nn <= n1; nn += 21) {
            int lo = off[nn], hi = off[nn + 1];
            int rlo = (lo > base) ? lo - base : 0;
            int rhi = ((hi < base + REB) ? hi : base + REB) - base;
            if (rlo < rhi) {                     // same for both halves of a pair
                float4 acc = make_float4(0.f, 0.f, 0.f, 0.f);
                for (int r = rlo + half; r < rhi; r += 2) {
                    float4 v = *(const float4*)&s_msg[r][q * 4];
                    acc.x += v.x; acc.y += v.y; acc.z += v.z; acc.w += v.w;
                }
                acc.x += __shfl_xor(acc.x, 1);
                acc.y += __shfl_xor(acc.y, 1);
                acc.z += __shfl_xor(acc.z, 1);
                acc.w += __shfl_xor(acc.w, 1);
                if (half == 0) {
                    float* dp = dx + (size_t)nn * HID + q * 4;
                    if (lo < base || hi > base + REB) {
                        atomicAdd(dp + 0, acc.x); atomicAdd(dp + 1, acc.y);
                        atomicAdd(dp + 2, acc.z); atomicAdd(dp + 3, acc.w);
                    } else {
                        *(float4*)dp = acc;
                    }
                }
            }
        }
    }
    __syncthreads();

    // ================= PASS B: channels v=8..15 (cols 24..47) =================
#pragma unroll
    for (int qq = 0; qq < 6; qq++) {
        float4 b = *(const float4*)(m2b + 24 + qq * 4);
        m[qq * 4 + 0] = b.x; m[qq * 4 + 1] = b.y; m[qq * 4 + 2] = b.z; m[qq * 4 + 3] = b.w;
    }
#pragma unroll
    for (int j = 0; j < 16; j++) {
        float hj = hid[j];
#pragma unroll
        for (int qq = 0; qq < 6; qq++) {
            float4 w4 = *(const float4*)(m2w + j * 48 + 24 + qq * 4);
            m[qq * 4 + 0] = fmaf(hj, w4.x, m[qq * 4 + 0]);
            m[qq * 4 + 1] = fmaf(hj, w4.y, m[qq * 4 + 1]);
            m[qq * 4 + 2] = fmaf(hj, w4.z, m[qq * 4 + 2]);
            m[qq * 4 + 3] = fmaf(hj, w4.w, m[qq * 4 + 3]);
        }
    }
#pragma unroll
    for (int v = 0; v < 8; v++) {
        float x0 = xj[v * 3 + 0], x1 = xj[v * 3 + 1], x2 = xj[v * 3 + 2];
        float c0 = x1 * shz - x2 * shy;
        float c1 = x2 * shx - x0 * shz;
        float c2 = x0 * shy - x1 * shx;
        m[v * 3 + 0] *= c0 * TP_NORM;
        m[v * 3 + 1] *= c1 * TP_NORM;
        m[v * 3 + 2] *= c2 * TP_NORM;
    }
    {
        float4* row = (float4*)&s_msg[t][0];
#pragma unroll
        for (int qq = 0; qq < 6; qq++) row[qq] = ((float4*)m)[qq];
    }
    __syncthreads();

    if (t < 252) {
        for (int nn = n0 + gid; nn <= n1; nn += 21) {
            int lo = off[nn], hi = off[nn + 1];
            int rlo = (lo > base) ? lo - base : 0;
            int rhi = ((hi < base + REB) ? hi : base + REB) - base;
            if (rlo < rhi) {
                float4 acc = make_float4(0.f, 0.f, 0.f, 0.f);
                for (int r = rlo + half; r < rhi; r += 2) {
                    float4 v = *(const float4*)&s_msg[r][q * 4];
                    acc.x += v.x; acc.y += v.y; acc.z += v.z; acc.w += v.w;
                }
                acc.x += __shfl_xor(acc.x, 1);
                acc.y += __shfl_xor(acc.y, 1);
                acc.z += __shfl_xor(acc.z, 1);
                acc.w += __shfl_xor(acc.w, 1);
                if (half == 0) {
                    float* dp = dx + (size_t)nn * HID + 24 + q * 4;
                    if (lo < base || hi > base + REB) {
                        atomicAdd(dp + 0, acc.x); atomicAdd(dp + 1, acc.y);
                        atomicAdd(dp + 2, acc.z); atomicAdd(dp + 3, acc.w);
                    } else {
                        *(float4*)dp = acc;
                    }
                }
            }
        }
    }
}

// ---------------- h += dx; dx = 0 (fallback path only) ----------------
__global__ void k_add(float* __restrict__ h, float* __restrict__ dx) {
    int t = blockIdx.x * blockDim.x + threadIdx.x;
    if (t >= N_NODES * HID) return;
    h[t] += dx[t];
    dx[t] = 0.f;
}

// ---------------- pool: per-graph mean of ((h+dx) @ lin_w) ----------------
__global__ void __launch_bounds__(256) k_pool(
    const float* __restrict__ h, const float* __restrict__ dxin, const int* __restrict__ batch,
    const float* __restrict__ linw, float* __restrict__ gsum, float* __restrict__ gcnt)
{
    __shared__ float ss[N_GRAPHS];
    __shared__ float sc[N_GRAPHS];
    for (int i = threadIdx.x; i < N_GRAPHS; i += 256) { ss[i] = 0.f; sc[i] = 0.f; }
    __syncthreads();
    int n = blockIdx.x * 256 + threadIdx.x;
    if (n < N_NODES) {
        float s = 0.f;
        const float4* hv = (const float4*)(h + (size_t)n * HID);
        const float4* dv = (const float4*)(dxin + (size_t)n * HID);
#pragma unroll
        for (int qq = 0; qq < 12; qq++) {
            float4 v = hv[qq], d = dv[qq];
            s += (v.x + d.x) * linw[qq * 4 + 0] + (v.y + d.y) * linw[qq * 4 + 1]
               + (v.z + d.z) * linw[qq * 4 + 2] + (v.w + d.w) * linw[qq * 4 + 3];
        }
        int b = batch[n];
        atomicAdd(&ss[b], s);
        atomicAdd(&sc[b], 1.f);
    }
    __syncthreads();
    for (int i = threadIdx.x; i < N_GRAPHS; i += 256) {
        if (sc[i] != 0.f) {
            atomicAdd(&gsum[i], ss[i]);
            atomicAdd(&gcnt[i], sc[i]);
        }
    }
}

__global__ void k_final(const float* __restrict__ gsum, const float* __restrict__ gcnt,
                        const float* __restrict__ linb, float* __restrict__ out) {
    int g = threadIdx.x;
    if (g < N_GRAPHS) out[g] = gsum[g] / fmaxf(gcnt[g], 1.f) + linb[0];
}

// ---------------- fallback (round-1 proven atomic path) ----------------
__global__ void __launch_bounds__(256) k_edge_atomic(
    const int* __restrict__ ei, const float* __restrict__ ea,
    const float* __restrict__ h, float* __restrict__ dx,
    const float* __restrict__ m1w, const float* __restrict__ m1b,
    const float* __restrict__ m2w, const float* __restrict__ m2b,
    const float* __restrict__ tpw)
{
    __shared__ float s_m1w[48];
    __shared__ float s_m1b[16];
    __shared__ float s_m2w[768];
    __shared__ float s_m2b[48];
    __shared__ float s_tpw[256];
    for (int i = threadIdx.x; i < 48;  i += 256) s_m1w[i] = m1w[i];
    for (int i = threadIdx.x; i < 16;  i += 256) s_m1b[i] = m1b[i];
    for (int i = threadIdx.x; i < 768; i += 256) s_m2w[i] = m2w[i];
    for (int i = threadIdx.x; i < 48;  i += 256) s_m2b[i] = m2b[i];
    for (int i = threadIdx.x; i < 256; i += 256) s_tpw[i] = tpw[i];
    __syncthreads();
    int e = blockIdx.x * 256 + threadIdx.x;
    int src = ei[e];
    int dst = ei[N_EDGES + e];
    float a0 = ea[e * 5 + 0], a1 = ea[e * 5 + 1];
    float rx = ea[e * 5 + 2], ry = ea[e * 5 + 3], rz = ea[e * 5 + 4];
    float r2 = rx * rx + ry * ry + rz * rz;
    float inv = rsqrtf(fmaxf(r2, 1e-24f));
    float shx = SQRT3 * rx * inv, shy = SQRT3 * ry * inv, shz = SQRT3 * rz * inv;
    float hid[16];
#pragma unroll
    for (int j = 0; j < 16; j++) {
        float z = a0 * s_m1w[j] + a1 * s_m1w[16 + j] + r2 * s_m1w[32 + j] + s_m1b[j];
        hid[j] = z / (1.f + __expf(-z));
    }
    float xj[48];
    const float4* hv = (const float4*)(h + (size_t)src * HID);
#pragma unroll
    for (int qq = 0; qq < 12; qq++) {
        float4 v = hv[qq];
        xj[qq * 4 + 0] = v.x; xj[qq * 4 + 1] = v.y; xj[qq * 4 + 2] = v.z; xj[qq * 4 + 3] = v.w;
    }
    float cr[48];
#pragma unroll
    for (int u = 0; u < 16; u++) {
        float x0 = xj[u * 3 + 0], x1 = xj[u * 3 + 1], x2 = xj[u * 3 + 2];
        cr[u * 3 + 0] = x1 * shz - x2 * shy;
        cr[u * 3 + 1] = x2 * shx - x0 * shz;
        cr[u * 3 + 2] = x0 * shy - x1 * shx;
    }
    float* dd = dx + (size_t)dst * HID;
#pragma unroll
    for (int v = 0; v < 16; v++) {
        float t0 = 0.f, t1 = 0.f, t2 = 0.f;
#pragma unroll
        for (int u = 0; u < 16; u++) {
            float w = s_tpw[u * 16 + v];
            t0 += w * cr[u * 3 + 0];
            t1 += w * cr[u * 3 + 1];
            t2 += w * cr[u * 3 + 2];
        }
        float g0 = s_m2b[v * 3 + 0], g1 = s_m2b[v * 3 + 1], g2 = s_m2b[v * 3 + 2];
#pragma unroll
        for (int j = 0; j < 16; j++) {
            float hj = hid[j];
            g0 = fmaf(hj, s_m2w[j * 48 + v * 3 + 0], g0);
            g1 = fmaf(hj, s_m2w[j * 48 + v * 3 + 1], g1);
            g2 = fmaf(hj, s_m2w[j * 48 + v * 3 + 2], g2);
        }
        atomicAdd(dd + v * 3 + 0, g0 * t0 * TP_NORM);
        atomicAdd(dd + v * 3 + 1, g1 * t1 * TP_NORM);
        atomicAdd(dd + v * 3 + 2, g2 * t2 * TP_NORM);
    }
}

extern "C" void kernel_launch(void* const* d_in, const int* in_sizes, int n_in,
                              void* d_out, int out_size, void* d_ws, size_t ws_size,
                              hipStream_t stream) {
    const float* x    = (const float*)d_in[0];
    const int*   ei   = (const int*)  d_in[1];
    const float* ea   = (const float*)d_in[2];
    const int*   batch= (const int*)  d_in[3];
    const float* ew   = (const float*)d_in[4];
    const float* m1w  = (const float*)d_in[5];
    const float* m1b  = (const float*)d_in[6];
    const float* m2w  = (const float*)d_in[7];
    const float* m2b  = (const float*)d_in[8];
    const float* tpw  = (const float*)d_in[9];
    const float* linw = (const float*)d_in[10];
    const float* linb = (const float*)d_in[11];
    float* out = (float*)d_out;

    // -------- workspace layout (256B-aligned carve) --------
    char* w = (char*)d_ws;
    auto alloc = [&](size_t bytes) -> char* {
        char* p = w;
        w += (bytes + 255) & ~(size_t)255;
        return p;
    };
    float*    hA   = (float*)   alloc((size_t)N_NODES * HID * 4);
    float*    hB   = (float*)   alloc((size_t)N_NODES * HID * 4);
    unsigned* h2   = (unsigned*)alloc((size_t)N_NODES * 24 * 4);   // bf16-packed, 96B/row
    float*    dxA  = (float*)   alloc((size_t)N_NODES * HID * 4);
    float*    dxB  = (float*)   alloc((size_t)N_NODES * HID * 4);
    float*    gbuf = (float*)   alloc(2 * N_GRAPHS * 4);
    float*    es_s = (float*)   alloc((size_t)N_EDGES * 8 * 4);
    int*      off  = (int*)     alloc((size_t)(N_NODES + 1) * 4);
    int*      cnt  = (int*)     alloc((size_t)N_NODES * 4);
    int*      rank = (int*)     alloc((size_t)N_EDGES * 4);
    int*      blk  = (int*)     alloc((size_t)NBLK * 2 * 4);
    int*      bsum = (int*)     alloc((size_t)NPART * 4);
    int*      bbase= (int*)     alloc((size_t)(NPART + 1) * 4);
    size_t need = (size_t)(w - (char*)d_ws);
    float* gsum = gbuf;
    float* gcnt = gbuf + N_GRAPHS;

    if (ws_size < need) {
        // -------- fallback: round-1 atomic path (needs 19.2MB + 512B) --------
        float* fh   = (float*)d_ws;
        float* fdx  = fh + (size_t)N_NODES * HID;
        float* fgs  = fdx + (size_t)N_NODES * HID;
        float* fgc  = fgs + N_GRAPHS;
        hipMemsetAsync(fdx, 0, ((size_t)N_NODES * HID + 2 * N_GRAPHS) * sizeof(float), stream);
        k_embed<<<(N_NODES * HID + 255) / 256, 256, 0, stream>>>(x, ew, fh);
        for (int l = 0; l < N_LAYERS; l++) {
            k_edge_atomic<<<N_EDGES / 256, 256, 0, stream>>>(ei, ea, fh, fdx,
                m1w + l * 48, m1b + l * 16, m2w + l * 768, m2b + l * 48, tpw + l * 256);
            k_add<<<(N_NODES * HID + 255) / 256, 256, 0, stream>>>(fh, fdx);
        }
        hipMemsetAsync(fdx, 0, (size_t)N_NODES * HID * 4, stream);
        k_pool<<<(N_NODES + 255) / 256, 256, 0, stream>>>(fh, fdx, batch, linw, fgs, fgc);
        k_final<<<1, 64, 0, stream>>>(fgs, fgc, linb, out);
        return;
    }

    // -------- CSR setup: one atomic pass + two-level scan --------
    hipMemsetAsync(cnt, 0, (size_t)N_NODES * 4, stream);
    hipMemsetAsync(gbuf, 0, 2 * N_GRAPHS * 4, stream);
    k_count<<<N_EDGES / 256, 256, 0, stream>>>(ei, cnt, rank);
    k_sred<<<NPART, 256, 0, stream>>>(cnt, bsum);
    k_sscan<<<1, 256, 0, stream>>>(bsum, bbase);
    k_soff<<<NPART, 256, 0, stream>>>(cnt, bbase, off);
    k_rng<<<(NBLK + 255) / 256, 256, 0, stream>>>(off, blk);
    k_build<<<N_EDGES / 256, 256, 0, stream>>>(ei, ea, off, rank, es_s);

    k_embed<<<(N_NODES * HID + 255) / 256, 256, 0, stream>>>(x, ew, hA);

    const int npBlocks = (N_NODES * 24 + 255) / 256;
    float* dxs[2] = { dxA, dxB };
    float* hcur = hA;
    float* hnxt = hB;
    for (int l = 0; l < N_LAYERS; l++) {
        float* dxw = dxs[l & 1];
        if (l == 0) {
            k_h2<<<npBlocks, 256, 0, stream>>>(hcur, tpw, h2, dxw);
        } else {
            // read previous layer's dx, zero THIS layer's dx (disjoint buffers)
            k_h2_add<<<npBlocks, 256, 0, stream>>>(hcur, dxs[(l - 1) & 1], tpw + l * 256,
                                                   h2, hnxt, dxw);
            float* tmp = hcur; hcur = hnxt; hnxt = tmp;
        }
        k_fused<<<NBLK, 256, 0, stream>>>(es_s, off, blk, h2, dxw,
            m1w + l * 48, m1b + l * 16, m2w + l * 768, m2b + l * 48);
    }

    // pool over h_final = hcur + dx_last
    k_pool<<<(N_NODES + 255) / 256, 256, 0, stream>>>(hcur, dxs[(N_LAYERS - 1) & 1],
                                                      batch, linw, gsum, gcnt);
    k_final<<<1, 64, 0, stream>>>(gsum, gcnt, linb, out);
}

// Round 10
// 450.109 us; speedup vs baseline: 34.9803x; 1.0367x over previous
//
#include <hip/hip_runtime.h>

#define N_NODES 50000
#define N_EDGES 1600000
#define N_LAYERS 4
#define N_CH 16
#define HID 48            // N_CH * 3
#define N_GRAPHS 64
#define TP_NORM 0.17677669529663687f   // 1/sqrt(2*N_CH)
#define SQRT3 1.7320508075688772f
#define REB 256           // edges per block in fused kernel
#define MPAD 28           // LDS row stride (floats) for 24-col half-message
#define NBLK (N_EDGES / REB)
#define NPART ((N_NODES + 255) / 256)   // 196 scan partials

typedef float v2f __attribute__((ext_vector_type(2)));

// bf16 pack/unpack (RNE pack; unpack is 1 bit-op per value)
__device__ __forceinline__ unsigned bfpack2(float a, float b) {
    unsigned ua = __float_as_uint(a);
    unsigned ub = __float_as_uint(b);
    ua = (ua + 0x7fffu + ((ua >> 16) & 1u)) >> 16;
    ub = (ub + 0x7fffu + ((ub >> 16) & 1u)) >> 16;
    return ua | (ub << 16);
}
#define BFLO(u) __uint_as_float((u) << 16)
#define BFHI(u) __uint_as_float((u) & 0xffff0000u)

// ---------------- embed: h = x @ embed_w ----------------
__global__ void k_embed(const float* __restrict__ x, const float* __restrict__ ew,
                        float* __restrict__ h) {
    int t = blockIdx.x * blockDim.x + threadIdx.x;
    if (t >= N_NODES * HID) return;
    int n = t / HID, c = t % HID;
    h[t] = x[n * 3 + 0] * ew[c] + x[n * 3 + 1] * ew[HID + c] + x[n * 3 + 2] * ew[2 * HID + c];
}

// ---------------- CSR build (single atomic pass) ----------------
__global__ void k_count(const int* __restrict__ ei, int* __restrict__ cnt,
                        int* __restrict__ rank) {
    int e = blockIdx.x * 256 + threadIdx.x;              // N_EDGES % 256 == 0
    rank[e] = atomicAdd(&cnt[ei[N_EDGES + e]], 1);
}

// ---- two-level scan of cnt -> off ----
__global__ void k_sred(const int* __restrict__ cnt, int* __restrict__ bsum) {
    __shared__ int red[256];
    int b = blockIdx.x, t = threadIdx.x;
    int idx = b * 256 + t;
    red[t] = (idx < N_NODES) ? cnt[idx] : 0;
    __syncthreads();
    for (int d = 128; d > 0; d >>= 1) {
        if (t < d) red[t] += red[t + d];
        __syncthreads();
    }
    if (t == 0) bsum[b] = red[0];
}

__global__ void k_sscan(const int* __restrict__ bsum, int* __restrict__ bbase) {
    __shared__ int s[256];
    int t = threadIdx.x;
    int v = (t < NPART) ? bsum[t] : 0;
    s[t] = v;
    __syncthreads();
    for (int d = 1; d < 256; d <<= 1) {
        int x = (t >= d) ? s[t - d] : 0;
        __syncthreads();
        s[t] += x;
        __syncthreads();
    }
    if (t < NPART) bbase[t] = s[t] - v;          // exclusive
    if (t == NPART - 1) bbase[NPART] = s[t];     // grand total (== N_EDGES)
}

__global__ void k_soff(const int* __restrict__ cnt, const int* __restrict__ bbase,
                       int* __restrict__ off) {
    __shared__ int s[256];
    int b = blockIdx.x, t = threadIdx.x;
    int idx = b * 256 + t;
    int v = (idx < N_NODES) ? cnt[idx] : 0;
    s[t] = v;
    __syncthreads();
    for (int d = 1; d < 256; d <<= 1) {
        int x = (t >= d) ? s[t - d] : 0;
        __syncthreads();
        s[t] += x;
        __syncthreads();
    }
    if (idx < N_NODES) off[idx] = bbase[b] + s[t] - v;   // exclusive prefix
    if (idx == 0) off[N_NODES] = bbase[NPART];
}

// per fused-block node range via binary search
__global__ void k_rng(const int* __restrict__ off, int* __restrict__ blk) {
    int b = blockIdx.x * blockDim.x + threadIdx.x;
    if (b >= NBLK) return;
    int base = b * REB;
    int lo = 0, hi = N_NODES;
    while (lo < hi) { int mid = (lo + hi + 1) >> 1; if (off[mid] <= base) lo = mid; else hi = mid - 1; }
    blk[2 * b] = lo;
    int last = base + REB - 1;
    int hi2 = N_NODES;
    while (lo < hi2) { int mid = (lo + hi2 + 1) >> 1; if (off[mid] <= last) lo = mid; else hi2 = mid - 1; }
    blk[2 * b + 1] = lo;
}

// sorted 16B record per edge: [a0|a1, r2|shx, shy|shz (bf16 pairs), src]
__global__ void k_build(const int* __restrict__ ei, const float* __restrict__ ea,
                        const int* __restrict__ off, const int* __restrict__ rank,
                        uint4* __restrict__ es_s) {
    int e = blockIdx.x * 256 + threadIdx.x;
    int d = ei[N_EDGES + e];
    int pos = off[d] + rank[e];
    float a0 = ea[e * 5 + 0], a1 = ea[e * 5 + 1];
    float rx = ea[e * 5 + 2], ry = ea[e * 5 + 3], rz = ea[e * 5 + 4];
    float r2 = rx * rx + ry * ry + rz * rz;
    float inv = rsqrtf(fmaxf(r2, 1e-24f)) * SQRT3;
    uint4 o;
    o.x = bfpack2(a0, a1);
    o.y = bfpack2(r2, rx * inv);
    o.z = bfpack2(ry * inv, rz * inv);
    o.w = (unsigned)ei[e];
    es_s[pos] = o;
}

// ---------------- per-node tpw transform -> bf16 h2; zero dx ----------------
// thread per channel-pair: h2[n, 2p..2p+1] packed into one uint
__global__ void k_h2(const float* __restrict__ hin, const float* __restrict__ tpw,
                     unsigned* __restrict__ h2, float* __restrict__ dx) {
    int t = blockIdx.x * blockDim.x + threadIdx.x;
    if (t >= N_NODES * 24) return;
    int n = t / 24, p = t % 24;
    int c0 = 2 * p, c1 = c0 + 1;
    int v0 = c0 / 3, i0 = c0 % 3;
    int v1 = c1 / 3, i1 = c1 % 3;
    const float* hr = hin + (size_t)n * HID;
    float s0 = 0.f, s1 = 0.f;
#pragma unroll
    for (int u = 0; u < 16; u++) {
        s0 = fmaf(tpw[u * 16 + v0], hr[u * 3 + i0], s0);
        s1 = fmaf(tpw[u * 16 + v1], hr[u * 3 + i1], s1);
    }
    h2[t] = bfpack2(s0, s1);
    *(float2*)(dx + (size_t)n * HID + c0) = make_float2(0.f, 0.f);
}

// reads (hin + dxin) [both read-only], writes hout = hin+dxin, h2 bf16, zeroes dxout.
// dxin/dxout are DISJOINT ping-pong buffers.
__global__ void k_h2_add(const float* __restrict__ hin, const float* __restrict__ dxin,
                         const float* __restrict__ tpw,
                         unsigned* __restrict__ h2, float* __restrict__ hout,
                         float* __restrict__ dxout) {
    int t = blockIdx.x * blockDim.x + threadIdx.x;
    if (t >= N_NODES * 24) return;
    int n = t / 24, p = t % 24;
    int c0 = 2 * p, c1 = c0 + 1;
    int v0 = c0 / 3, i0 = c0 % 3;
    int v1 = c1 / 3, i1 = c1 % 3;
    size_t rb = (size_t)n * HID;
    const float* hr = hin + rb;
    const float* dr = dxin + rb;
    float s0 = 0.f, s1 = 0.f;
#pragma unroll
    for (int u = 0; u < 16; u++) {
        float e0 = hr[u * 3 + i0] + dr[u * 3 + i0];
        float e1 = hr[u * 3 + i1] + dr[u * 3 + i1];
        s0 = fmaf(tpw[u * 16 + v0], e0, s0);
        s1 = fmaf(tpw[u * 16 + v1], e1, s1);
    }
    h2[t] = bfpack2(s0, s1);
    float2 hv = *(const float2*)(hr + c0);
    float2 dv = *(const float2*)(dr + c0);
    *(float2*)(hout + rb + c0) = make_float2(hv.x + dv.x, hv.y + dv.y);
    *(float2*)(dxout + rb + c0) = make_float2(0.f, 0.f);
}

// ---------------- fused: message compute + in-LDS segmented reduce -> dx ----------------
// Weights via wave-uniform scalar-cache reads; h2 + edge records bf16;
// gate matmul in packed float2 fma (v_pk_fma_f32).
__global__ void __launch_bounds__(256) k_fused(
    const uint4* __restrict__ es_s, const int* __restrict__ off,
    const int* __restrict__ blk,
    const unsigned* __restrict__ h2, float* __restrict__ dx,
    const float* __restrict__ m1w, const float* __restrict__ m1b,
    const float* __restrict__ m2w, const float* __restrict__ m2b)
{
    __shared__ float s_msg[REB][MPAD];

    int t = threadIdx.x;
    int base = blockIdx.x * REB;
    int e2 = base + t;

    // per-lane global loads issued first (latency buried under gate compute)
    uint4 rec = es_s[e2];                      // 16B bf16 record
    int src = (int)rec.w;
    const uint4* hv = (const uint4*)(h2 + (size_t)src * 24);   // 96B bf16 row
    uint4 A0 = hv[0], A1 = hv[1], A2 = hv[2];  // pass-A half (c 0..23)
    int n0 = blk[2 * blockIdx.x];
    int n1 = blk[2 * blockIdx.x + 1];

    float a0 = BFLO(rec.x), a1 = BFHI(rec.x);
    float r2 = BFLO(rec.y), shx = BFHI(rec.y);
    float shy = BFLO(rec.z), shz = BFHI(rec.z);

    float hid[16];
#pragma unroll
    for (int j = 0; j < 16; j++) {
        float z = fmaf(a0, m1w[j], fmaf(a1, m1w[16 + j], fmaf(r2, m1w[32 + j], m1b[j])));
        hid[j] = z / (1.f + __expf(-z));
    }

    int gid = t / 12;            // 0..20 (21 groups); threads 252..255 idle in reduce
    int rem = t % 12;
    int q   = rem >> 1;          // float4 column 0..5
    int half= rem & 1;           // row-parity split, combined via shfl_xor(1)

    float xj[24];
#define UNPK8(u, d) { (d)[0]=BFLO((u).x); (d)[1]=BFHI((u).x); (d)[2]=BFLO((u).y); (d)[3]=BFHI((u).y); \
                      (d)[4]=BFLO((u).z); (d)[5]=BFHI((u).z); (d)[6]=BFLO((u).w); (d)[7]=BFHI((u).w); }
    UNPK8(A0, &xj[0]); UNPK8(A1, &xj[8]); UNPK8(A2, &xj[16]);

    alignas(16) v2f mv[12];
    float* m = (float*)mv;

    // ================= PASS A: channels v=0..7 (cols 0..23) =================
#pragma unroll
    for (int qq = 0; qq < 6; qq++) {
        float4 b = *(const float4*)(m2b + qq * 4);
        mv[2 * qq + 0] = (v2f){b.x, b.y};
        mv[2 * qq + 1] = (v2f){b.z, b.w};
    }
#pragma unroll
    for (int j = 0; j < 16; j++) {
        v2f hj2 = (v2f){hid[j], hid[j]};
#pragma unroll
        for (int qq = 0; qq < 6; qq++) {
            float4 w4 = *(const float4*)(m2w + j * 48 + qq * 4);
            mv[2 * qq + 0] = __builtin_elementwise_fma(hj2, (v2f){w4.x, w4.y}, mv[2 * qq + 0]);
            mv[2 * qq + 1] = __builtin_elementwise_fma(hj2, (v2f){w4.z, w4.w}, mv[2 * qq + 1]);
        }
    }
#pragma unroll
    for (int v = 0; v < 8; v++) {
        float x0 = xj[v * 3 + 0], x1 = xj[v * 3 + 1], x2 = xj[v * 3 + 2];
        float c0 = x1 * shz - x2 * shy;
        float c1 = x2 * shx - x0 * shz;
        float c2 = x0 * shy - x1 * shx;
        m[v * 3 + 0] *= c0 * TP_NORM;
        m[v * 3 + 1] *= c1 * TP_NORM;
        m[v * 3 + 2] *= c2 * TP_NORM;
    }
    {
        float4* row = (float4*)&s_msg[t][0];
#pragma unroll
        for (int qq = 0; qq < 6; qq++) row[qq] = ((float4*)m)[qq];
    }
    // prefetch + unpack pass-B half (overlaps reduce A)
    {
        uint4 B0 = hv[3], B1 = hv[4], B2 = hv[5];
        UNPK8(B0, &xj[0]); UNPK8(B1, &xj[8]); UNPK8(B2, &xj[16]);
    }
    __syncthreads();

    if (t < 252) {
        for (int nn = n0 + gid; nn <= n1; nn += 21) {
            int lo = off[nn], hi = off[nn + 1];
            int rlo = (lo > base) ? lo - base : 0;
            int rhi = ((hi < base + REB) ? hi : base + REB) - base;
            if (rlo < rhi) {                     // same for both halves of a pair
                float4 acc = make_float4(0.f, 0.f, 0.f, 0.f);
                for (int r = rlo + half; r < rhi; r += 2) {
                    float4 v = *(const float4*)&s_msg[r][q * 4];
                    acc.x += v.x; acc.y += v.y; acc.z += v.z; acc.w += v.w;
                }
                acc.x += __shfl_xor(acc.x, 1);
                acc.y += __shfl_xor(acc.y, 1);
                acc.z += __shfl_xor(acc.z, 1);
                acc.w += __shfl_xor(acc.w, 1);
                if (half == 0) {
                    float* dp = dx + (size_t)nn * HID + q * 4;
                    if (lo < base || hi > base + REB) {
                        atomicAdd(dp + 0, acc.x); atomicAdd(dp + 1, acc.y);
                        atomicAdd(dp + 2, acc.z); atomicAdd(dp + 3, acc.w);
                    } else {
                        *(float4*)dp = acc;
                    }
                }
            }
        }
    }
    __syncthreads();

    // ================= PASS B: channels v=8..15 (cols 24..47) =================
#pragma unroll
    for (int qq = 0; qq < 6; qq++) {
        float4 b = *(const float4*)(m2b + 24 + qq * 4);
        mv[2 * qq + 0] = (v2f){b.x, b.y};
        mv[2 * qq + 1] = (v2f){b.z, b.w};
    }
#pragma unroll
    for (int j = 0; j < 16; j++) {
        v2f hj2 = (v2f){hid[j], hid[j]};
#pragma unroll
        for (int qq = 0; qq < 6; qq++) {
            float4 w4 = *(const float4*)(m2w + j * 48 + 24 + qq * 4);
            mv[2 * qq + 0] = __builtin_elementwise_fma(hj2, (v2f){w4.x, w4.y}, mv[2 * qq + 0]);
            mv[2 * qq + 1] = __builtin_elementwise_fma(hj2, (v2f){w4.z, w4.w}, mv[2 * qq + 1]);
        }
    }
#pragma unroll
    for (int v = 0; v < 8; v++) {
        float x0 = xj[v * 3 + 0], x1 = xj[v * 3 + 1], x2 = xj[v * 3 + 2];
        float c0 = x1 * shz - x2 * shy;
        float c1 = x2 * shx - x0 * shz;
        float c2 = x0 * shy - x1 * shx;
        m[v * 3 + 0] *= c0 * TP_NORM;
        m[v * 3 + 1] *= c1 * TP_NORM;
        m[v * 3 + 2] *= c2 * TP_NORM;
    }
    {
        float4* row = (float4*)&s_msg[t][0];
#pragma unroll
        for (int qq = 0; qq < 6; qq++) row[qq] = ((float4*)m)[qq];
    }
    __syncthreads();

    if (t < 252) {
        for (int nn = n0 + gid; nn <= n1; nn += 21) {
            int lo = off[nn], hi = off[nn + 1];
            int rlo = (lo > base) ? lo - base : 0;
            int rhi = ((hi < base + REB) ? hi : base + REB) - base;
            if (rlo < rhi) {
                float4 acc = make_float4(0.f, 0.f, 0.f, 0.f);
                for (int r = rlo + half; r < rhi; r += 2) {
                    float4 v = *(const float4*)&s_msg[r][q * 4];
                    acc.x += v.x; acc.y += v.y; acc.z += v.z; acc.w += v.w;
                }
                acc.x += __shfl_xor(acc.x, 1);
                acc.y += __shfl_xor(acc.y, 1);
                acc.z += __shfl_xor(acc.z, 1);
                acc.w += __shfl_xor(acc.w, 1);
                if (half == 0) {
                    float* dp = dx + (size_t)nn * HID + 24 + q * 4;
                    if (lo < base || hi > base + REB) {
                        atomicAdd(dp + 0, acc.x); atomicAdd(dp + 1, acc.y);
                        atomicAdd(dp + 2, acc.z); atomicAdd(dp + 3, acc.w);
                    } else {
                        *(float4*)dp = acc;
                    }
                }
            }
        }
    }
}

// ---------------- h += dx; dx = 0 (fallback path only) ----------------
__global__ void k_add(float* __restrict__ h, float* __restrict__ dx) {
    int t = blockIdx.x * blockDim.x + threadIdx.x;
    if (t >= N_NODES * HID) return;
    h[t] += dx[t];
    dx[t] = 0.f;
}

// ---------------- pool: per-graph mean of ((h+dx) @ lin_w) ----------------
__global__ void __launch_bounds__(256) k_pool(
    const float* __restrict__ h, const float* __restrict__ dxin, const int* __restrict__ batch,
    const float* __restrict__ linw, float* __restrict__ gsum, float* __restrict__ gcnt)
{
    __shared__ float ss[N_GRAPHS];
    __shared__ float sc[N_GRAPHS];
    for (int i = threadIdx.x; i < N_GRAPHS; i += 256) { ss[i] = 0.f; sc[i] = 0.f; }
    __syncthreads();
    int n = blockIdx.x * 256 + threadIdx.x;
    if (n < N_NODES) {
        float s = 0.f;
        const float4* hv = (const float4*)(h + (size_t)n * HID);
        const float4* dv = (const float4*)(dxin + (size_t)n * HID);
#pragma unroll
        for (int qq = 0; qq < 12; qq++) {
            float4 v = hv[qq], d = dv[qq];
            s += (v.x + d.x) * linw[qq * 4 + 0] + (v.y + d.y) * linw[qq * 4 + 1]
               + (v.z + d.z) * linw[qq * 4 + 2] + (v.w + d.w) * linw[qq * 4 + 3];
        }
        int b = batch[n];
        atomicAdd(&ss[b], s);
        atomicAdd(&sc[b], 1.f);
    }
    __syncthreads();
    for (int i = threadIdx.x; i < N_GRAPHS; i += 256) {
        if (sc[i] != 0.f) {
            atomicAdd(&gsum[i], ss[i]);
            atomicAdd(&gcnt[i], sc[i]);
        }
    }
}

__global__ void k_final(const float* __restrict__ gsum, const float* __restrict__ gcnt,
                        const float* __restrict__ linb, float* __restrict__ out) {
    int g = threadIdx.x;
    if (g < N_GRAPHS) out[g] = gsum[g] / fmaxf(gcnt[g], 1.f) + linb[0];
}

// ---------------- fallback (round-1 proven atomic path) ----------------
__global__ void __launch_bounds__(256) k_edge_atomic(
    const int* __restrict__ ei, const float* __restrict__ ea,
    const float* __restrict__ h, float* __restrict__ dx,
    const float* __restrict__ m1w, const float* __restrict__ m1b,
    const float* __restrict__ m2w, const float* __restrict__ m2b,
    const float* __restrict__ tpw)
{
    __shared__ float s_m1w[48];
    __shared__ float s_m1b[16];
    __shared__ float s_m2w[768];
    __shared__ float s_m2b[48];
    __shared__ float s_tpw[256];
    for (int i = threadIdx.x; i < 48;  i += 256) s_m1w[i] = m1w[i];
    for (int i = threadIdx.x; i < 16;  i += 256) s_m1b[i] = m1b[i];
    for (int i = threadIdx.x; i < 768; i += 256) s_m2w[i] = m2w[i];
    for (int i = threadIdx.x; i < 48;  i += 256) s_m2b[i] = m2b[i];
    for (int i = threadIdx.x; i < 256; i += 256) s_tpw[i] = tpw[i];
    __syncthreads();
    int e = blockIdx.x * 256 + threadIdx.x;
    int src = ei[e];
    int dst = ei[N_EDGES + e];
    float a0 = ea[e * 5 + 0], a1 = ea[e * 5 + 1];
    float rx = ea[e * 5 + 2], ry = ea[e * 5 + 3], rz = ea[e * 5 + 4];
    float r2 = rx * rx + ry * ry + rz * rz;
    float inv = rsqrtf(fmaxf(r2, 1e-24f));
    float shx = SQRT3 * rx * inv, shy = SQRT3 * ry * inv, shz = SQRT3 * rz * inv;
    float hid[16];
#pragma unroll
    for (int j = 0; j < 16; j++) {
        float z = a0 * s_m1w[j] + a1 * s_m1w[16 + j] + r2 * s_m1w[32 + j] + s_m1b[j];
        hid[j] = z / (1.f + __expf(-z));
    }
    float xj[48];
    const float4* hv = (const float4*)(h + (size_t)src * HID);
#pragma unroll
    for (int qq = 0; qq < 12; qq++) {
        float4 v = hv[qq];
        xj[qq * 4 + 0] = v.x; xj[qq * 4 + 1] = v.y; xj[qq * 4 + 2] = v.z; xj[qq * 4 + 3] = v.w;
    }
    float cr[48];
#pragma unroll
    for (int u = 0; u < 16; u++) {
        float x0 = xj[u * 3 + 0], x1 = xj[u * 3 + 1], x2 = xj[u * 3 + 2];
        cr[u * 3 + 0] = x1 * shz - x2 * shy;
        cr[u * 3 + 1] = x2 * shx - x0 * shz;
        cr[u * 3 + 2] = x0 * shy - x1 * shx;
    }
    float* dd = dx + (size_t)dst * HID;
#pragma unroll
    for (int v = 0; v < 16; v++) {
        float t0 = 0.f, t1 = 0.f, t2 = 0.f;
#pragma unroll
        for (int u = 0; u < 16; u++) {
            float w = s_tpw[u * 16 + v];
            t0 += w * cr[u * 3 + 0];
            t1 += w * cr[u * 3 + 1];
            t2 += w * cr[u * 3 + 2];
        }
        float g0 = s_m2b[v * 3 + 0], g1 = s_m2b[v * 3 + 1], g2 = s_m2b[v * 3 + 2];
#pragma unroll
        for (int j = 0; j < 16; j++) {
            float hj = hid[j];
            g0 = fmaf(hj, s_m2w[j * 48 + v * 3 + 0], g0);
            g1 = fmaf(hj, s_m2w[j * 48 + v * 3 + 1], g1);
            g2 = fmaf(hj, s_m2w[j * 48 + v * 3 + 2], g2);
        }
        atomicAdd(dd + v * 3 + 0, g0 * t0 * TP_NORM);
        atomicAdd(dd + v * 3 + 1, g1 * t1 * TP_NORM);
        atomicAdd(dd + v * 3 + 2, g2 * t2 * TP_NORM);
    }
}

extern "C" void kernel_launch(void* const* d_in, const int* in_sizes, int n_in,
                              void* d_out, int out_size, void* d_ws, size_t ws_size,
                              hipStream_t stream) {
    const float* x    = (const float*)d_in[0];
    const int*   ei   = (const int*)  d_in[1];
    const float* ea   = (const float*)d_in[2];
    const int*   batch= (const int*)  d_in[3];
    const float* ew   = (const float*)d_in[4];
    const float* m1w  = (const float*)d_in[5];
    const float* m1b  = (const float*)d_in[6];
    const float* m2w  = (const float*)d_in[7];
    const float* m2b  = (const float*)d_in[8];
    const float* tpw  = (const float*)d_in[9];
    const float* linw = (const float*)d_in[10];
    const float* linb = (const float*)d_in[11];
    float* out = (float*)d_out;

    // -------- workspace layout (256B-aligned carve) --------
    char* w = (char*)d_ws;
    auto alloc = [&](size_t bytes) -> char* {
        char* p = w;
        w += (bytes + 255) & ~(size_t)255;
        return p;
    };
    float*    hA   = (float*)   alloc((size_t)N_NODES * HID * 4);
    float*    hB   = (float*)   alloc((size_t)N_NODES * HID * 4);
    unsigned* h2   = (unsigned*)alloc((size_t)N_NODES * 24 * 4);   // bf16-packed, 96B/row
    float*    dxA  = (float*)   alloc((size_t)N_NODES * HID * 4);
    float*    dxB  = (float*)   alloc((size_t)N_NODES * HID * 4);
    float*    gbuf = (float*)   alloc(2 * N_GRAPHS * 4);
    uint4*    es_s = (uint4*)   alloc((size_t)N_EDGES * 16);       // 16B bf16 records
    int*      off  = (int*)     alloc((size_t)(N_NODES + 1) * 4);
    int*      cnt  = (int*)     alloc((size_t)N_NODES * 4);
    int*      rank = (int*)     alloc((size_t)N_EDGES * 4);
    int*      blk  = (int*)     alloc((size_t)NBLK * 2 * 4);
    int*      bsum = (int*)     alloc((size_t)NPART * 4);
    int*      bbase= (int*)     alloc((size_t)(NPART + 1) * 4);
    size_t need = (size_t)(w - (char*)d_ws);
    float* gsum = gbuf;
    float* gcnt = gbuf + N_GRAPHS;

    if (ws_size < need) {
        // -------- fallback: round-1 atomic path (needs 19.2MB + 512B) --------
        float* fh   = (float*)d_ws;
        float* fdx  = fh + (size_t)N_NODES * HID;
        float* fgs  = fdx + (size_t)N_NODES * HID;
        float* fgc  = fgs + N_GRAPHS;
        hipMemsetAsync(fdx, 0, ((size_t)N_NODES * HID + 2 * N_GRAPHS) * sizeof(float), stream);
        k_embed<<<(N_NODES * HID + 255) / 256, 256, 0, stream>>>(x, ew, fh);
        for (int l = 0; l < N_LAYERS; l++) {
            k_edge_atomic<<<N_EDGES / 256, 256, 0, stream>>>(ei, ea, fh, fdx,
                m1w + l * 48, m1b + l * 16, m2w + l * 768, m2b + l * 48, tpw + l * 256);
            k_add<<<(N_NODES * HID + 255) / 256, 256, 0, stream>>>(fh, fdx);
        }
        hipMemsetAsync(fdx, 0, (size_t)N_NODES * HID * 4, stream);
        k_pool<<<(N_NODES + 255) / 256, 256, 0, stream>>>(fh, fdx, batch, linw, fgs, fgc);
        k_final<<<1, 64, 0, stream>>>(fgs, fgc, linb, out);
        return;
    }

    // -------- CSR setup: one atomic pass + two-level scan --------
    hipMemsetAsync(cnt, 0, (size_t)N_NODES * 4, stream);
    hipMemsetAsync(gbuf, 0, 2 * N_GRAPHS * 4, stream);
    k_count<<<N_EDGES / 256, 256, 0, stream>>>(ei, cnt, rank);
    k_sred<<<NPART, 256, 0, stream>>>(cnt, bsum);
    k_sscan<<<1, 256, 0, stream>>>(bsum, bbase);
    k_soff<<<NPART, 256, 0, stream>>>(cnt, bbase, off);
    k_rng<<<(NBLK + 255) / 256, 256, 0, stream>>>(off, blk);
    k_build<<<N_EDGES / 256, 256, 0, stream>>>(ei, ea, off, rank, es_s);

    k_embed<<<(N_NODES * HID + 255) / 256, 256, 0, stream>>>(x, ew, hA);

    const int npBlocks = (N_NODES * 24 + 255) / 256;
    float* dxs[2] = { dxA, dxB };
    float* hcur = hA;
    float* hnxt = hB;
    for (int l = 0; l < N_LAYERS; l++) {
        float* dxw = dxs[l & 1];
        if (l == 0) {
            k_h2<<<npBlocks, 256, 0, stream>>>(hcur, tpw, h2, dxw);
        } else {
            // read previous layer's dx, zero THIS layer's dx (disjoint buffers)
            k_h2_add<<<npBlocks, 256, 0, stream>>>(hcur, dxs[(l - 1) & 1], tpw + l * 256,
                                                   h2, hnxt, dxw);
            float* tmp = hcur; hcur = hnxt; hnxt = tmp;
        }
        k_fused<<<NBLK, 256, 0, stream>>>(es_s, off, blk, h2, dxw,
            m1w + l * 48, m1b + l * 16, m2w + l * 768, m2b + l * 48);
    }

    // pool over h_final = hcur + dx_last
    k_pool<<<(N_NODES + 255) / 256, 256, 0, stream>>>(hcur, dxs[(N_LAYERS - 1) & 1],
                                                      batch, linw, gsum, gcnt);
    k_final<<<1, 64, 0, stream>>>(gsum, gcnt, linb, out);
}

// Round 11
// 444.870 us; speedup vs baseline: 35.3923x; 1.0118x over previous
//
#include <hip/hip_runtime.h>

#define N_NODES 50000
#define N_EDGES 1600000
#define N_LAYERS 4
#define N_CH 16
#define HID 48            // N_CH * 3
#define N_GRAPHS 64
#define TP_NORM 0.17677669529663687f   // 1/sqrt(2*N_CH)
#define SQRT3 1.7320508075688772f
#define REB 256           // edges per block in fused kernel
#define MPAD 28           // LDS row stride (floats) for 24-col half-message
#define NBLK (N_EDGES / REB)
#define NPART ((N_NODES + 255) / 256)   // 196 scan partials

typedef float v2f __attribute__((ext_vector_type(2)));

// bf16 pack/unpack (RNE pack; unpack is 1 bit-op per value)
__device__ __forceinline__ unsigned bfpack2(float a, float b) {
    unsigned ua = __float_as_uint(a);
    unsigned ub = __float_as_uint(b);
    ua = (ua + 0x7fffu + ((ua >> 16) & 1u)) >> 16;
    ub = (ub + 0x7fffu + ((ub >> 16) & 1u)) >> 16;
    return ua | (ub << 16);
}
#define BFLO(u) __uint_as_float((u) << 16)
#define BFHI(u) __uint_as_float((u) & 0xffff0000u)

// ---------------- embed: h = x @ embed_w ----------------
__global__ void k_embed(const float* __restrict__ x, const float* __restrict__ ew,
                        float* __restrict__ h) {
    int t = blockIdx.x * blockDim.x + threadIdx.x;
    if (t >= N_NODES * HID) return;
    int n = t / HID, c = t % HID;
    h[t] = x[n * 3 + 0] * ew[c] + x[n * 3 + 1] * ew[HID + c] + x[n * 3 + 2] * ew[2 * HID + c];
}

// ---------------- CSR build: byte-packed counters (max degree ~58 << 255) ----------------
// 4 counters per 32-bit word -> atomic sector writeback 51MB -> ~13MB
__global__ void k_count(const int* __restrict__ ei, unsigned* __restrict__ cnt32,
                        unsigned char* __restrict__ rank8) {
    int e = blockIdx.x * 256 + threadIdx.x;              // N_EDGES % 256 == 0
    int d = ei[N_EDGES + e];
    int sh = 8 * (d & 3);
    unsigned old = atomicAdd(&cnt32[d >> 2], 1u << sh);
    rank8[e] = (unsigned char)((old >> sh) & 0xffu);
}

// ---- two-level scan of byte counters -> off ----
__global__ void k_sred(const unsigned char* __restrict__ cnt8, int* __restrict__ bsum) {
    __shared__ int red[256];
    int b = blockIdx.x, t = threadIdx.x;
    int idx = b * 256 + t;
    red[t] = (idx < N_NODES) ? (int)cnt8[idx] : 0;
    __syncthreads();
    for (int d = 128; d > 0; d >>= 1) {
        if (t < d) red[t] += red[t + d];
        __syncthreads();
    }
    if (t == 0) bsum[b] = red[0];
}

__global__ void k_sscan(const int* __restrict__ bsum, int* __restrict__ bbase) {
    __shared__ int s[256];
    int t = threadIdx.x;
    int v = (t < NPART) ? bsum[t] : 0;
    s[t] = v;
    __syncthreads();
    for (int d = 1; d < 256; d <<= 1) {
        int x = (t >= d) ? s[t - d] : 0;
        __syncthreads();
        s[t] += x;
        __syncthreads();
    }
    if (t < NPART) bbase[t] = s[t] - v;          // exclusive
    if (t == NPART - 1) bbase[NPART] = s[t];     // grand total (== N_EDGES)
}

__global__ void k_soff(const unsigned char* __restrict__ cnt8, const int* __restrict__ bbase,
                       int* __restrict__ off) {
    __shared__ int s[256];
    int b = blockIdx.x, t = threadIdx.x;
    int idx = b * 256 + t;
    int v = (idx < N_NODES) ? (int)cnt8[idx] : 0;
    s[t] = v;
    __syncthreads();
    for (int d = 1; d < 256; d <<= 1) {
        int x = (t >= d) ? s[t - d] : 0;
        __syncthreads();
        s[t] += x;
        __syncthreads();
    }
    if (idx < N_NODES) off[idx] = bbase[b] + s[t] - v;   // exclusive prefix
    if (idx == 0) off[N_NODES] = bbase[NPART];
}

// per fused-block node range via binary search
__global__ void k_rng(const int* __restrict__ off, int* __restrict__ blk) {
    int b = blockIdx.x * blockDim.x + threadIdx.x;
    if (b >= NBLK) return;
    int base = b * REB;
    int lo = 0, hi = N_NODES;
    while (lo < hi) { int mid = (lo + hi + 1) >> 1; if (off[mid] <= base) lo = mid; else hi = mid - 1; }
    blk[2 * b] = lo;
    int last = base + REB - 1;
    int hi2 = N_NODES;
    while (lo < hi2) { int mid = (lo + hi2 + 1) >> 1; if (off[mid] <= last) lo = mid; else hi2 = mid - 1; }
    blk[2 * b + 1] = lo;
}

// sorted 16B record per edge: [a0|a1, r2|shx, shy|shz (bf16 pairs), src]
__global__ void k_build(const int* __restrict__ ei, const float* __restrict__ ea,
                        const int* __restrict__ off, const unsigned char* __restrict__ rank8,
                        uint4* __restrict__ es_s) {
    int e = blockIdx.x * 256 + threadIdx.x;
    int d = ei[N_EDGES + e];
    int pos = off[d] + (int)rank8[e];
    float a0 = ea[e * 5 + 0], a1 = ea[e * 5 + 1];
    float rx = ea[e * 5 + 2], ry = ea[e * 5 + 3], rz = ea[e * 5 + 4];
    float r2 = rx * rx + ry * ry + rz * rz;
    float inv = rsqrtf(fmaxf(r2, 1e-24f)) * SQRT3;
    uint4 o;
    o.x = bfpack2(a0, a1);
    o.y = bfpack2(r2, rx * inv);
    o.z = bfpack2(ry * inv, rz * inv);
    o.w = (unsigned)ei[e];
    es_s[pos] = o;
}

// ---------------- per-node tpw transform -> bf16 h2; zero dx ----------------
__global__ void k_h2(const float* __restrict__ hin, const float* __restrict__ tpw,
                     unsigned* __restrict__ h2, float* __restrict__ dx) {
    int t = blockIdx.x * blockDim.x + threadIdx.x;
    if (t >= N_NODES * 24) return;
    int n = t / 24, p = t % 24;
    int c0 = 2 * p, c1 = c0 + 1;
    int v0 = c0 / 3, i0 = c0 % 3;
    int v1 = c1 / 3, i1 = c1 % 3;
    const float* hr = hin + (size_t)n * HID;
    float s0 = 0.f, s1 = 0.f;
#pragma unroll
    for (int u = 0; u < 16; u++) {
        s0 = fmaf(tpw[u * 16 + v0], hr[u * 3 + i0], s0);
        s1 = fmaf(tpw[u * 16 + v1], hr[u * 3 + i1], s1);
    }
    h2[t] = bfpack2(s0, s1);
    *(float2*)(dx + (size_t)n * HID + c0) = make_float2(0.f, 0.f);
}

// reads (hin + dxin) [both read-only], writes hout = hin+dxin, h2 bf16, zeroes dxout.
// dxin/dxout are DISJOINT ping-pong buffers.
__global__ void k_h2_add(const float* __restrict__ hin, const float* __restrict__ dxin,
                         const float* __restrict__ tpw,
                         unsigned* __restrict__ h2, float* __restrict__ hout,
                         float* __restrict__ dxout) {
    int t = blockIdx.x * blockDim.x + threadIdx.x;
    if (t >= N_NODES * 24) return;
    int n = t / 24, p = t % 24;
    int c0 = 2 * p, c1 = c0 + 1;
    int v0 = c0 / 3, i0 = c0 % 3;
    int v1 = c1 / 3, i1 = c1 % 3;
    size_t rb = (size_t)n * HID;
    const float* hr = hin + rb;
    const float* dr = dxin + rb;
    float s0 = 0.f, s1 = 0.f;
#pragma unroll
    for (int u = 0; u < 16; u++) {
        float e0 = hr[u * 3 + i0] + dr[u * 3 + i0];
        float e1 = hr[u * 3 + i1] + dr[u * 3 + i1];
        s0 = fmaf(tpw[u * 16 + v0], e0, s0);
        s1 = fmaf(tpw[u * 16 + v1], e1, s1);
    }
    h2[t] = bfpack2(s0, s1);
    float2 hv = *(const float2*)(hr + c0);
    float2 dv = *(const float2*)(dr + c0);
    *(float2*)(hout + rb + c0) = make_float2(hv.x + dv.x, hv.y + dv.y);
    *(float2*)(dxout + rb + c0) = make_float2(0.f, 0.f);
}

// ---------------- fused: message compute + in-LDS segmented reduce -> dx ----------------
// Reduce mapping: 10 node-groups x 6 float4-cols x 4-way row split (240 active threads;
// a 256-edge block spans ~8-9 nodes, so 10 groups cover the span in one iteration).
__global__ void __launch_bounds__(256) k_fused(
    const uint4* __restrict__ es_s, const int* __restrict__ off,
    const int* __restrict__ blk,
    const unsigned* __restrict__ h2, float* __restrict__ dx,
    const float* __restrict__ m1w, const float* __restrict__ m1b,
    const float* __restrict__ m2w, const float* __restrict__ m2b)
{
    __shared__ float s_msg[REB][MPAD];

    int t = threadIdx.x;
    int base = blockIdx.x * REB;
    int e2 = base + t;

    // per-lane global loads issued first (latency buried under gate compute)
    uint4 rec = es_s[e2];                      // 16B bf16 record
    int src = (int)rec.w;
    const uint4* hv = (const uint4*)(h2 + (size_t)src * 24);   // 96B bf16 row
    uint4 A0 = hv[0], A1 = hv[1], A2 = hv[2];  // pass-A half (c 0..23)
    int n0 = blk[2 * blockIdx.x];
    int n1 = blk[2 * blockIdx.x + 1];

    float a0 = BFLO(rec.x), a1 = BFHI(rec.x);
    float r2 = BFLO(rec.y), shx = BFHI(rec.y);
    float shy = BFLO(rec.z), shz = BFHI(rec.z);

    float hid[16];
#pragma unroll
    for (int j = 0; j < 16; j++) {
        float z = fmaf(a0, m1w[j], fmaf(a1, m1w[16 + j], fmaf(r2, m1w[32 + j], m1b[j])));
        hid[j] = z / (1.f + __expf(-z));
    }

    int gid = t / 24;            // 0..9 (10 groups); threads 240..255 idle in reduce
    int rem = t % 24;
    int q    = rem >> 2;         // float4 column 0..5
    int quad = rem & 3;          // 4-way row split; quads never straddle waves (4|64)

    float xj[24];
#define UNPK8(u, d) { (d)[0]=BFLO((u).x); (d)[1]=BFHI((u).x); (d)[2]=BFLO((u).y); (d)[3]=BFHI((u).y); \
                      (d)[4]=BFLO((u).z); (d)[5]=BFHI((u).z); (d)[6]=BFLO((u).w); (d)[7]=BFHI((u).w); }
    UNPK8(A0, &xj[0]); UNPK8(A1, &xj[8]); UNPK8(A2, &xj[16]);

    alignas(16) v2f mv[12];
    float* m = (float*)mv;

    // ================= PASS A: channels v=0..7 (cols 0..23) =================
#pragma unroll
    for (int qq = 0; qq < 6; qq++) {
        float4 b = *(const float4*)(m2b + qq * 4);
        mv[2 * qq + 0] = (v2f){b.x, b.y};
        mv[2 * qq + 1] = (v2f){b.z, b.w};
    }
#pragma unroll
    for (int j = 0; j < 16; j++) {
        v2f hj2 = (v2f){hid[j], hid[j]};
#pragma unroll
        for (int qq = 0; qq < 6; qq++) {
            float4 w4 = *(const float4*)(m2w + j * 48 + qq * 4);
            mv[2 * qq + 0] = __builtin_elementwise_fma(hj2, (v2f){w4.x, w4.y}, mv[2 * qq + 0]);
            mv[2 * qq + 1] = __builtin_elementwise_fma(hj2, (v2f){w4.z, w4.w}, mv[2 * qq + 1]);
        }
    }
#pragma unroll
    for (int v = 0; v < 8; v++) {
        float x0 = xj[v * 3 + 0], x1 = xj[v * 3 + 1], x2 = xj[v * 3 + 2];
        float c0 = x1 * shz - x2 * shy;
        float c1 = x2 * shx - x0 * shz;
        float c2 = x0 * shy - x1 * shx;
        m[v * 3 + 0] *= c0 * TP_NORM;
        m[v * 3 + 1] *= c1 * TP_NORM;
        m[v * 3 + 2] *= c2 * TP_NORM;
    }
    {
        float4* row = (float4*)&s_msg[t][0];
#pragma unroll
        for (int qq = 0; qq < 6; qq++) row[qq] = ((float4*)m)[qq];
    }
    // prefetch + unpack pass-B half (overlaps reduce A)
    {
        uint4 B0 = hv[3], B1 = hv[4], B2 = hv[5];
        UNPK8(B0, &xj[0]); UNPK8(B1, &xj[8]); UNPK8(B2, &xj[16]);
    }
    __syncthreads();

    if (t < 240) {
        for (int nn = n0 + gid; nn <= n1; nn += 10) {
            int lo = off[nn], hi = off[nn + 1];
            int rlo = (lo > base) ? lo - base : 0;
            int rhi = ((hi < base + REB) ? hi : base + REB) - base;
            if (rlo < rhi) {                     // same for all 4 quads of a group
                float4 acc = make_float4(0.f, 0.f, 0.f, 0.f);
                for (int r = rlo + quad; r < rhi; r += 4) {
                    float4 v = *(const float4*)&s_msg[r][q * 4];
                    acc.x += v.x; acc.y += v.y; acc.z += v.z; acc.w += v.w;
                }
                acc.x += __shfl_xor(acc.x, 1); acc.y += __shfl_xor(acc.y, 1);
                acc.z += __shfl_xor(acc.z, 1); acc.w += __shfl_xor(acc.w, 1);
                acc.x += __shfl_xor(acc.x, 2); acc.y += __shfl_xor(acc.y, 2);
                acc.z += __shfl_xor(acc.z, 2); acc.w += __shfl_xor(acc.w, 2);
                if (quad == 0) {
                    float* dp = dx + (size_t)nn * HID + q * 4;
                    if (lo < base || hi > base + REB) {
                        atomicAdd(dp + 0, acc.x); atomicAdd(dp + 1, acc.y);
                        atomicAdd(dp + 2, acc.z); atomicAdd(dp + 3, acc.w);
                    } else {
                        *(float4*)dp = acc;
                    }
                }
            }
        }
    }
    __syncthreads();

    // ================= PASS B: channels v=8..15 (cols 24..47) =================
#pragma unroll
    for (int qq = 0; qq < 6; qq++) {
        float4 b = *(const float4*)(m2b + 24 + qq * 4);
        mv[2 * qq + 0] = (v2f){b.x, b.y};
        mv[2 * qq + 1] = (v2f){b.z, b.w};
    }
#pragma unroll
    for (int j = 0; j < 16; j++) {
        v2f hj2 = (v2f){hid[j], hid[j]};
#pragma unroll
        for (int qq = 0; qq < 6; qq++) {
            float4 w4 = *(const float4*)(m2w + j * 48 + 24 + qq * 4);
            mv[2 * qq + 0] = __builtin_elementwise_fma(hj2, (v2f){w4.x, w4.y}, mv[2 * qq + 0]);
            mv[2 * qq + 1] = __builtin_elementwise_fma(hj2, (v2f){w4.z, w4.w}, mv[2 * qq + 1]);
        }
    }
#pragma unroll
    for (int v = 0; v < 8; v++) {
        float x0 = xj[v * 3 + 0], x1 = xj[v * 3 + 1], x2 = xj[v * 3 + 2];
        float c0 = x1 * shz - x2 * shy;
        float c1 = x2 * shx - x0 * shz;
        float c2 = x0 * shy - x1 * shx;
        m[v * 3 + 0] *= c0 * TP_NORM;
        m[v * 3 + 1] *= c1 * TP_NORM;
        m[v * 3 + 2] *= c2 * TP_NORM;
    }
    {
        float4* row = (float4*)&s_msg[t][0];
#pragma unroll
        for (int qq = 0; qq < 6; qq++) row[qq] = ((float4*)m)[qq];
    }
    __syncthreads();

    if (t < 240) {
        for (int nn = n0 + gid; nn <= n1; nn += 10) {
            int lo = off[nn], hi = off[nn + 1];
            int rlo = (lo > base) ? lo - base : 0;
            int rhi = ((hi < base + REB) ? hi : base + REB) - base;
            if (rlo < rhi) {
                float4 acc = make_float4(0.f, 0.f, 0.f, 0.f);
                for (int r = rlo + quad; r < rhi; r += 4) {
                    float4 v = *(const float4*)&s_msg[r][q * 4];
                    acc.x += v.x; acc.y += v.y; acc.z += v.z; acc.w += v.w;
                }
                acc.x += __shfl_xor(acc.x, 1); acc.y += __shfl_xor(acc.y, 1);
                acc.z += __shfl_xor(acc.z, 1); acc.w += __shfl_xor(acc.w, 1);
                acc.x += __shfl_xor(acc.x, 2); acc.y += __shfl_xor(acc.y, 2);
                acc.z += __shfl_xor(acc.z, 2); acc.w += __shfl_xor(acc.w, 2);
                if (quad == 0) {
                    float* dp = dx + (size_t)nn * HID + 24 + q * 4;
                    if (lo < base || hi > base + REB) {
                        atomicAdd(dp + 0, acc.x); atomicAdd(dp + 1, acc.y);
                        atomicAdd(dp + 2, acc.z); atomicAdd(dp + 3, acc.w);
                    } else {
                        *(float4*)dp = acc;
                    }
                }
            }
        }
    }
}

// ---------------- h += dx; dx = 0 (fallback path only) ----------------
__global__ void k_add(float* __restrict__ h, float* __restrict__ dx) {
    int t = blockIdx.x * blockDim.x + threadIdx.x;
    if (t >= N_NODES * HID) return;
    h[t] += dx[t];
    dx[t] = 0.f;
}

// ---------------- pool: per-graph mean of ((h+dx) @ lin_w) ----------------
__global__ void __launch_bounds__(256) k_pool(
    const float* __restrict__ h, const float* __restrict__ dxin, const int* __restrict__ batch,
    const float* __restrict__ linw, float* __restrict__ gsum, float* __restrict__ gcnt)
{
    __shared__ float ss[N_GRAPHS];
    __shared__ float sc[N_GRAPHS];
    for (int i = threadIdx.x; i < N_GRAPHS; i += 256) { ss[i] = 0.f; sc[i] = 0.f; }
    __syncthreads();
    int n = blockIdx.x * 256 + threadIdx.x;
    if (n < N_NODES) {
        float s = 0.f;
        const float4* hv = (const float4*)(h + (size_t)n * HID);
        const float4* dv = (const float4*)(dxin + (size_t)n * HID);
#pragma unroll
        for (int qq = 0; qq < 12; qq++) {
            float4 v = hv[qq], d = dv[qq];
            s += (v.x + d.x) * linw[qq * 4 + 0] + (v.y + d.y) * linw[qq * 4 + 1]
               + (v.z + d.z) * linw[qq * 4 + 2] + (v.w + d.w) * linw[qq * 4 + 3];
        }
        int b = batch[n];
        atomicAdd(&ss[b], s);
        atomicAdd(&sc[b], 1.f);
    }
    __syncthreads();
    for (int i = threadIdx.x; i < N_GRAPHS; i += 256) {
        if (sc[i] != 0.f) {
            atomicAdd(&gsum[i], ss[i]);
            atomicAdd(&gcnt[i], sc[i]);
        }
    }
}

__global__ void k_final(const float* __restrict__ gsum, const float* __restrict__ gcnt,
                        const float* __restrict__ linb, float* __restrict__ out) {
    int g = threadIdx.x;
    if (g < N_GRAPHS) out[g] = gsum[g] / fmaxf(gcnt[g], 1.f) + linb[0];
}

// ---------------- fallback (round-1 proven atomic path) ----------------
__global__ void __launch_bounds__(256) k_edge_atomic(
    const int* __restrict__ ei, const float* __restrict__ ea,
    const float* __restrict__ h, float* __restrict__ dx,
    const float* __restrict__ m1w, const float* __restrict__ m1b,
    const float* __restrict__ m2w, const float* __restrict__ m2b,
    const float* __restrict__ tpw)
{
    __shared__ float s_m1w[48];
    __shared__ float s_m1b[16];
    __shared__ float s_m2w[768];
    __shared__ float s_m2b[48];
    __shared__ float s_tpw[256];
    for (int i = threadIdx.x; i < 48;  i += 256) s_m1w[i] = m1w[i];
    for (int i = threadIdx.x; i < 16;  i += 256) s_m1b[i] = m1b[i];
    for (int i = threadIdx.x; i < 768; i += 256) s_m2w[i] = m2w[i];
    for (int i = threadIdx.x; i < 48;  i += 256) s_m2b[i] = m2b[i];
    for (int i = threadIdx.x; i < 256; i += 256) s_tpw[i] = tpw[i];
    __syncthreads();
    int e = blockIdx.x * 256 + threadIdx.x;
    int src = ei[e];
    int dst = ei[N_EDGES + e];
    float a0 = ea[e * 5 + 0], a1 = ea[e * 5 + 1];
    float rx = ea[e * 5 + 2], ry = ea[e * 5 + 3], rz = ea[e * 5 + 4];
    float r2 = rx * rx + ry * ry + rz * rz;
    float inv = rsqrtf(fmaxf(r2, 1e-24f));
    float shx = SQRT3 * rx * inv, shy = SQRT3 * ry * inv, shz = SQRT3 * rz * inv;
    float hid[16];
#pragma unroll
    for (int j = 0; j < 16; j++) {
        float z = a0 * s_m1w[j] + a1 * s_m1w[16 + j] + r2 * s_m1w[32 + j] + s_m1b[j];
        hid[j] = z / (1.f + __expf(-z));
    }
    float xj[48];
    const float4* hv = (const float4*)(h + (size_t)src * HID);
#pragma unroll
    for (int qq = 0; qq < 12; qq++) {
        float4 v = hv[qq];
        xj[qq * 4 + 0] = v.x; xj[qq * 4 + 1] = v.y; xj[qq * 4 + 2] = v.z; xj[qq * 4 + 3] = v.w;
    }
    float cr[48];
#pragma unroll
    for (int u = 0; u < 16; u++) {
        float x0 = xj[u * 3 + 0], x1 = xj[u * 3 + 1], x2 = xj[u * 3 + 2];
        cr[u * 3 + 0] = x1 * shz - x2 * shy;
        cr[u * 3 + 1] = x2 * shx - x0 * shz;
        cr[u * 3 + 2] = x0 * shy - x1 * shx;
    }
    float* dd = dx + (size_t)dst * HID;
#pragma unroll
    for (int v = 0; v < 16; v++) {
        float t0 = 0.f, t1 = 0.f, t2 = 0.f;
#pragma unroll
        for (int u = 0; u < 16; u++) {
            float w = s_tpw[u * 16 + v];
            t0 += w * cr[u * 3 + 0];
            t1 += w * cr[u * 3 + 1];
            t2 += w * cr[u * 3 + 2];
        }
        float g0 = s_m2b[v * 3 + 0], g1 = s_m2b[v * 3 + 1], g2 = s_m2b[v * 3 + 2];
#pragma unroll
        for (int j = 0; j < 16; j++) {
            float hj = hid[j];
            g0 = fmaf(hj, s_m2w[j * 48 + v * 3 + 0], g0);
            g1 = fmaf(hj, s_m2w[j * 48 + v * 3 + 1], g1);
            g2 = fmaf(hj, s_m2w[j * 48 + v * 3 + 2], g2);
        }
        atomicAdd(dd + v * 3 + 0, g0 * t0 * TP_NORM);
        atomicAdd(dd + v * 3 + 1, g1 * t1 * TP_NORM);
        atomicAdd(dd + v * 3 + 2, g2 * t2 * TP_NORM);
    }
}

extern "C" void kernel_launch(void* const* d_in, const int* in_sizes, int n_in,
                              void* d_out, int out_size, void* d_ws, size_t ws_size,
                              hipStream_t stream) {
    const float* x    = (const float*)d_in[0];
    const int*   ei   = (const int*)  d_in[1];
    const float* ea   = (const float*)d_in[2];
    const int*   batch= (const int*)  d_in[3];
    const float* ew   = (const float*)d_in[4];
    const float* m1w  = (const float*)d_in[5];
    const float* m1b  = (const float*)d_in[6];
    const float* m2w  = (const float*)d_in[7];
    const float* m2b  = (const float*)d_in[8];
    const float* tpw  = (const float*)d_in[9];
    const float* linw = (const float*)d_in[10];
    const float* linb = (const float*)d_in[11];
    float* out = (float*)d_out;

    // -------- workspace layout (256B-aligned carve) --------
    char* w = (char*)d_ws;
    auto alloc = [&](size_t bytes) -> char* {
        char* p = w;
        w += (bytes + 255) & ~(size_t)255;
        return p;
    };
    float*    hA   = (float*)   alloc((size_t)N_NODES * HID * 4);
    float*    hB   = (float*)   alloc((size_t)N_NODES * HID * 4);
    unsigned* h2   = (unsigned*)alloc((size_t)N_NODES * 24 * 4);   // bf16-packed, 96B/row
    float*    dxA  = (float*)   alloc((size_t)N_NODES * HID * 4);
    float*    dxB  = (float*)   alloc((size_t)N_NODES * HID * 4);
    float*    gbuf = (float*)   alloc(2 * N_GRAPHS * 4);
    uint4*    es_s = (uint4*)   alloc((size_t)N_EDGES * 16);       // 16B bf16 records
    int*      off  = (int*)     alloc((size_t)(N_NODES + 1) * 4);
    unsigned* cnt  = (unsigned*)alloc((size_t)((N_NODES + 3) / 4) * 4);  // byte-packed
    unsigned char* rank8 = (unsigned char*)alloc((size_t)N_EDGES);
    int*      blk  = (int*)     alloc((size_t)NBLK * 2 * 4);
    int*      bsum = (int*)     alloc((size_t)NPART * 4);
    int*      bbase= (int*)     alloc((size_t)(NPART + 1) * 4);
    size_t need = (size_t)(w - (char*)d_ws);
    float* gsum = gbuf;
    float* gcnt = gbuf + N_GRAPHS;

    if (ws_size < need) {
        // -------- fallback: round-1 atomic path (needs 19.2MB + 512B) --------
        float* fh   = (float*)d_ws;
        float* fdx  = fh + (size_t)N_NODES * HID;
        float* fgs  = fdx + (size_t)N_NODES * HID;
        float* fgc  = fgs + N_GRAPHS;
        hipMemsetAsync(fdx, 0, ((size_t)N_NODES * HID + 2 * N_GRAPHS) * sizeof(float), stream);
        k_embed<<<(N_NODES * HID + 255) / 256, 256, 0, stream>>>(x, ew, fh);
        for (int l = 0; l < N_LAYERS; l++) {
            k_edge_atomic<<<N_EDGES / 256, 256, 0, stream>>>(ei, ea, fh, fdx,
                m1w + l * 48, m1b + l * 16, m2w + l * 768, m2b + l * 48, tpw + l * 256);
            k_add<<<(N_NODES * HID + 255) / 256, 256, 0, stream>>>(fh, fdx);
        }
        hipMemsetAsync(fdx, 0, (size_t)N_NODES * HID * 4, stream);
        k_pool<<<(N_NODES + 255) / 256, 256, 0, stream>>>(fh, fdx, batch, linw, fgs, fgc);
        k_final<<<1, 64, 0, stream>>>(fgs, fgc, linb, out);
        return;
    }

    // -------- CSR setup: one byte-packed atomic pass + two-level scan --------
    hipMemsetAsync(cnt, 0, (size_t)((N_NODES + 3) / 4) * 4, stream);
    hipMemsetAsync(gbuf, 0, 2 * N_GRAPHS * 4, stream);
    k_count<<<N_EDGES / 256, 256, 0, stream>>>(ei, cnt, rank8);
    k_sred<<<NPART, 256, 0, stream>>>((const unsigned char*)cnt, bsum);
    k_sscan<<<1, 256, 0, stream>>>(bsum, bbase);
    k_soff<<<NPART, 256, 0, stream>>>((const unsigned char*)cnt, bbase, off);
    k_rng<<<(NBLK + 255) / 256, 256, 0, stream>>>(off, blk);
    k_build<<<N_EDGES / 256, 256, 0, stream>>>(ei, ea, off, rank8, es_s);

    k_embed<<<(N_NODES * HID + 255) / 256, 256, 0, stream>>>(x, ew, hA);

    const int npBlocks = (N_NODES * 24 + 255) / 256;
    float* dxs[2] = { dxA, dxB };
    float* hcur = hA;
    float* hnxt = hB;
    for (int l = 0; l < N_LAYERS; l++) {
        float* dxw = dxs[l & 1];
        if (l == 0) {
            k_h2<<<npBlocks, 256, 0, stream>>>(hcur, tpw, h2, dxw);
        } else {
            // read previous layer's dx, zero THIS layer's dx (disjoint buffers)
            k_h2_add<<<npBlocks, 256, 0, stream>>>(hcur, dxs[(l - 1) & 1], tpw + l * 256,
                                                   h2, hnxt, dxw);
            float* tmp = hcur; hcur = hnxt; hnxt = tmp;
        }
        k_fused<<<NBLK, 256, 0, stream>>>(es_s, off, blk, h2, dxw,
            m1w + l * 48, m1b + l * 16, m2w + l * 768, m2b + l * 48);
    }

    // pool over h_final = hcur + dx_last
    k_pool<<<(N_NODES + 255) / 256, 256, 0, stream>>>(hcur, dxs[(N_LAYERS - 1) & 1],
                                                      batch, linw, gsum, gcnt);
    k_final<<<1, 64, 0, stream>>>(gsum, gcnt, linb, out);
}

// Round 12
// 426.152 us; speedup vs baseline: 36.9468x; 1.0439x over previous
//
#include <hip/hip_runtime.h>

#define N_NODES 50000
#define N_EDGES 1600000
#define N_LAYERS 4
#define N_CH 16
#define HID 48            // N_CH * 3
#define N_GRAPHS 64
#define TP_NORM 0.17677669529663687f   // 1/sqrt(2*N_CH)
#define SQRT3 1.7320508075688772f
#define REB 256           // edges per block in fused kernel
#define MPAD 28           // LDS row stride (floats) for 24-col half-message
#define NBLK (N_EDGES / REB)
#define NPART ((N_NODES + 255) / 256)   // 196 scan partials

typedef float v2f __attribute__((ext_vector_type(2)));

// bf16 pack/unpack (RNE pack; unpack is 1 bit-op per value)
__device__ __forceinline__ unsigned bfpack2(float a, float b) {
    unsigned ua = __float_as_uint(a);
    unsigned ub = __float_as_uint(b);
    ua = (ua + 0x7fffu + ((ua >> 16) & 1u)) >> 16;
    ub = (ub + 0x7fffu + ((ub >> 16) & 1u)) >> 16;
    return ua | (ub << 16);
}
#define BFLO(u) __uint_as_float((u) << 16)
#define BFHI(u) __uint_as_float((u) & 0xffff0000u)

// ---------------- embed (fallback path only) ----------------
__global__ void k_embed(const float* __restrict__ x, const float* __restrict__ ew,
                        float* __restrict__ h) {
    int t = blockIdx.x * blockDim.x + threadIdx.x;
    if (t >= N_NODES * HID) return;
    int n = t / HID, c = t % HID;
    h[t] = x[n * 3 + 0] * ew[c] + x[n * 3 + 1] * ew[HID + c] + x[n * 3 + 2] * ew[2 * HID + c];
}

// ---------------- CSR count + fused embed ----------------
// The returning atomic leaves VALU ~0.5% busy; the embed grid-stride epilogue
// executes under the atomic drain for free.
__global__ void k_count(const int* __restrict__ ei, unsigned* __restrict__ cnt32,
                        unsigned char* __restrict__ rank8,
                        const float* __restrict__ x, const float* __restrict__ ew,
                        float* __restrict__ h) {
    int e = blockIdx.x * 256 + threadIdx.x;              // N_EDGES % 256 == 0
    int d = ei[N_EDGES + e];
    int sh = 8 * (d & 3);
    unsigned old = atomicAdd(&cnt32[d >> 2], 1u << sh);
    rank8[e] = (unsigned char)((old >> sh) & 0xffu);
    // embed: 2.4M elements over 1.6M threads (<=2 iterations)
    for (int t = e; t < N_NODES * HID; t += N_EDGES) {
        int n = t / HID, c = t % HID;
        h[t] = x[n * 3 + 0] * ew[c] + x[n * 3 + 1] * ew[HID + c] + x[n * 3 + 2] * ew[2 * HID + c];
    }
}

// ---- two-level scan of byte counters -> off ----
__global__ void k_sred(const unsigned char* __restrict__ cnt8, int* __restrict__ bsum) {
    __shared__ int red[256];
    int b = blockIdx.x, t = threadIdx.x;
    int idx = b * 256 + t;
    red[t] = (idx < N_NODES) ? (int)cnt8[idx] : 0;
    __syncthreads();
    for (int d = 128; d > 0; d >>= 1) {
        if (t < d) red[t] += red[t + d];
        __syncthreads();
    }
    if (t == 0) bsum[b] = red[0];
}

__global__ void k_sscan(const int* __restrict__ bsum, int* __restrict__ bbase) {
    __shared__ int s[256];
    int t = threadIdx.x;
    int v = (t < NPART) ? bsum[t] : 0;
    s[t] = v;
    __syncthreads();
    for (int d = 1; d < 256; d <<= 1) {
        int x = (t >= d) ? s[t - d] : 0;
        __syncthreads();
        s[t] += x;
        __syncthreads();
    }
    if (t < NPART) bbase[t] = s[t] - v;          // exclusive
    if (t == NPART - 1) bbase[NPART] = s[t];     // grand total (== N_EDGES)
}

__global__ void k_soff(const unsigned char* __restrict__ cnt8, const int* __restrict__ bbase,
                       int* __restrict__ off) {
    __shared__ int s[256];
    int b = blockIdx.x, t = threadIdx.x;
    int idx = b * 256 + t;
    int v = (idx < N_NODES) ? (int)cnt8[idx] : 0;
    s[t] = v;
    __syncthreads();
    for (int d = 1; d < 256; d <<= 1) {
        int x = (t >= d) ? s[t - d] : 0;
        __syncthreads();
        s[t] += x;
        __syncthreads();
    }
    if (idx < N_NODES) off[idx] = bbase[b] + s[t] - v;   // exclusive prefix
    if (idx == 0) off[N_NODES] = bbase[NPART];
}

// per fused-block node range via binary search
__global__ void k_rng(const int* __restrict__ off, int* __restrict__ blk) {
    int b = blockIdx.x * blockDim.x + threadIdx.x;
    if (b >= NBLK) return;
    int base = b * REB;
    int lo = 0, hi = N_NODES;
    while (lo < hi) { int mid = (lo + hi + 1) >> 1; if (off[mid] <= base) lo = mid; else hi = mid - 1; }
    blk[2 * b] = lo;
    int last = base + REB - 1;
    int hi2 = N_NODES;
    while (lo < hi2) { int mid = (lo + hi2 + 1) >> 1; if (off[mid] <= last) lo = mid; else hi2 = mid - 1; }
    blk[2 * b + 1] = lo;
}

// sorted 16B record per edge: [a0|a1, r2|shx, shy|shz (bf16 pairs), src]
// sh is pre-scaled by SQRT3*TP_NORM (msg is linear in sh) -> 48 fewer muls/edge in k_fused
__global__ void k_build(const int* __restrict__ ei, const float* __restrict__ ea,
                        const int* __restrict__ off, const unsigned char* __restrict__ rank8,
                        uint4* __restrict__ es_s) {
    int e = blockIdx.x * 256 + threadIdx.x;
    int d = ei[N_EDGES + e];
    int pos = off[d] + (int)rank8[e];
    float a0 = ea[e * 5 + 0], a1 = ea[e * 5 + 1];
    float rx = ea[e * 5 + 2], ry = ea[e * 5 + 3], rz = ea[e * 5 + 4];
    float r2 = rx * rx + ry * ry + rz * rz;
    float inv = rsqrtf(fmaxf(r2, 1e-24f)) * (SQRT3 * TP_NORM);
    uint4 o;
    o.x = bfpack2(a0, a1);
    o.y = bfpack2(r2, rx * inv);
    o.z = bfpack2(ry * inv, rz * inv);
    o.w = (unsigned)ei[e];
    es_s[pos] = o;
}

// ---------------- per-node tpw transform -> bf16 h2; zero dx ----------------
__global__ void k_h2(const float* __restrict__ hin, const float* __restrict__ tpw,
                     unsigned* __restrict__ h2, float* __restrict__ dx) {
    int t = blockIdx.x * blockDim.x + threadIdx.x;
    if (t >= N_NODES * 24) return;
    int n = t / 24, p = t % 24;
    int c0 = 2 * p, c1 = c0 + 1;
    int v0 = c0 / 3, i0 = c0 % 3;
    int v1 = c1 / 3, i1 = c1 % 3;
    const float* hr = hin + (size_t)n * HID;
    float s0 = 0.f, s1 = 0.f;
#pragma unroll
    for (int u = 0; u < 16; u++) {
        s0 = fmaf(tpw[u * 16 + v0], hr[u * 3 + i0], s0);
        s1 = fmaf(tpw[u * 16 + v1], hr[u * 3 + i1], s1);
    }
    h2[t] = bfpack2(s0, s1);
    *(float2*)(dx + (size_t)n * HID + c0) = make_float2(0.f, 0.f);
}

// reads (hin + dxin) [both read-only], writes hout = hin+dxin, h2 bf16, zeroes dxout.
// dxin/dxout are DISJOINT ping-pong buffers.
__global__ void k_h2_add(const float* __restrict__ hin, const float* __restrict__ dxin,
                         const float* __restrict__ tpw,
                         unsigned* __restrict__ h2, float* __restrict__ hout,
                         float* __restrict__ dxout) {
    int t = blockIdx.x * blockDim.x + threadIdx.x;
    if (t >= N_NODES * 24) return;
    int n = t / 24, p = t % 24;
    int c0 = 2 * p, c1 = c0 + 1;
    int v0 = c0 / 3, i0 = c0 % 3;
    int v1 = c1 / 3, i1 = c1 % 3;
    size_t rb = (size_t)n * HID;
    const float* hr = hin + rb;
    const float* dr = dxin + rb;
    float s0 = 0.f, s1 = 0.f;
#pragma unroll
    for (int u = 0; u < 16; u++) {
        float e0 = hr[u * 3 + i0] + dr[u * 3 + i0];
        float e1 = hr[u * 3 + i1] + dr[u * 3 + i1];
        s0 = fmaf(tpw[u * 16 + v0], e0, s0);
        s1 = fmaf(tpw[u * 16 + v1], e1, s1);
    }
    h2[t] = bfpack2(s0, s1);
    float2 hv = *(const float2*)(hr + c0);
    float2 dv = *(const float2*)(dr + c0);
    *(float2*)(hout + rb + c0) = make_float2(hv.x + dv.x, hv.y + dv.y);
    *(float2*)(dxout + rb + c0) = make_float2(0.f, 0.f);
}

// ---------------- fused: message compute + in-LDS segmented reduce -> dx ----------------
__global__ void __launch_bounds__(256) k_fused(
    const uint4* __restrict__ es_s, const int* __restrict__ off,
    const int* __restrict__ blk,
    const unsigned* __restrict__ h2, float* __restrict__ dx,
    const float* __restrict__ m1w, const float* __restrict__ m1b,
    const float* __restrict__ m2w, const float* __restrict__ m2b)
{
    __shared__ float s_msg[REB][MPAD];

    int t = threadIdx.x;
    int base = blockIdx.x * REB;
    int e2 = base + t;

    // per-lane global loads issued first (latency buried under gate compute)
    uint4 rec = es_s[e2];                      // 16B bf16 record
    int src = (int)rec.w;
    const uint4* hv = (const uint4*)(h2 + (size_t)src * 24);   // 96B bf16 row
    uint4 A0 = hv[0], A1 = hv[1], A2 = hv[2];  // pass-A half (c 0..23)
    int n0 = blk[2 * blockIdx.x];
    int n1 = blk[2 * blockIdx.x + 1];

    float a0 = BFLO(rec.x), a1 = BFHI(rec.x);
    float r2 = BFLO(rec.y), shx = BFHI(rec.y);
    float shy = BFLO(rec.z), shz = BFHI(rec.z);

    // silu via v_rcp (1 ulp) instead of IEEE f32 div (~10 inst each)
    float hid[16];
#pragma unroll
    for (int j = 0; j < 16; j++) {
        float z = fmaf(a0, m1w[j], fmaf(a1, m1w[16 + j], fmaf(r2, m1w[32 + j], m1b[j])));
        hid[j] = z * __builtin_amdgcn_rcpf(1.f + __expf(-z));
    }

    int gid = t / 24;            // 0..9 (10 groups); threads 240..255 idle in reduce
    int rem = t % 24;
    int q    = rem >> 2;         // float4 column 0..5
    int quad = rem & 3;          // 4-way row split; quads never straddle waves (4|64)

    float xj[24];
#define UNPK8(u, d) { (d)[0]=BFLO((u).x); (d)[1]=BFHI((u).x); (d)[2]=BFLO((u).y); (d)[3]=BFHI((u).y); \
                      (d)[4]=BFLO((u).z); (d)[5]=BFHI((u).z); (d)[6]=BFLO((u).w); (d)[7]=BFHI((u).w); }
    UNPK8(A0, &xj[0]); UNPK8(A1, &xj[8]); UNPK8(A2, &xj[16]);

    alignas(16) v2f mv[12];
    float* m = (float*)mv;

    // ================= PASS A: channels v=0..7 (cols 0..23) =================
#pragma unroll
    for (int qq = 0; qq < 6; qq++) {
        float4 b = *(const float4*)(m2b + qq * 4);
        mv[2 * qq + 0] = (v2f){b.x, b.y};
        mv[2 * qq + 1] = (v2f){b.z, b.w};
    }
#pragma unroll
    for (int j = 0; j < 16; j++) {
        v2f hj2 = (v2f){hid[j], hid[j]};
#pragma unroll
        for (int qq = 0; qq < 6; qq++) {
            float4 w4 = *(const float4*)(m2w + j * 48 + qq * 4);
            mv[2 * qq + 0] = __builtin_elementwise_fma(hj2, (v2f){w4.x, w4.y}, mv[2 * qq + 0]);
            mv[2 * qq + 1] = __builtin_elementwise_fma(hj2, (v2f){w4.z, w4.w}, mv[2 * qq + 1]);
        }
    }
#pragma unroll
    for (int v = 0; v < 8; v++) {
        float x0 = xj[v * 3 + 0], x1 = xj[v * 3 + 1], x2 = xj[v * 3 + 2];
        m[v * 3 + 0] *= x1 * shz - x2 * shy;   // TP_NORM pre-folded into sh
        m[v * 3 + 1] *= x2 * shx - x0 * shz;
        m[v * 3 + 2] *= x0 * shy - x1 * shx;
    }
    {
        float4* row = (float4*)&s_msg[t][0];
#pragma unroll
        for (int qq = 0; qq < 6; qq++) row[qq] = ((float4*)m)[qq];
    }
    // prefetch + unpack pass-B half (overlaps reduce A)
    {
        uint4 B0 = hv[3], B1 = hv[4], B2 = hv[5];
        UNPK8(B0, &xj[0]); UNPK8(B1, &xj[8]); UNPK8(B2, &xj[16]);
    }
    __syncthreads();

    if (t < 240) {
        for (int nn = n0 + gid; nn <= n1; nn += 10) {
            int lo = off[nn], hi = off[nn + 1];
            int rlo = (lo > base) ? lo - base : 0;
            int rhi = ((hi < base + REB) ? hi : base + REB) - base;
            if (rlo < rhi) {                     // same for all 4 quads of a group
                float4 acc = make_float4(0.f, 0.f, 0.f, 0.f);
                for (int r = rlo + quad; r < rhi; r += 4) {
                    float4 v = *(const float4*)&s_msg[r][q * 4];
                    acc.x += v.x; acc.y += v.y; acc.z += v.z; acc.w += v.w;
                }
                acc.x += __shfl_xor(acc.x, 1); acc.y += __shfl_xor(acc.y, 1);
                acc.z += __shfl_xor(acc.z, 1); acc.w += __shfl_xor(acc.w, 1);
                acc.x += __shfl_xor(acc.x, 2); acc.y += __shfl_xor(acc.y, 2);
                acc.z += __shfl_xor(acc.z, 2); acc.w += __shfl_xor(acc.w, 2);
                if (quad == 0) {
                    float* dp = dx + (size_t)nn * HID + q * 4;
                    if (lo < base || hi > base + REB) {
                        atomicAdd(dp + 0, acc.x); atomicAdd(dp + 1, acc.y);
                        atomicAdd(dp + 2, acc.z); atomicAdd(dp + 3, acc.w);
                    } else {
                        *(float4*)dp = acc;
                    }
                }
            }
        }
    }
    __syncthreads();

    // ================= PASS B: channels v=8..15 (cols 24..47) =================
#pragma unroll
    for (int qq = 0; qq < 6; qq++) {
        float4 b = *(const float4*)(m2b + 24 + qq * 4);
        mv[2 * qq + 0] = (v2f){b.x, b.y};
        mv[2 * qq + 1] = (v2f){b.z, b.w};
    }
#pragma unroll
    for (int j = 0; j < 16; j++) {
        v2f hj2 = (v2f){hid[j], hid[j]};
#pragma unroll
        for (int qq = 0; qq < 6; qq++) {
            float4 w4 = *(const float4*)(m2w + j * 48 + 24 + qq * 4);
            mv[2 * qq + 0] = __builtin_elementwise_fma(hj2, (v2f){w4.x, w4.y}, mv[2 * qq + 0]);
            mv[2 * qq + 1] = __builtin_elementwise_fma(hj2, (v2f){w4.z, w4.w}, mv[2 * qq + 1]);
        }
    }
#pragma unroll
    for (int v = 0; v < 8; v++) {
        float x0 = xj[v * 3 + 0], x1 = xj[v * 3 + 1], x2 = xj[v * 3 + 2];
        m[v * 3 + 0] *= x1 * shz - x2 * shy;
        m[v * 3 + 1] *= x2 * shx - x0 * shz;
        m[v * 3 + 2] *= x0 * shy - x1 * shx;
    }
    {
        float4* row = (float4*)&s_msg[t][0];
#pragma unroll
        for (int qq = 0; qq < 6; qq++) row[qq] = ((float4*)m)[qq];
    }
    __syncthreads();

    if (t < 240) {
        for (int nn = n0 + gid; nn <= n1; nn += 10) {
            int lo = off[nn], hi = off[nn + 1];
            int rlo = (lo > base) ? lo - base : 0;
            int rhi = ((hi < base + REB) ? hi : base + REB) - base;
            if (rlo < rhi) {
                float4 acc = make_float4(0.f, 0.f, 0.f, 0.f);
                for (int r = rlo + quad; r < rhi; r += 4) {
                    float4 v = *(const float4*)&s_msg[r][q * 4];
                    acc.x += v.x; acc.y += v.y; acc.z += v.z; acc.w += v.w;
                }
                acc.x += __shfl_xor(acc.x, 1); acc.y += __shfl_xor(acc.y, 1);
                acc.z += __shfl_xor(acc.z, 1); acc.w += __shfl_xor(acc.w, 1);
                acc.x += __shfl_xor(acc.x, 2); acc.y += __shfl_xor(acc.y, 2);
                acc.z += __shfl_xor(acc.z, 2); acc.w += __shfl_xor(acc.w, 2);
                if (quad == 0) {
                    float* dp = dx + (size_t)nn * HID + 24 + q * 4;
                    if (lo < base || hi > base + REB) {
                        atomicAdd(dp + 0, acc.x); atomicAdd(dp + 1, acc.y);
                        atomicAdd(dp + 2, acc.z); atomicAdd(dp + 3, acc.w);
                    } else {
                        *(float4*)dp = acc;
                    }
                }
            }
        }
    }
}

// ---------------- h += dx; dx = 0 (fallback path only) ----------------
__global__ void k_add(float* __restrict__ h, float* __restrict__ dx) {
    int t = blockIdx.x * blockDim.x + threadIdx.x;
    if (t >= N_NODES * HID) return;
    h[t] += dx[t];
    dx[t] = 0.f;
}

// ---------------- pool: per-graph mean of ((h+dx) @ lin_w) ----------------
__global__ void __launch_bounds__(256) k_pool(
    const float* __restrict__ h, const float* __restrict__ dxin, const int* __restrict__ batch,
    const float* __restrict__ linw, float* __restrict__ gsum, float* __restrict__ gcnt)
{
    __shared__ float ss[N_GRAPHS];
    __shared__ float sc[N_GRAPHS];
    for (int i = threadIdx.x; i < N_GRAPHS; i += 256) { ss[i] = 0.f; sc[i] = 0.f; }
    __syncthreads();
    int n = blockIdx.x * 256 + threadIdx.x;
    if (n < N_NODES) {
        float s = 0.f;
        const float4* hv = (const float4*)(h + (size_t)n * HID);
        const float4* dv = (const float4*)(dxin + (size_t)n * HID);
#pragma unroll
        for (int qq = 0; qq < 12; qq++) {
            float4 v = hv[qq], d = dv[qq];
            s += (v.x + d.x) * linw[qq * 4 + 0] + (v.y + d.y) * linw[qq * 4 + 1]
               + (v.z + d.z) * linw[qq * 4 + 2] + (v.w + d.w) * linw[qq * 4 + 3];
        }
        int b = batch[n];
        atomicAdd(&ss[b], s);
        atomicAdd(&sc[b], 1.f);
    }
    __syncthreads();
    for (int i = threadIdx.x; i < N_GRAPHS; i += 256) {
        if (sc[i] != 0.f) {
            atomicAdd(&gsum[i], ss[i]);
            atomicAdd(&gcnt[i], sc[i]);
        }
    }
}

__global__ void k_final(const float* __restrict__ gsum, const float* __restrict__ gcnt,
                        const float* __restrict__ linb, float* __restrict__ out) {
    int g = threadIdx.x;
    if (g < N_GRAPHS) out[g] = gsum[g] / fmaxf(gcnt[g], 1.f) + linb[0];
}

// ---------------- fallback (round-1 proven atomic path) ----------------
__global__ void __launch_bounds__(256) k_edge_atomic(
    const int* __restrict__ ei, const float* __restrict__ ea,
    const float* __restrict__ h, float* __restrict__ dx,
    const float* __restrict__ m1w, const float* __restrict__ m1b,
    const float* __restrict__ m2w, const float* __restrict__ m2b,
    const float* __restrict__ tpw)
{
    __shared__ float s_m1w[48];
    __shared__ float s_m1b[16];
    __shared__ float s_m2w[768];
    __shared__ float s_m2b[48];
    __shared__ float s_tpw[256];
    for (int i = threadIdx.x; i < 48;  i += 256) s_m1w[i] = m1w[i];
    for (int i = threadIdx.x; i < 16;  i += 256) s_m1b[i] = m1b[i];
    for (int i = threadIdx.x; i < 768; i += 256) s_m2w[i] = m2w[i];
    for (int i = threadIdx.x; i < 48;  i += 256) s_m2b[i] = m2b[i];
    for (int i = threadIdx.x; i < 256; i += 256) s_tpw[i] = tpw[i];
    __syncthreads();
    int e = blockIdx.x * 256 + threadIdx.x;
    int src = ei[e];
    int dst = ei[N_EDGES + e];
    float a0 = ea[e * 5 + 0], a1 = ea[e * 5 + 1];
    float rx = ea[e * 5 + 2], ry = ea[e * 5 + 3], rz = ea[e * 5 + 4];
    float r2 = rx * rx + ry * ry + rz * rz;
    float inv = rsqrtf(fmaxf(r2, 1e-24f));
    float shx = SQRT3 * rx * inv, shy = SQRT3 * ry * inv, shz = SQRT3 * rz * inv;
    float hid[16];
#pragma unroll
    for (int j = 0; j < 16; j++) {
        float z = a0 * s_m1w[j] + a1 * s_m1w[16 + j] + r2 * s_m1w[32 + j] + s_m1b[j];
        hid[j] = z / (1.f + __expf(-z));
    }
    float xj[48];
    const float4* hv = (const float4*)(h + (size_t)src * HID);
#pragma unroll
    for (int qq = 0; qq < 12; qq++) {
        float4 v = hv[qq];
        xj[qq * 4 + 0] = v.x; xj[qq * 4 + 1] = v.y; xj[qq * 4 + 2] = v.z; xj[qq * 4 + 3] = v.w;
    }
    float cr[48];
#pragma unroll
    for (int u = 0; u < 16; u++) {
        float x0 = xj[u * 3 + 0], x1 = xj[u * 3 + 1], x2 = xj[u * 3 + 2];
        cr[u * 3 + 0] = x1 * shz - x2 * shy;
        cr[u * 3 + 1] = x2 * shx - x0 * shz;
        cr[u * 3 + 2] = x0 * shy - x1 * shx;
    }
    float* dd = dx + (size_t)dst * HID;
#pragma unroll
    for (int v = 0; v < 16; v++) {
        float t0 = 0.f, t1 = 0.f, t2 = 0.f;
#pragma unroll
        for (int u = 0; u < 16; u++) {
            float w = s_tpw[u * 16 + v];
            t0 += w * cr[u * 3 + 0];
            t1 += w * cr[u * 3 + 1];
            t2 += w * cr[u * 3 + 2];
        }
        float g0 = s_m2b[v * 3 + 0], g1 = s_m2b[v * 3 + 1], g2 = s_m2b[v * 3 + 2];
#pragma unroll
        for (int j = 0; j < 16; j++) {
            float hj = hid[j];
            g0 = fmaf(hj, s_m2w[j * 48 + v * 3 + 0], g0);
            g1 = fmaf(hj, s_m2w[j * 48 + v * 3 + 1], g1);
            g2 = fmaf(hj, s_m2w[j * 48 + v * 3 + 2], g2);
        }
        atomicAdd(dd + v * 3 + 0, g0 * t0 * TP_NORM);
        atomicAdd(dd + v * 3 + 1, g1 * t1 * TP_NORM);
        atomicAdd(dd + v * 3 + 2, g2 * t2 * TP_NORM);
    }
}

extern "C" void kernel_launch(void* const* d_in, const int* in_sizes, int n_in,
                              void* d_out, int out_size, void* d_ws, size_t ws_size,
                              hipStream_t stream) {
    const float* x    = (const float*)d_in[0];
    const int*   ei   = (const int*)  d_in[1];
    const float* ea   = (const float*)d_in[2];
    const int*   batch= (const int*)  d_in[3];
    const float* ew   = (const float*)d_in[4];
    const float* m1w  = (const float*)d_in[5];
    const float* m1b  = (const float*)d_in[6];
    const float* m2w  = (const float*)d_in[7];
    const float* m2b  = (const float*)d_in[8];
    const float* tpw  = (const float*)d_in[9];
    const float* linw = (const float*)d_in[10];
    const float* linb = (const float*)d_in[11];
    float* out = (float*)d_out;

    // -------- workspace layout (256B-aligned carve) --------
    char* w = (char*)d_ws;
    auto alloc = [&](size_t bytes) -> char* {
        char* p = w;
        w += (bytes + 255) & ~(size_t)255;
        return p;
    };
    float*    hA   = (float*)   alloc((size_t)N_NODES * HID * 4);
    float*    hB   = (float*)   alloc((size_t)N_NODES * HID * 4);
    unsigned* h2   = (unsigned*)alloc((size_t)N_NODES * 24 * 4);   // bf16-packed, 96B/row
    float*    dxA  = (float*)   alloc((size_t)N_NODES * HID * 4);
    float*    dxB  = (float*)   alloc((size_t)N_NODES * HID * 4);
    float*    gbuf = (float*)   alloc(2 * N_GRAPHS * 4);
    uint4*    es_s = (uint4*)   alloc((size_t)N_EDGES * 16);       // 16B bf16 records
    int*      off  = (int*)     alloc((size_t)(N_NODES + 1) * 4);
    unsigned* cnt  = (unsigned*)alloc((size_t)((N_NODES + 3) / 4) * 4);  // byte-packed
    unsigned char* rank8 = (unsigned char*)alloc((size_t)N_EDGES);
    int*      blk  = (int*)     alloc((size_t)NBLK * 2 * 4);
    int*      bsum = (int*)     alloc((size_t)NPART * 4);
    int*      bbase= (int*)     alloc((size_t)(NPART + 1) * 4);
    size_t need = (size_t)(w - (char*)d_ws);
    float* gsum = gbuf;
    float* gcnt = gbuf + N_GRAPHS;

    if (ws_size < need) {
        // -------- fallback: round-1 atomic path (needs 19.2MB + 512B) --------
        float* fh   = (float*)d_ws;
        float* fdx  = fh + (size_t)N_NODES * HID;
        float* fgs  = fdx + (size_t)N_NODES * HID;
        float* fgc  = fgs + N_GRAPHS;
        hipMemsetAsync(fdx, 0, ((size_t)N_NODES * HID + 2 * N_GRAPHS) * sizeof(float), stream);
        k_embed<<<(N_NODES * HID + 255) / 256, 256, 0, stream>>>(x, ew, fh);
        for (int l = 0; l < N_LAYERS; l++) {
            k_edge_atomic<<<N_EDGES / 256, 256, 0, stream>>>(ei, ea, fh, fdx,
                m1w + l * 48, m1b + l * 16, m2w + l * 768, m2b + l * 48, tpw + l * 256);
            k_add<<<(N_NODES * HID + 255) / 256, 256, 0, stream>>>(fh, fdx);
        }
        hipMemsetAsync(fdx, 0, (size_t)N_NODES * HID * 4, stream);
        k_pool<<<(N_NODES + 255) / 256, 256, 0, stream>>>(fh, fdx, batch, linw, fgs, fgc);
        k_final<<<1, 64, 0, stream>>>(fgs, fgc, linb, out);
        return;
    }

    // -------- CSR setup: byte-packed atomic pass (+fused embed) + two-level scan --------
    hipMemsetAsync(cnt, 0, (size_t)((N_NODES + 3) / 4) * 4, stream);
    hipMemsetAsync(gbuf, 0, 2 * N_GRAPHS * 4, stream);
    k_count<<<N_EDGES / 256, 256, 0, stream>>>(ei, cnt, rank8, x, ew, hA);
    k_sred<<<NPART, 256, 0, stream>>>((const unsigned char*)cnt, bsum);
    k_sscan<<<1, 256, 0, stream>>>(bsum, bbase);
    k_soff<<<NPART, 256, 0, stream>>>((const unsigned char*)cnt, bbase, off);
    k_rng<<<(NBLK + 255) / 256, 256, 0, stream>>>(off, blk);
    k_build<<<N_EDGES / 256, 256, 0, stream>>>(ei, ea, off, rank8, es_s);

    const int npBlocks = (N_NODES * 24 + 255) / 256;
    float* dxs[2] = { dxA, dxB };
    float* hcur = hA;
    float* hnxt = hB;
    for (int l = 0; l < N_LAYERS; l++) {
        float* dxw = dxs[l & 1];
        if (l == 0) {
            k_h2<<<npBlocks, 256, 0, stream>>>(hcur, tpw, h2, dxw);
        } else {
            // read previous layer's dx, zero THIS layer's dx (disjoint buffers)
            k_h2_add<<<npBlocks, 256, 0, stream>>>(hcur, dxs[(l - 1) & 1], tpw + l * 256,
                                                   h2, hnxt, dxw);
            float* tmp = hcur; hcur = hnxt; hnxt = tmp;
        }
        k_fused<<<NBLK, 256, 0, stream>>>(es_s, off, blk, h2, dxw,
            m1w + l * 48, m1b + l * 16, m2w + l * 768, m2b + l * 48);
    }

    // pool over h_final = hcur + dx_last
    k_pool<<<(N_NODES + 255) / 256, 256, 0, stream>>>(hcur, dxs[(N_LAYERS - 1) & 1],
                                                      batch, linw, gsum, gcnt);
    k_final<<<1, 64, 0, stream>>>(gsum, gcnt, linb, out);
}

// Round 13
// 379.506 us; speedup vs baseline: 41.4880x; 1.1229x over previous
//
#include <hip/hip_runtime.h>

#define N_NODES 50000
#define N_EDGES 1600000
#define N_LAYERS 4
#define N_CH 16
#define HID 48            // N_CH * 3
#define N_GRAPHS 64
#define TP_NORM 0.17677669529663687f   // 1/sqrt(2*N_CH)
#define SQRT3 1.7320508075688772f
#define REB 256           // edges per block in fused kernel
#define MPAD 28           // LDS row stride (floats) for 24-col half-message
#define NBLK (N_EDGES / REB)
#define NPART ((N_NODES + 255) / 256)   // 196 scan partials
#define SBLK 256                        // sort blocks
#define EPB (N_EDGES / SBLK)            // 6250 edges per sort block
#define HW ((N_NODES + 3) / 4)          // 12500 histogram words per block
#define HB (HW * 4)                     // 50000 histogram bytes per block

typedef float v2f __attribute__((ext_vector_type(2)));

// bf16 pack/unpack (RNE pack; unpack is 1 bit-op per value)
__device__ __forceinline__ unsigned bfpack2(float a, float b) {
    unsigned ua = __float_as_uint(a);
    unsigned ub = __float_as_uint(b);
    ua = (ua + 0x7fffu + ((ua >> 16) & 1u)) >> 16;
    ub = (ub + 0x7fffu + ((ub >> 16) & 1u)) >> 16;
    return ua | (ub << 16);
}
#define BFLO(u) __uint_as_float((u) << 16)
#define BFHI(u) __uint_as_float((u) & 0xffff0000u)

// ---------------- embed (fallback path only) ----------------
__global__ void k_embed(const float* __restrict__ x, const float* __restrict__ ew,
                        float* __restrict__ h) {
    int t = blockIdx.x * blockDim.x + threadIdx.x;
    if (t >= N_NODES * HID) return;
    int n = t / HID, c = t % HID;
    h[t] = x[n * 3 + 0] * ew[c] + x[n * 3 + 1] * ew[HID + c] + x[n * 3 + 2] * ew[2 * HID + c];
}

// ---------------- sort pass 1: per-block LDS histogram (NO global atomics) ----------------
// max per-block count for a node <= its degree (~66 max) << 255, so byte counters are safe.
// embed rides along as a grid-stride epilogue.
__global__ void __launch_bounds__(512) k_hist1(
    const int* __restrict__ ei, unsigned* __restrict__ hist32,
    const float* __restrict__ x, const float* __restrict__ ew, float* __restrict__ h) {
    __shared__ unsigned lh[HW];
    int b = blockIdx.x, t = threadIdx.x;
    for (int i = t; i < HW; i += 512) lh[i] = 0;
    __syncthreads();
    int e0 = b * EPB, e1 = e0 + EPB;
    for (int e = e0 + t; e < e1; e += 512) {
        int d = ei[N_EDGES + e];
        atomicAdd(&lh[d >> 2], 1u << (8 * (d & 3)));
    }
    __syncthreads();
    unsigned* gh = hist32 + (size_t)b * HW;
    for (int i = t; i < HW; i += 512) gh[i] = lh[i];
    // embed epilogue
    int tid = b * 512 + t;
    for (int i = tid; i < N_NODES * HID; i += SBLK * 512) {
        int n = i / HID, c = i % HID;
        h[i] = x[n * 3 + 0] * ew[c] + x[n * 3 + 1] * ew[HID + c] + x[n * 3 + 2] * ew[2 * HID + c];
    }
}

// ---------------- sort pass 1.5: column scan (per-bin exclusive prefix over blocks) ----------
// hist8[b*HB + d] := sum_{b'<b} count_{b'}(d)  (fits a byte: <= degree <= ~66)
// deg32[d] := total degree (int, for the off scan)
__global__ void k_cscan(unsigned char* __restrict__ hist8, int* __restrict__ deg32) {
    int d = blockIdx.x * 256 + threadIdx.x;
    if (d >= N_NODES) return;
    unsigned run = 0;
    unsigned char* p = hist8 + d;
#pragma unroll 8
    for (int b = 0; b < SBLK; b++) {
        unsigned v = p[(size_t)b * HB];
        p[(size_t)b * HB] = (unsigned char)run;
        run += v;
    }
    deg32[d] = (int)run;
}

// ---- two-level scan of int degrees -> off ----
__global__ void k_sred(const int* __restrict__ cnt, int* __restrict__ bsum) {
    __shared__ int red[256];
    int b = blockIdx.x, t = threadIdx.x;
    int idx = b * 256 + t;
    red[t] = (idx < N_NODES) ? cnt[idx] : 0;
    __syncthreads();
    for (int d = 128; d > 0; d >>= 1) {
        if (t < d) red[t] += red[t + d];
        __syncthreads();
    }
    if (t == 0) bsum[b] = red[0];
}

__global__ void k_sscan(const int* __restrict__ bsum, int* __restrict__ bbase) {
    __shared__ int s[256];
    int t = threadIdx.x;
    int v = (t < NPART) ? bsum[t] : 0;
    s[t] = v;
    __syncthreads();
    for (int d = 1; d < 256; d <<= 1) {
        int x = (t >= d) ? s[t - d] : 0;
        __syncthreads();
        s[t] += x;
        __syncthreads();
    }
    if (t < NPART) bbase[t] = s[t] - v;          // exclusive
    if (t == NPART - 1) bbase[NPART] = s[t];     // grand total (== N_EDGES)
}

__global__ void k_soff(const int* __restrict__ cnt, const int* __restrict__ bbase,
                       int* __restrict__ off) {
    __shared__ int s[256];
    int b = blockIdx.x, t = threadIdx.x;
    int idx = b * 256 + t;
    int v = (idx < N_NODES) ? cnt[idx] : 0;
    s[t] = v;
    __syncthreads();
    for (int d = 1; d < 256; d <<= 1) {
        int x = (t >= d) ? s[t - d] : 0;
        __syncthreads();
        s[t] += x;
        __syncthreads();
    }
    if (idx < N_NODES) off[idx] = bbase[b] + s[t] - v;   // exclusive prefix
    if (idx == 0) off[N_NODES] = bbase[NPART];
}

// per fused-block node range via binary search
__global__ void k_rng(const int* __restrict__ off, int* __restrict__ blk) {
    int b = blockIdx.x * blockDim.x + threadIdx.x;
    if (b >= NBLK) return;
    int base = b * REB;
    int lo = 0, hi = N_NODES;
    while (lo < hi) { int mid = (lo + hi + 1) >> 1; if (off[mid] <= base) lo = mid; else hi = mid - 1; }
    blk[2 * b] = lo;
    int last = base + REB - 1;
    int hi2 = N_NODES;
    while (lo < hi2) { int mid = (lo + hi2 + 1) >> 1; if (off[mid] <= last) lo = mid; else hi2 = mid - 1; }
    blk[2 * b + 1] = lo;
}

// ---------------- sort pass 2: rank via LDS atomics + record scatter ----------------
// pos = off[d] + blockPrefix[b][d] + localRank  (unique per edge; order within a node
// varies with schedule but any permutation is valid — fp sum tolerance covers it)
__global__ void __launch_bounds__(512) k_build2(
    const int* __restrict__ ei, const float* __restrict__ ea,
    const int* __restrict__ off, const unsigned char* __restrict__ hist8,
    uint4* __restrict__ es_s) {
    __shared__ unsigned lr[HW];
    int b = blockIdx.x, t = threadIdx.x;
    for (int i = t; i < HW; i += 512) lr[i] = 0;
    __syncthreads();
    int e0 = b * EPB, e1 = e0 + EPB;
    const unsigned char* hb = hist8 + (size_t)b * HB;
    for (int e = e0 + t; e < e1; e += 512) {
        int d = ei[N_EDGES + e];
        int sh = 8 * (d & 3);
        unsigned old = atomicAdd(&lr[d >> 2], 1u << sh);
        int local = (int)((old >> sh) & 0xffu);
        int pos = off[d] + (int)hb[d] + local;
        float a0 = ea[e * 5 + 0], a1 = ea[e * 5 + 1];
        float rx = ea[e * 5 + 2], ry = ea[e * 5 + 3], rz = ea[e * 5 + 4];
        float r2 = rx * rx + ry * ry + rz * rz;
        float inv = rsqrtf(fmaxf(r2, 1e-24f)) * (SQRT3 * TP_NORM);
        uint4 o;
        o.x = bfpack2(a0, a1);
        o.y = bfpack2(r2, rx * inv);
        o.z = bfpack2(ry * inv, rz * inv);
        o.w = (unsigned)ei[e];
        es_s[pos] = o;
    }
}

// ---------------- per-node tpw transform -> bf16 h2; zero dx ----------------
__global__ void k_h2(const float* __restrict__ hin, const float* __restrict__ tpw,
                     unsigned* __restrict__ h2, float* __restrict__ dx) {
    int t = blockIdx.x * blockDim.x + threadIdx.x;
    if (t >= N_NODES * 24) return;
    int n = t / 24, p = t % 24;
    int c0 = 2 * p, c1 = c0 + 1;
    int v0 = c0 / 3, i0 = c0 % 3;
    int v1 = c1 / 3, i1 = c1 % 3;
    const float* hr = hin + (size_t)n * HID;
    float s0 = 0.f, s1 = 0.f;
#pragma unroll
    for (int u = 0; u < 16; u++) {
        s0 = fmaf(tpw[u * 16 + v0], hr[u * 3 + i0], s0);
        s1 = fmaf(tpw[u * 16 + v1], hr[u * 3 + i1], s1);
    }
    h2[t] = bfpack2(s0, s1);
    *(float2*)(dx + (size_t)n * HID + c0) = make_float2(0.f, 0.f);
}

// reads (hin + dxin) [both read-only], writes hout = hin+dxin, h2 bf16, zeroes dxout.
// dxin/dxout are DISJOINT ping-pong buffers.
__global__ void k_h2_add(const float* __restrict__ hin, const float* __restrict__ dxin,
                         const float* __restrict__ tpw,
                         unsigned* __restrict__ h2, float* __restrict__ hout,
                         float* __restrict__ dxout) {
    int t = blockIdx.x * blockDim.x + threadIdx.x;
    if (t >= N_NODES * 24) return;
    int n = t / 24, p = t % 24;
    int c0 = 2 * p, c1 = c0 + 1;
    int v0 = c0 / 3, i0 = c0 % 3;
    int v1 = c1 / 3, i1 = c1 % 3;
    size_t rb = (size_t)n * HID;
    const float* hr = hin + rb;
    const float* dr = dxin + rb;
    float s0 = 0.f, s1 = 0.f;
#pragma unroll
    for (int u = 0; u < 16; u++) {
        float e0 = hr[u * 3 + i0] + dr[u * 3 + i0];
        float e1 = hr[u * 3 + i1] + dr[u * 3 + i1];
        s0 = fmaf(tpw[u * 16 + v0], e0, s0);
        s1 = fmaf(tpw[u * 16 + v1], e1, s1);
    }
    h2[t] = bfpack2(s0, s1);
    float2 hv = *(const float2*)(hr + c0);
    float2 dv = *(const float2*)(dr + c0);
    *(float2*)(hout + rb + c0) = make_float2(hv.x + dv.x, hv.y + dv.y);
    *(float2*)(dxout + rb + c0) = make_float2(0.f, 0.f);
}

// ---------------- fused: message compute + in-LDS segmented reduce -> dx ----------------
__global__ void __launch_bounds__(256) k_fused(
    const uint4* __restrict__ es_s, const int* __restrict__ off,
    const int* __restrict__ blk,
    const unsigned* __restrict__ h2, float* __restrict__ dx,
    const float* __restrict__ m1w, const float* __restrict__ m1b,
    const float* __restrict__ m2w, const float* __restrict__ m2b)
{
    __shared__ float s_msg[REB][MPAD];

    int t = threadIdx.x;
    int base = blockIdx.x * REB;
    int e2 = base + t;

    // ALL per-lane global loads issued up front (full gather in flight under gate compute)
    uint4 rec = es_s[e2];                      // 16B bf16 record
    int src = (int)rec.w;
    const uint4* hv = (const uint4*)(h2 + (size_t)src * 24);   // 96B bf16 row
    uint4 A0 = hv[0], A1 = hv[1], A2 = hv[2];
    uint4 B0 = hv[3], B1 = hv[4], B2 = hv[5];
    int n0 = blk[2 * blockIdx.x];
    int n1 = blk[2 * blockIdx.x + 1];

    float a0 = BFLO(rec.x), a1 = BFHI(rec.x);
    float r2 = BFLO(rec.y), shx = BFHI(rec.y);
    float shy = BFLO(rec.z), shz = BFHI(rec.z);

    // silu via v_rcp (1 ulp) instead of IEEE f32 div
    float hid[16];
#pragma unroll
    for (int j = 0; j < 16; j++) {
        float z = fmaf(a0, m1w[j], fmaf(a1, m1w[16 + j], fmaf(r2, m1w[32 + j], m1b[j])));
        hid[j] = z * __builtin_amdgcn_rcpf(1.f + __expf(-z));
    }

    int gid = t / 24;            // 0..9 (10 groups); threads 240..255 idle in reduce
    int rem = t % 24;
    int q    = rem >> 2;         // float4 column 0..5
    int quad = rem & 3;          // 4-way row split; quads never straddle waves (4|64)

    float xj[24];
#define UNPK8(u, d) { (d)[0]=BFLO((u).x); (d)[1]=BFHI((u).x); (d)[2]=BFLO((u).y); (d)[3]=BFHI((u).y); \
                      (d)[4]=BFLO((u).z); (d)[5]=BFHI((u).z); (d)[6]=BFLO((u).w); (d)[7]=BFHI((u).w); }
    UNPK8(A0, &xj[0]); UNPK8(A1, &xj[8]); UNPK8(A2, &xj[16]);

    alignas(16) v2f mv[12];
    float* m = (float*)mv;

    // ================= PASS A: channels v=0..7 (cols 0..23) =================
#pragma unroll
    for (int qq = 0; qq < 6; qq++) {
        float4 b = *(const float4*)(m2b + qq * 4);
        mv[2 * qq + 0] = (v2f){b.x, b.y};
        mv[2 * qq + 1] = (v2f){b.z, b.w};
    }
#pragma unroll
    for (int j = 0; j < 16; j++) {
        v2f hj2 = (v2f){hid[j], hid[j]};
#pragma unroll
        for (int qq = 0; qq < 6; qq++) {
            float4 w4 = *(const float4*)(m2w + j * 48 + qq * 4);
            mv[2 * qq + 0] = __builtin_elementwise_fma(hj2, (v2f){w4.x, w4.y}, mv[2 * qq + 0]);
            mv[2 * qq + 1] = __builtin_elementwise_fma(hj2, (v2f){w4.z, w4.w}, mv[2 * qq + 1]);
        }
    }
#pragma unroll
    for (int v = 0; v < 8; v++) {
        float x0 = xj[v * 3 + 0], x1 = xj[v * 3 + 1], x2 = xj[v * 3 + 2];
        m[v * 3 + 0] *= x1 * shz - x2 * shy;   // TP_NORM pre-folded into sh
        m[v * 3 + 1] *= x2 * shx - x0 * shz;
        m[v * 3 + 2] *= x0 * shy - x1 * shx;
    }
    {
        float4* row = (float4*)&s_msg[t][0];
#pragma unroll
        for (int qq = 0; qq < 6; qq++) row[qq] = ((float4*)m)[qq];
    }
    // unpack pass-B half (loads already in flight since kernel entry)
    UNPK8(B0, &xj[0]); UNPK8(B1, &xj[8]); UNPK8(B2, &xj[16]);
    __syncthreads();

    if (t < 240) {
        for (int nn = n0 + gid; nn <= n1; nn += 10) {
            int lo = off[nn], hi = off[nn + 1];
            int rlo = (lo > base) ? lo - base : 0;
            int rhi = ((hi < base + REB) ? hi : base + REB) - base;
            if (rlo < rhi) {                     // same for all 4 quads of a group
                float4 acc = make_float4(0.f, 0.f, 0.f, 0.f);
                for (int r = rlo + quad; r < rhi; r += 4) {
                    float4 v = *(const float4*)&s_msg[r][q * 4];
                    acc.x += v.x; acc.y += v.y; acc.z += v.z; acc.w += v.w;
                }
                acc.x += __shfl_xor(acc.x, 1); acc.y += __shfl_xor(acc.y, 1);
                acc.z += __shfl_xor(acc.z, 1); acc.w += __shfl_xor(acc.w, 1);
                acc.x += __shfl_xor(acc.x, 2); acc.y += __shfl_xor(acc.y, 2);
                acc.z += __shfl_xor(acc.z, 2); acc.w += __shfl_xor(acc.w, 2);
                if (quad == 0) {
                    float* dp = dx + (size_t)nn * HID + q * 4;
                    if (lo < base || hi > base + REB) {
                        atomicAdd(dp + 0, acc.x); atomicAdd(dp + 1, acc.y);
                        atomicAdd(dp + 2, acc.z); atomicAdd(dp + 3, acc.w);
                    } else {
                        *(float4*)dp = acc;
                    }
                }
            }
        }
    }
    __syncthreads();

    // ================= PASS B: channels v=8..15 (cols 24..47) =================
#pragma unroll
    for (int qq = 0; qq < 6; qq++) {
        float4 b = *(const float4*)(m2b + 24 + qq * 4);
        mv[2 * qq + 0] = (v2f){b.x, b.y};
        mv[2 * qq + 1] = (v2f){b.z, b.w};
    }
#pragma unroll
    for (int j = 0; j < 16; j++) {
        v2f hj2 = (v2f){hid[j], hid[j]};
#pragma unroll
        for (int qq = 0; qq < 6; qq++) {
            float4 w4 = *(const float4*)(m2w + j * 48 + 24 + qq * 4);
            mv[2 * qq + 0] = __builtin_elementwise_fma(hj2, (v2f){w4.x, w4.y}, mv[2 * qq + 0]);
            mv[2 * qq + 1] = __builtin_elementwise_fma(hj2, (v2f){w4.z, w4.w}, mv[2 * qq + 1]);
        }
    }
#pragma unroll
    for (int v = 0; v < 8; v++) {
        float x0 = xj[v * 3 + 0], x1 = xj[v * 3 + 1], x2 = xj[v * 3 + 2];
        m[v * 3 + 0] *= x1 * shz - x2 * shy;
        m[v * 3 + 1] *= x2 * shx - x0 * shz;
        m[v * 3 + 2] *= x0 * shy - x1 * shx;
    }
    {
        float4* row = (float4*)&s_msg[t][0];
#pragma unroll
        for (int qq = 0; qq < 6; qq++) row[qq] = ((float4*)m)[qq];
    }
    __syncthreads();

    if (t < 240) {
        for (int nn = n0 + gid; nn <= n1; nn += 10) {
            int lo = off[nn], hi = off[nn + 1];
            int rlo = (lo > base) ? lo - base : 0;
            int rhi = ((hi < base + REB) ? hi : base + REB) - base;
            if (rlo < rhi) {
                float4 acc = make_float4(0.f, 0.f, 0.f, 0.f);
                for (int r = rlo + quad; r < rhi; r += 4) {
                    float4 v = *(const float4*)&s_msg[r][q * 4];
                    acc.x += v.x; acc.y += v.y; acc.z += v.z; acc.w += v.w;
                }
                acc.x += __shfl_xor(acc.x, 1); acc.y += __shfl_xor(acc.y, 1);
                acc.z += __shfl_xor(acc.z, 1); acc.w += __shfl_xor(acc.w, 1);
                acc.x += __shfl_xor(acc.x, 2); acc.y += __shfl_xor(acc.y, 2);
                acc.z += __shfl_xor(acc.z, 2); acc.w += __shfl_xor(acc.w, 2);
                if (quad == 0) {
                    float* dp = dx + (size_t)nn * HID + 24 + q * 4;
                    if (lo < base || hi > base + REB) {
                        atomicAdd(dp + 0, acc.x); atomicAdd(dp + 1, acc.y);
                        atomicAdd(dp + 2, acc.z); atomicAdd(dp + 3, acc.w);
                    } else {
                        *(float4*)dp = acc;
                    }
                }
            }
        }
    }
}

// ---------------- h += dx; dx = 0 (fallback path only) ----------------
__global__ void k_add(float* __restrict__ h, float* __restrict__ dx) {
    int t = blockIdx.x * blockDim.x + threadIdx.x;
    if (t >= N_NODES * HID) return;
    h[t] += dx[t];
    dx[t] = 0.f;
}

// ---------------- pool: per-graph mean of ((h+dx) @ lin_w) ----------------
__global__ void __launch_bounds__(256) k_pool(
    const float* __restrict__ h, const float* __restrict__ dxin, const int* __restrict__ batch,
    const float* __restrict__ linw, float* __restrict__ gsum, float* __restrict__ gcnt)
{
    __shared__ float ss[N_GRAPHS];
    __shared__ float sc[N_GRAPHS];
    for (int i = threadIdx.x; i < N_GRAPHS; i += 256) { ss[i] = 0.f; sc[i] = 0.f; }
    __syncthreads();
    int n = blockIdx.x * 256 + threadIdx.x;
    if (n < N_NODES) {
        float s = 0.f;
        const float4* hv = (const float4*)(h + (size_t)n * HID);
        const float4* dv = (const float4*)(dxin + (size_t)n * HID);
#pragma unroll
        for (int qq = 0; qq < 12; qq++) {
            float4 v = hv[qq], d = dv[qq];
            s += (v.x + d.x) * linw[qq * 4 + 0] + (v.y + d.y) * linw[qq * 4 + 1]
               + (v.z + d.z) * linw[qq * 4 + 2] + (v.w + d.w) * linw[qq * 4 + 3];
        }
        int b = batch[n];
        atomicAdd(&ss[b], s);
        atomicAdd(&sc[b], 1.f);
    }
    __syncthreads();
    for (int i = threadIdx.x; i < N_GRAPHS; i += 256) {
        if (sc[i] != 0.f) {
            atomicAdd(&gsum[i], ss[i]);
            atomicAdd(&gcnt[i], sc[i]);
        }
    }
}

__global__ void k_final(const float* __restrict__ gsum, const float* __restrict__ gcnt,
                        const float* __restrict__ linb, float* __restrict__ out) {
    int g = threadIdx.x;
    if (g < N_GRAPHS) out[g] = gsum[g] / fmaxf(gcnt[g], 1.f) + linb[0];
}

// ---------------- fallback (round-1 proven atomic path) ----------------
__global__ void __launch_bounds__(256) k_edge_atomic(
    const int* __restrict__ ei, const float* __restrict__ ea,
    const float* __restrict__ h, float* __restrict__ dx,
    const float* __restrict__ m1w, const float* __restrict__ m1b,
    const float* __restrict__ m2w, const float* __restrict__ m2b,
    const float* __restrict__ tpw)
{
    __shared__ float s_m1w[48];
    __shared__ float s_m1b[16];
    __shared__ float s_m2w[768];
    __shared__ float s_m2b[48];
    __shared__ float s_tpw[256];
    for (int i = threadIdx.x; i < 48;  i += 256) s_m1w[i] = m1w[i];
    for (int i = threadIdx.x; i < 16;  i += 256) s_m1b[i] = m1b[i];
    for (int i = threadIdx.x; i < 768; i += 256) s_m2w[i] = m2w[i];
    for (int i = threadIdx.x; i < 48;  i += 256) s_m2b[i] = m2b[i];
    for (int i = threadIdx.x; i < 256; i += 256) s_tpw[i] = tpw[i];
    __syncthreads();
    int e = blockIdx.x * 256 + threadIdx.x;
    int src = ei[e];
    int dst = ei[N_EDGES + e];
    float a0 = ea[e * 5 + 0], a1 = ea[e * 5 + 1];
    float rx = ea[e * 5 + 2], ry = ea[e * 5 + 3], rz = ea[e * 5 + 4];
    float r2 = rx * rx + ry * ry + rz * rz;
    float inv = rsqrtf(fmaxf(r2, 1e-24f));
    float shx = SQRT3 * rx * inv, shy = SQRT3 * ry * inv, shz = SQRT3 * rz * inv;
    float hid[16];
#pragma unroll
    for (int j = 0; j < 16; j++) {
        float z = a0 * s_m1w[j] + a1 * s_m1w[16 + j] + r2 * s_m1w[32 + j] + s_m1b[j];
        hid[j] = z / (1.f + __expf(-z));
    }
    float xj[48];
    const float4* hv = (const float4*)(h + (size_t)src * HID);
#pragma unroll
    for (int qq = 0; qq < 12; qq++) {
        float4 v = hv[qq];
        xj[qq * 4 + 0] = v.x; xj[qq * 4 + 1] = v.y; xj[qq * 4 + 2] = v.z; xj[qq * 4 + 3] = v.w;
    }
    float cr[48];
#pragma unroll
    for (int u = 0; u < 16; u++) {
        float x0 = xj[u * 3 + 0], x1 = xj[u * 3 + 1], x2 = xj[u * 3 + 2];
        cr[u * 3 + 0] = x1 * shz - x2 * shy;
        cr[u * 3 + 1] = x2 * shx - x0 * shz;
        cr[u * 3 + 2] = x0 * shy - x1 * shx;
    }
    float* dd = dx + (size_t)dst * HID;
#pragma unroll
    for (int v = 0; v < 16; v++) {
        float t0 = 0.f, t1 = 0.f, t2 = 0.f;
#pragma unroll
        for (int u = 0; u < 16; u++) {
            float w = s_tpw[u * 16 + v];
            t0 += w * cr[u * 3 + 0];
            t1 += w * cr[u * 3 + 1];
            t2 += w * cr[u * 3 + 2];
        }
        float g0 = s_m2b[v * 3 + 0], g1 = s_m2b[v * 3 + 1], g2 = s_m2b[v * 3 + 2];
#pragma unroll
        for (int j = 0; j < 16; j++) {
            float hj = hid[j];
            g0 = fmaf(hj, s_m2w[j * 48 + v * 3 + 0], g0);
            g1 = fmaf(hj, s_m2w[j * 48 + v * 3 + 1], g1);
            g2 = fmaf(hj, s_m2w[j * 48 + v * 3 + 2], g2);
        }
        atomicAdd(dd + v * 3 + 0, g0 * t0 * TP_NORM);
        atomicAdd(dd + v * 3 + 1, g1 * t1 * TP_NORM);
        atomicAdd(dd + v * 3 + 2, g2 * t2 * TP_NORM);
    }
}

extern "C" void kernel_launch(void* const* d_in, const int* in_sizes, int n_in,
                              void* d_out, int out_size, void* d_ws, size_t ws_size,
                              hipStream_t stream) {
    const float* x    = (const float*)d_in[0];
    const int*   ei   = (const int*)  d_in[1];
    const float* ea   = (const float*)d_in[2];
    const int*   batch= (const int*)  d_in[3];
    const float* ew   = (const float*)d_in[4];
    const float* m1w  = (const float*)d_in[5];
    const float* m1b  = (const float*)d_in[6];
    const float* m2w  = (const float*)d_in[7];
    const float* m2b  = (const float*)d_in[8];
    const float* tpw  = (const float*)d_in[9];
    const float* linw = (const float*)d_in[10];
    const float* linb = (const float*)d_in[11];
    float* out = (float*)d_out;

    // -------- workspace layout (256B-aligned carve) --------
    char* w = (char*)d_ws;
    auto alloc = [&](size_t bytes) -> char* {
        char* p = w;
        w += (bytes + 255) & ~(size_t)255;
        return p;
    };
    float*    hA   = (float*)   alloc((size_t)N_NODES * HID * 4);
    float*    hB   = (float*)   alloc((size_t)N_NODES * HID * 4);
    unsigned* h2   = (unsigned*)alloc((size_t)N_NODES * 24 * 4);   // bf16-packed, 96B/row
    float*    dxA  = (float*)   alloc((size_t)N_NODES * HID * 4);
    float*    dxB  = (float*)   alloc((size_t)N_NODES * HID * 4);
    float*    gbuf = (float*)   alloc(2 * N_GRAPHS * 4);
    uint4*    es_s = (uint4*)   alloc((size_t)N_EDGES * 16);       // 16B bf16 records
    int*      off  = (int*)     alloc((size_t)(N_NODES + 1) * 4);
    unsigned* hist = (unsigned*)alloc((size_t)SBLK * HW * 4);      // 12.8MB block histograms
    int*      deg  = (int*)     alloc((size_t)N_NODES * 4);
    int*      blk  = (int*)     alloc((size_t)NBLK * 2 * 4);
    int*      bsum = (int*)     alloc((size_t)NPART * 4);
    int*      bbase= (int*)     alloc((size_t)(NPART + 1) * 4);
    size_t need = (size_t)(w - (char*)d_ws);
    float* gsum = gbuf;
    float* gcnt = gbuf + N_GRAPHS;

    if (ws_size < need) {
        // -------- fallback: round-1 atomic path (needs 19.2MB + 512B) --------
        float* fh   = (float*)d_ws;
        float* fdx  = fh + (size_t)N_NODES * HID;
        float* fgs  = fdx + (size_t)N_NODES * HID;
        float* fgc  = fgs + N_GRAPHS;
        hipMemsetAsync(fdx, 0, ((size_t)N_NODES * HID + 2 * N_GRAPHS) * sizeof(float), stream);
        k_embed<<<(N_NODES * HID + 255) / 256, 256, 0, stream>>>(x, ew, fh);
        for (int l = 0; l < N_LAYERS; l++) {
            k_edge_atomic<<<N_EDGES / 256, 256, 0, stream>>>(ei, ea, fh, fdx,
                m1w + l * 48, m1b + l * 16, m2w + l * 768, m2b + l * 48, tpw + l * 256);
            k_add<<<(N_NODES * HID + 255) / 256, 256, 0, stream>>>(fh, fdx);
        }
        hipMemsetAsync(fdx, 0, (size_t)N_NODES * HID * 4, stream);
        k_pool<<<(N_NODES + 255) / 256, 256, 0, stream>>>(fh, fdx, batch, linw, fgs, fgc);
        k_final<<<1, 64, 0, stream>>>(fgs, fgc, linb, out);
        return;
    }

    // -------- CSR setup: LDS counting sort (no global atomics) --------
    hipMemsetAsync(gbuf, 0, 2 * N_GRAPHS * 4, stream);
    k_hist1<<<SBLK, 512, 0, stream>>>(ei, hist, x, ew, hA);
    k_cscan<<<(N_NODES + 255) / 256, 256, 0, stream>>>((unsigned char*)hist, deg);
    k_sred<<<NPART, 256, 0, stream>>>(deg, bsum);
    k_sscan<<<1, 256, 0, stream>>>(bsum, bbase);
    k_soff<<<NPART, 256, 0, stream>>>(deg, bbase, off);
    k_rng<<<(NBLK + 255) / 256, 256, 0, stream>>>(off, blk);
    k_build2<<<SBLK, 512, 0, stream>>>(ei, ea, off, (const unsigned char*)hist, es_s);

    const int npBlocks = (N_NODES * 24 + 255) / 256;
    float* dxs[2] = { dxA, dxB };
    float* hcur = hA;
    float* hnxt = hB;
    for (int l = 0; l < N_LAYERS; l++) {
        float* dxw = dxs[l & 1];
        if (l == 0) {
            k_h2<<<npBlocks, 256, 0, stream>>>(hcur, tpw, h2, dxw);
        } else {
            // read previous layer's dx, zero THIS layer's dx (disjoint buffers)
            k_h2_add<<<npBlocks, 256, 0, stream>>>(hcur, dxs[(l - 1) & 1], tpw + l * 256,
                                                   h2, hnxt, dxw);
            float* tmp = hcur; hcur = hnxt; hnxt = tmp;
        }
        k_fused<<<NBLK, 256, 0, stream>>>(es_s, off, blk, h2, dxw,
            m1w + l * 48, m1b + l * 16, m2w + l * 768, m2b + l * 48);
    }

    // pool over h_final = hcur + dx_last
    k_pool<<<(N_NODES + 255) / 256, 256, 0, stream>>>(hcur, dxs[(N_LAYERS - 1) & 1],
                                                      batch, linw, gsum, gcnt);
    k_final<<<1, 64, 0, stream>>>(gsum, gcnt, linb, out);
}